// Round 4
// baseline (320.231 us; speedup 1.0000x reference)
//
#include <hip/hip_runtime.h>
#include <math.h>

#define Bsz 4
#define Lq  1024
#define Emb 1024
#define Hh  16
#define Dd  64

typedef short bf16x8 __attribute__((ext_vector_type(8)));
typedef float f32x4 __attribute__((ext_vector_type(4)));

static __device__ __forceinline__ unsigned short f2bf(float f) {
    unsigned u = __float_as_uint(f);
    return (unsigned short)((u + 0x7FFFu + ((u >> 16) & 1u)) >> 16);
}
// pack two f32 -> two bf16 (round-half-up) in one v_perm
static __device__ __forceinline__ unsigned pack2(float lo, float hi) {
    return __builtin_amdgcn_perm(__float_as_uint(hi) + 0x8000u,
                                 __float_as_uint(lo) + 0x8000u, 0x07060302u);
}

// ---------------------------------------------------------------------------
__global__ __launch_bounds__(256) void bias_kernel(const float* __restrict__ mask,
                                                   const int* __restrict__ kpm,
                                                   float* __restrict__ bias, int n)
{
    int i = blockIdx.x * 256 + threadIdx.x;
    if (i < n) {
        float b = 8.0f * logf(fmaxf(mask[i], 1e-6f));
        bias[i] = kpm[i] ? -INFINITY : b;
    }
}

// ---------------------------------------------------------------------------
__global__ __launch_bounds__(256) void cvt_bf16(const float* __restrict__ in,
                                                unsigned short* __restrict__ out, int n4)
{
    int i = blockIdx.x * 256 + threadIdx.x;
    if (i < n4) {
        float4 v = ((const float4*)in)[i];
        ushort4 o;
        o.x = f2bf(v.x); o.y = f2bf(v.y); o.z = f2bf(v.z); o.w = f2bf(v.w);
        ((ushort4*)out)[i] = o;
    }
}

// ---------------------------------------------------------------------------
// C = A(M,K) @ B(N,K)^T + bias.  bf16 in, fp32 accum.  128x128 tile, BK=32.
// MODE 0: bf16 out scattered to (B,H,L,D). MODE 1: f32 out (M,N).
// MODE 2: bf16 out scattered to (B,H,D,L)  (transposed V for PV frags).
// ---------------------------------------------------------------------------
template<int MODE>
__global__ __launch_bounds__(256) void gemm_bf16(const unsigned short* __restrict__ A,
                                                 const unsigned short* __restrict__ Bw,
                                                 const float* __restrict__ bias,
                                                 void* __restrict__ outp)
{
    const int K = 1024;
    __shared__ unsigned short sA[128][40];
    __shared__ unsigned short sB[128][40];
    int tid = threadIdx.x;
    int bm = blockIdx.y * 128, bn = blockIdx.x * 128;
    int w = tid >> 6, lane = tid & 63;
    int wr = (w >> 1) * 64, wc = (w & 1) * 64;
    int fr = lane & 15, fk = (lane >> 4) * 8;
    int srow = tid >> 1, skc = (tid & 1) * 16;
    const unsigned short* Ap = A + (size_t)(bm + srow) * K + skc;
    const unsigned short* Bp = Bw + (size_t)(bn + srow) * K + skc;

    f32x4 acc[4][4];
#pragma unroll
    for (int i = 0; i < 4; ++i)
#pragma unroll
        for (int j = 0; j < 4; ++j) acc[i][j] = (f32x4){0.f, 0.f, 0.f, 0.f};

    for (int k0 = 0; k0 < K; k0 += 32) {
        bf16x8 a0 = *(const bf16x8*)(Ap + k0);
        bf16x8 a1 = *(const bf16x8*)(Ap + k0 + 8);
        bf16x8 b0 = *(const bf16x8*)(Bp + k0);
        bf16x8 b1 = *(const bf16x8*)(Bp + k0 + 8);
        __syncthreads();
        *(bf16x8*)&sA[srow][skc]     = a0;
        *(bf16x8*)&sA[srow][skc + 8] = a1;
        *(bf16x8*)&sB[srow][skc]     = b0;
        *(bf16x8*)&sB[srow][skc + 8] = b1;
        __syncthreads();
        bf16x8 af[4], bfv[4];
#pragma unroll
        for (int i = 0; i < 4; ++i) af[i]  = *(const bf16x8*)&sA[wr + i * 16 + fr][fk];
#pragma unroll
        for (int j = 0; j < 4; ++j) bfv[j] = *(const bf16x8*)&sB[wc + j * 16 + fr][fk];
#pragma unroll
        for (int i = 0; i < 4; ++i)
#pragma unroll
            for (int j = 0; j < 4; ++j)
                acc[i][j] = __builtin_amdgcn_mfma_f32_16x16x32_bf16(af[i], bfv[j], acc[i][j], 0, 0, 0);
    }

    int rb = (lane >> 4) * 4;
#pragma unroll
    for (int j = 0; j < 4; ++j) {
        int n = bn + wc + j * 16 + fr;
        float bia = bias[n];
#pragma unroll
        for (int i = 0; i < 4; ++i) {
#pragma unroll
            for (int r = 0; r < 4; ++r) {
                int m = bm + wr + i * 16 + rb + r;
                float v = acc[i][j][r] + bia;
                if (MODE == 0) {
                    int b = m >> 10, l = m & 1023, h = n >> 6, d = n & 63;
                    ((unsigned short*)outp)[(((size_t)(b * Hh + h)) * Lq + l) * Dd + d] = f2bf(v);
                } else if (MODE == 1) {
                    ((float*)outp)[(size_t)m * 1024 + n] = v;
                } else {
                    int b = m >> 10, l = m & 1023, h = n >> 6, d = n & 63;
                    ((unsigned short*)outp)[(((size_t)(b * Hh + h)) * Dd + d) * Lq + l] = f2bf(v);
                }
            }
        }
    }
}

// ---------------------------------------------------------------------------
// Pass C: flash attention.  1D grid of 1024 blocks, XCD-swizzled so all 16
// qt-blocks of one (b,h) land on the same XCD (K/V become L2-resident there).
// 256 thr / 4 waves, each wave owns 16 q-rows.  Swapped QK^T (mfma(K,Q)):
// lane holds 16 k-vals of q-row (q0w + lane&15).  K-fragments are register
// double-buffered across chunks (kA/kB) to create cross-chunk MLP; V loads
// are grouped after softmax (single L2-latency exposure).
// ---------------------------------------------------------------------------
__global__ __launch_bounds__(256, 4) void attn_flash(const unsigned short* __restrict__ Qh,
                                                     const unsigned short* __restrict__ Kh,
                                                     const unsigned short* __restrict__ Vt,
                                                     const float* __restrict__ mbias,
                                                     unsigned short* __restrict__ ctx,
                                                     float* __restrict__ mstats,
                                                     float* __restrict__ lstats)
{
    __shared__ float sBias[1024];
    __shared__ unsigned short Wl[4][16][64];   // per-wave P tile, XOR-swizzled

    int tid = threadIdx.x;
    int w = tid >> 6, lane = tid & 63;
    int fr = lane & 15, fg = lane >> 4;

    // XCD-colocation decode: lin & 7 = xcd; all blocks of one (b,h) share it.
    int lin = blockIdx.x;
    int xcd = lin & 7, jj = lin >> 3;          // jj in [0,128)
    int pair = xcd * 8 + (jj >> 4);            // 0..63 == h*4 + b
    int qt = jj & 15;
    int b = pair & 3, h = pair >> 2;

    int q0w = qt * 64 + w * 16;
    int swz = (fr & 7) << 2;                   // XOR on 4-byte-word index

    for (int i = tid; i < 1024; i += 256) sBias[i] = mbias[b * Lq + i];
    __syncthreads();

    const unsigned short* Qp = Qh + ((size_t)(b * Hh + h)) * Lq * Dd;
    const unsigned short* Kp = Kh + ((size_t)(b * Hh + h)) * Lq * Dd;
    const unsigned short* Vp = Vt + ((size_t)(b * Hh + h)) * Dd * Lq;

    bf16x8 bq0 = *(const bf16x8*)(Qp + (size_t)(q0w + fr) * Dd + fg * 8);
    bf16x8 bq1 = *(const bf16x8*)(Qp + (size_t)(q0w + fr) * Dd + 32 + fg * 8);

    f32x4 O[4];
#pragma unroll
    for (int dt = 0; dt < 4; ++dt) O[dt] = (f32x4){0.f, 0.f, 0.f, 0.f};
    float m_run = -INFINITY, l_run = 0.f;

    bf16x8 kA0[4], kA1[4], kB0[4], kB1[4];

#define LOADK(K0, K1, KC) do {                                                   \
    _Pragma("unroll")                                                            \
    for (int kt = 0; kt < 4; ++kt) {                                             \
        K0[kt] = *(const bf16x8*)(Kp + (size_t)((KC) + kt * 16 + fr) * Dd + fg * 8);        \
        K1[kt] = *(const bf16x8*)(Kp + (size_t)((KC) + kt * 16 + fr) * Dd + 32 + fg * 8);   \
    }                                                                            \
} while (0)

#define PROCESS(KC, K0, K1) do {                                                 \
    f32x4 s_[4];                                                                 \
    _Pragma("unroll")                                                            \
    for (int kt = 0; kt < 4; ++kt) {                                             \
        s_[kt] = __builtin_amdgcn_mfma_f32_16x16x32_bf16(K0[kt], bq0, (f32x4){0.f, 0.f, 0.f, 0.f}, 0, 0, 0); \
        s_[kt] = __builtin_amdgcn_mfma_f32_16x16x32_bf16(K1[kt], bq1, s_[kt], 0, 0, 0); \
    }                                                                            \
    float v_[16];                                                                \
    float pmax = -INFINITY;                                                      \
    _Pragma("unroll")                                                            \
    for (int kt = 0; kt < 4; ++kt) {                                             \
        float4 bb = *(const float4*)&sBias[(KC) + kt * 16 + fg * 4];             \
        _Pragma("unroll")                                                        \
        for (int r = 0; r < 4; ++r) {                                            \
            float v = s_[kt][r] * 0.125f + (&bb.x)[r];                           \
            v_[kt * 4 + r] = v;                                                  \
            pmax = fmaxf(pmax, v);                                               \
        }                                                                        \
    }                                                                            \
    pmax = fmaxf(pmax, __shfl_xor(pmax, 16, 64));                                \
    pmax = fmaxf(pmax, __shfl_xor(pmax, 32, 64));                                \
    float m_new = fmaxf(m_run, pmax);                                            \
    float scale = __expf(m_run - m_new);                                         \
    float csum = 0.f;                                                            \
    _Pragma("unroll")                                                            \
    for (int i = 0; i < 16; ++i) { float e = __expf(v_[i] - m_new); v_[i] = e; csum += e; } \
    csum += __shfl_xor(csum, 16, 64);                                            \
    csum += __shfl_xor(csum, 32, 64);                                            \
    l_run = l_run * scale + csum;                                                \
    m_run = m_new;                                                               \
    _Pragma("unroll")                                                            \
    for (int r = 0; r < 4; ++r) {                                                \
        float sr = __shfl(scale, fg * 4 + r, 64);                                \
        _Pragma("unroll")                                                        \
        for (int dt = 0; dt < 4; ++dt) O[dt][r] *= sr;                           \
    }                                                                            \
    _Pragma("unroll")                                                            \
    for (int kt = 0; kt < 4; ++kt) {                                             \
        unsigned w0 = pack2(v_[kt * 4 + 0], v_[kt * 4 + 1]);                     \
        unsigned w1 = pack2(v_[kt * 4 + 2], v_[kt * 4 + 3]);                     \
        int base = kt * 8 + fg * 2;                                              \
        uint2 pr; pr.x = w0; pr.y = w1;                                          \
        *(uint2*)&Wl[w][fr][2 * (base ^ swz)] = pr;                              \
    }                                                                            \
    bf16x8 pa0 = *(const bf16x8*)&Wl[w][fr][2 * ((fg * 4) ^ swz)];               \
    bf16x8 pa1 = *(const bf16x8*)&Wl[w][fr][2 * ((16 + fg * 4) ^ swz)];          \
    bf16x8 vb0[4], vb1[4];                                                       \
    _Pragma("unroll")                                                            \
    for (int dt = 0; dt < 4; ++dt) {                                             \
        vb0[dt] = *(const bf16x8*)(Vp + (size_t)(dt * 16 + fr) * Lq + (KC) + fg * 8);      \
        vb1[dt] = *(const bf16x8*)(Vp + (size_t)(dt * 16 + fr) * Lq + (KC) + 32 + fg * 8); \
    }                                                                            \
    _Pragma("unroll")                                                            \
    for (int dt = 0; dt < 4; ++dt) {                                             \
        O[dt] = __builtin_amdgcn_mfma_f32_16x16x32_bf16(pa0, vb0[dt], O[dt], 0, 0, 0); \
        O[dt] = __builtin_amdgcn_mfma_f32_16x16x32_bf16(pa1, vb1[dt], O[dt], 0, 0, 0); \
    }                                                                            \
} while (0)

    LOADK(kA0, kA1, 0);
#pragma unroll 1
    for (int c = 0; c < 16; c += 2) {
        LOADK(kB0, kB1, (c + 1) * 64);      // prefetch c+1 while computing c
        PROCESS(c * 64, kA0, kA1);
        if (c + 2 < 16) LOADK(kA0, kA1, (c + 2) * 64);
        PROCESS((c + 1) * 64, kB0, kB1);
    }
#undef LOADK
#undef PROCESS

    float linv = 1.f / l_run;
#pragma unroll
    for (int r = 0; r < 4; ++r) {
        float lr = __shfl(linv, fg * 4 + r, 64);
#pragma unroll
        for (int dt = 0; dt < 4; ++dt) O[dt][r] *= lr;
    }
#pragma unroll
    for (int dt = 0; dt < 4; ++dt)
#pragma unroll
        for (int r = 0; r < 4; ++r)
            ctx[((size_t)(b * Lq + q0w + fg * 4 + r)) * Emb + h * Dd + dt * 16 + fr] = f2bf(O[dt][r]);

    if (lane < 16) {
        mstats[(size_t)(b * Hh + h) * Lq + q0w + lane] = m_run;
        lstats[(size_t)(b * Hh + h) * Lq + q0w + lane] = linv;
    }
}

// ---------------------------------------------------------------------------
// Pass B: out2 = mean_h softmax weights.  Block = (qt32, kc128, b), 256 thr.
// Recomputes QK^T per head and applies exp(s+bias-m)*linv straight from MFMA
// output registers (stats from pass C) -- no reductions, no main-loop barriers.
// ---------------------------------------------------------------------------
__global__ __launch_bounds__(256) void attn_out2(const unsigned short* __restrict__ Qh,
                                                 const unsigned short* __restrict__ Kh,
                                                 const float* __restrict__ mbias,
                                                 const float* __restrict__ mstats,
                                                 const float* __restrict__ lstats,
                                                 float* __restrict__ out2)
{
    __shared__ float sM[16][32];
    __shared__ float sLi[16][32];
    int tid = threadIdx.x;
    int w = tid >> 6, lane = tid & 63;
    int fr = lane & 15, fg = lane >> 4;
    int q0 = blockIdx.x * 32;
    int kc = blockIdx.y * 128;
    int b  = blockIdx.z;

    for (int i = tid; i < 512; i += 256) {
        int h = i >> 5, qq = i & 31;
        sM[h][qq]  = mstats[(size_t)(b * Hh + h) * Lq + q0 + qq];
        sLi[h][qq] = lstats[(size_t)(b * Hh + h) * Lq + q0 + qq];
    }
    __syncthreads();

    float bias0 = mbias[b * Lq + kc + w * 32 + fr];
    float bias1 = mbias[b * Lq + kc + w * 32 + 16 + fr];

    float o2[2][2][4];
#pragma unroll
    for (int rt = 0; rt < 2; ++rt)
#pragma unroll
        for (int ct = 0; ct < 2; ++ct)
#pragma unroll
            for (int r = 0; r < 4; ++r) o2[rt][ct][r] = 0.f;

    for (int h = 0; h < Hh; ++h) {
        const unsigned short* Qp = Qh + ((size_t)(b * Hh + h)) * Lq * Dd;
        const unsigned short* Kp = Kh + ((size_t)(b * Hh + h)) * Lq * Dd;
        bf16x8 aq[2][2], bk[2][2];
#pragma unroll
        for (int rt = 0; rt < 2; ++rt)
#pragma unroll
            for (int ks = 0; ks < 2; ++ks)
                aq[rt][ks] = *(const bf16x8*)(Qp + (size_t)(q0 + rt * 16 + fr) * Dd + ks * 32 + fg * 8);
#pragma unroll
        for (int ct = 0; ct < 2; ++ct)
#pragma unroll
            for (int ks = 0; ks < 2; ++ks)
                bk[ct][ks] = *(const bf16x8*)(Kp + (size_t)(kc + w * 32 + ct * 16 + fr) * Dd + ks * 32 + fg * 8);
        float4 mrow[2], lirow[2];
#pragma unroll
        for (int rt = 0; rt < 2; ++rt) {
            mrow[rt]  = *(const float4*)&sM[h][rt * 16 + fg * 4];
            lirow[rt] = *(const float4*)&sLi[h][rt * 16 + fg * 4];
        }
#pragma unroll
        for (int rt = 0; rt < 2; ++rt)
#pragma unroll
            for (int ct = 0; ct < 2; ++ct) {
                f32x4 s = __builtin_amdgcn_mfma_f32_16x16x32_bf16(aq[rt][0], bk[ct][0], (f32x4){0.f, 0.f, 0.f, 0.f}, 0, 0, 0);
                s = __builtin_amdgcn_mfma_f32_16x16x32_bf16(aq[rt][1], bk[ct][1], s, 0, 0, 0);
                float bia = ct ? bias1 : bias0;
#pragma unroll
                for (int r = 0; r < 4; ++r)
                    o2[rt][ct][r] += __expf(s[r] * 0.125f + bia - mrow[rt][r]) * lirow[rt][r];
            }
    }

#pragma unroll
    for (int rt = 0; rt < 2; ++rt)
#pragma unroll
        for (int ct = 0; ct < 2; ++ct)
#pragma unroll
            for (int r = 0; r < 4; ++r)
                out2[((size_t)(b * Lq + q0 + rt * 16 + fg * 4 + r)) * Lq + kc + w * 32 + ct * 16 + fr]
                    = o2[rt][ct][r] * 0.0625f;
}

// ---------------------------------------------------------------------------
extern "C" void kernel_launch(void* const* d_in, const int* in_sizes, int n_in,
                              void* d_out, int out_size, void* d_ws, size_t ws_size,
                              hipStream_t stream)
{
    const float* query = (const float*)d_in[0];
    const float* key   = (const float*)d_in[1];
    const float* value = (const float*)d_in[2];
    const float* amask = (const float*)d_in[3];
    const int*   kpm   = (const int*)d_in[4];
    const float* Wq = (const float*)d_in[5];
    const float* bq = (const float*)d_in[6];
    const float* Wk = (const float*)d_in[7];
    const float* bk = (const float*)d_in[8];
    const float* Wv = (const float*)d_in[9];
    const float* bv = (const float*)d_in[10];
    const float* Wo = (const float*)d_in[11];
    const float* bo = (const float*)d_in[12];

    float* out1 = (float*)d_out;                       // (B,L,E) f32
    float* out2 = out1 + (size_t)Bsz * Lq * Emb;       // (B,L,L) f32

    const size_t MB = 1u << 20;
    char* ws = (char*)d_ws;
    unsigned short* qbf = (unsigned short*)(ws + 0 * MB);
    unsigned short* kbf = (unsigned short*)(ws + 8 * MB);
    unsigned short* vbf = (unsigned short*)(ws + 16 * MB);
    unsigned short* wqb = (unsigned short*)(ws + 24 * MB);
    unsigned short* wkb = (unsigned short*)(ws + 26 * MB);
    unsigned short* wvb = (unsigned short*)(ws + 28 * MB);
    unsigned short* wob = (unsigned short*)(ws + 30 * MB);
    unsigned short* QhB = (unsigned short*)(ws + 32 * MB);  // (B,H,L,D) bf16
    unsigned short* KhB = (unsigned short*)(ws + 40 * MB);
    unsigned short* VtB = (unsigned short*)(ws + 48 * MB);  // (B,H,D,L) bf16
    unsigned short* ctxB = (unsigned short*)(ws + 56 * MB); // (B,L,E) bf16
    float* mbias  = (float*)(ws + 64 * MB);                 // 16 KB
    // stats alias the qbf region (dead after the Q-projection GEMM)
    float* mstats = (float*)(ws + 0 * MB);                  // 256 KB
    float* lstats = (float*)(ws + 0 * MB + 256 * 1024);     // 256 KB

    bias_kernel<<<16, 256, 0, stream>>>(amask, kpm, mbias, Bsz * Lq);

    cvt_bf16<<<4096, 256, 0, stream>>>(query, qbf, 1048576);
    cvt_bf16<<<4096, 256, 0, stream>>>(key,   kbf, 1048576);
    cvt_bf16<<<4096, 256, 0, stream>>>(value, vbf, 1048576);
    cvt_bf16<<<1024, 256, 0, stream>>>(Wq, wqb, 262144);
    cvt_bf16<<<1024, 256, 0, stream>>>(Wk, wkb, 262144);
    cvt_bf16<<<1024, 256, 0, stream>>>(Wv, wvb, 262144);
    cvt_bf16<<<1024, 256, 0, stream>>>(Wo, wob, 262144);

    dim3 gg(8, 32), gb(256);
    gemm_bf16<0><<<gg, gb, 0, stream>>>(qbf, wqb, bq, QhB);
    gemm_bf16<0><<<gg, gb, 0, stream>>>(kbf, wkb, bk, KhB);
    gemm_bf16<2><<<gg, gb, 0, stream>>>(vbf, wvb, bv, VtB);

    attn_flash<<<1024, 256, 0, stream>>>(QhB, KhB, VtB, mbias, ctxB, mstats, lstats);
    attn_out2<<<dim3(32, 8, 4), 256, 0, stream>>>(QhB, KhB, mbias, mstats, lstats, out2);

    gemm_bf16<1><<<gg, gb, 0, stream>>>(ctxB, wob, bo, out1);
}

// Round 5
// 264.709 us; speedup vs baseline: 1.2097x; 1.2097x over previous
//
#include <hip/hip_runtime.h>
#include <math.h>

#define Bsz 4
#define Lq  1024
#define Emb 1024
#define Hh  16
#define Dd  64

typedef short bf16x8 __attribute__((ext_vector_type(8)));
typedef float f32x4 __attribute__((ext_vector_type(4)));

static __device__ __forceinline__ unsigned short f2bf(float f) {
    unsigned u = __float_as_uint(f);
    return (unsigned short)((u + 0x7FFFu + ((u >> 16) & 1u)) >> 16);
}
// pack two f32 -> two bf16 (round-half-up) in one v_perm
static __device__ __forceinline__ unsigned pack2(float lo, float hi) {
    return __builtin_amdgcn_perm(__float_as_uint(hi) + 0x8000u,
                                 __float_as_uint(lo) + 0x8000u, 0x07060302u);
}

// ---------------------------------------------------------------------------
__global__ __launch_bounds__(256) void bias_kernel(const float* __restrict__ mask,
                                                   const int* __restrict__ kpm,
                                                   float* __restrict__ bias, int n)
{
    int i = blockIdx.x * 256 + threadIdx.x;
    if (i < n) {
        float b = 8.0f * logf(fmaxf(mask[i], 1e-6f));
        bias[i] = kpm[i] ? -INFINITY : b;
    }
}

// ---------------------------------------------------------------------------
__global__ __launch_bounds__(256) void cvt_bf16(const float* __restrict__ in,
                                                unsigned short* __restrict__ out, int n4)
{
    int i = blockIdx.x * 256 + threadIdx.x;
    if (i < n4) {
        float4 v = ((const float4*)in)[i];
        ushort4 o;
        o.x = f2bf(v.x); o.y = f2bf(v.y); o.z = f2bf(v.z); o.w = f2bf(v.w);
        ((ushort4*)out)[i] = o;
    }
}

// ---------------------------------------------------------------------------
// C = A(M,K) @ B(N,K)^T + bias.  bf16 in, fp32 accum.  128x128 tile, BK=32.
// MODE 0: bf16 out scattered to (B,H,L,D). MODE 1: f32 out (M,N).
// MODE 2: bf16 out scattered to (B,H,D,L)  (transposed V for PV frags).
// ---------------------------------------------------------------------------
template<int MODE>
__global__ __launch_bounds__(256) void gemm_bf16(const unsigned short* __restrict__ A,
                                                 const unsigned short* __restrict__ Bw,
                                                 const float* __restrict__ bias,
                                                 void* __restrict__ outp)
{
    const int K = 1024;
    __shared__ unsigned short sA[128][40];
    __shared__ unsigned short sB[128][40];
    int tid = threadIdx.x;
    int bm = blockIdx.y * 128, bn = blockIdx.x * 128;
    int w = tid >> 6, lane = tid & 63;
    int wr = (w >> 1) * 64, wc = (w & 1) * 64;
    int fr = lane & 15, fk = (lane >> 4) * 8;
    int srow = tid >> 1, skc = (tid & 1) * 16;
    const unsigned short* Ap = A + (size_t)(bm + srow) * K + skc;
    const unsigned short* Bp = Bw + (size_t)(bn + srow) * K + skc;

    f32x4 acc[4][4];
#pragma unroll
    for (int i = 0; i < 4; ++i)
#pragma unroll
        for (int j = 0; j < 4; ++j) acc[i][j] = (f32x4){0.f, 0.f, 0.f, 0.f};

    for (int k0 = 0; k0 < K; k0 += 32) {
        bf16x8 a0 = *(const bf16x8*)(Ap + k0);
        bf16x8 a1 = *(const bf16x8*)(Ap + k0 + 8);
        bf16x8 b0 = *(const bf16x8*)(Bp + k0);
        bf16x8 b1 = *(const bf16x8*)(Bp + k0 + 8);
        __syncthreads();
        *(bf16x8*)&sA[srow][skc]     = a0;
        *(bf16x8*)&sA[srow][skc + 8] = a1;
        *(bf16x8*)&sB[srow][skc]     = b0;
        *(bf16x8*)&sB[srow][skc + 8] = b1;
        __syncthreads();
        bf16x8 af[4], bfv[4];
#pragma unroll
        for (int i = 0; i < 4; ++i) af[i]  = *(const bf16x8*)&sA[wr + i * 16 + fr][fk];
#pragma unroll
        for (int j = 0; j < 4; ++j) bfv[j] = *(const bf16x8*)&sB[wc + j * 16 + fr][fk];
#pragma unroll
        for (int i = 0; i < 4; ++i)
#pragma unroll
            for (int j = 0; j < 4; ++j)
                acc[i][j] = __builtin_amdgcn_mfma_f32_16x16x32_bf16(af[i], bfv[j], acc[i][j], 0, 0, 0);
    }

    int rb = (lane >> 4) * 4;
#pragma unroll
    for (int j = 0; j < 4; ++j) {
        int n = bn + wc + j * 16 + fr;
        float bia = bias[n];
#pragma unroll
        for (int i = 0; i < 4; ++i) {
#pragma unroll
            for (int r = 0; r < 4; ++r) {
                int m = bm + wr + i * 16 + rb + r;
                float v = acc[i][j][r] + bia;
                if (MODE == 0) {
                    int b = m >> 10, l = m & 1023, h = n >> 6, d = n & 63;
                    ((unsigned short*)outp)[(((size_t)(b * Hh + h)) * Lq + l) * Dd + d] = f2bf(v);
                } else if (MODE == 1) {
                    ((float*)outp)[(size_t)m * 1024 + n] = v;
                } else {
                    int b = m >> 10, l = m & 1023, h = n >> 6, d = n & 63;
                    ((unsigned short*)outp)[(((size_t)(b * Hh + h)) * Dd + d) * Lq + l] = f2bf(v);
                }
            }
        }
    }
}

// ---------------------------------------------------------------------------
// Pass C: flash attention, ILP edition.
// 512 blocks (XCD-colocated per (b,h)), 4 waves, 32 q-rows per wave = two
// independent 16-q tiles A/B -> two overlapping softmax chains per wave.
// __launch_bounds__(256,2): ~240 VGPR so K double-buffer + hoisted V frags
// stay live.  PV is operand-swapped (O^T = mfma(V,P)) so the online-softmax
// rescale and 1/l are per-lane multiplies (q = lane&15) -- zero bpermutes in
// the main loop.
// ---------------------------------------------------------------------------
__global__ __launch_bounds__(256, 2) void attn_flash(const unsigned short* __restrict__ Qh,
                                                     const unsigned short* __restrict__ Kh,
                                                     const unsigned short* __restrict__ Vt,
                                                     const float* __restrict__ mbias,
                                                     unsigned short* __restrict__ ctx,
                                                     float* __restrict__ mstats,
                                                     float* __restrict__ lstats)
{
    __shared__ float sBias[1024];
    __shared__ unsigned short Wl[4][2][16][64];   // per-wave, per-tile P, swizzled

    int tid = threadIdx.x;
    int w = tid >> 6, lane = tid & 63;
    int fr = lane & 15, fg = lane >> 4;

    // XCD-colocation: all 8 qt-blocks of one (b,h) share an XCD.
    int lin = blockIdx.x;
    int xcd = lin & 7, jj = lin >> 3;          // jj in [0,64)
    int pair = xcd * 8 + (jj >> 3);            // 0..63 == h*4 + b
    int qt = jj & 7;
    int b = pair & 3, h = pair >> 2;

    int q0A = qt * 128 + w * 32;
    int q0B = q0A + 16;
    int swz = (fr & 7) << 2;                   // XOR on 4-byte-word index

    for (int i = tid; i < 1024; i += 256) sBias[i] = mbias[b * Lq + i];
    __syncthreads();

    const unsigned short* Qp = Qh + ((size_t)(b * Hh + h)) * Lq * Dd;
    const unsigned short* Kp = Kh + ((size_t)(b * Hh + h)) * Lq * Dd;
    const unsigned short* Vp = Vt + ((size_t)(b * Hh + h)) * Dd * Lq;

    bf16x8 qA0 = *(const bf16x8*)(Qp + (size_t)(q0A + fr) * Dd + fg * 8);
    bf16x8 qA1 = *(const bf16x8*)(Qp + (size_t)(q0A + fr) * Dd + 32 + fg * 8);
    bf16x8 qB0 = *(const bf16x8*)(Qp + (size_t)(q0B + fr) * Dd + fg * 8);
    bf16x8 qB1 = *(const bf16x8*)(Qp + (size_t)(q0B + fr) * Dd + 32 + fg * 8);

    f32x4 OA[4], OB[4];
#pragma unroll
    for (int dt = 0; dt < 4; ++dt) { OA[dt] = (f32x4){0.f,0.f,0.f,0.f}; OB[dt] = (f32x4){0.f,0.f,0.f,0.f}; }
    float mA = -INFINITY, lA = 0.f, mB = -INFINITY, lB = 0.f;

    bf16x8 kX0[4], kX1[4], kY0[4], kY1[4];
    bf16x8 vb0[4], vb1[4];

#define LOADK(K0, K1, KC) do {                                                   \
    _Pragma("unroll")                                                            \
    for (int kt = 0; kt < 4; ++kt) {                                             \
        K0[kt] = *(const bf16x8*)(Kp + (size_t)((KC) + kt * 16 + fr) * Dd + fg * 8);        \
        K1[kt] = *(const bf16x8*)(Kp + (size_t)((KC) + kt * 16 + fr) * Dd + 32 + fg * 8);   \
    }                                                                            \
} while (0)

#define LOADV(KC) do {                                                           \
    _Pragma("unroll")                                                            \
    for (int dt = 0; dt < 4; ++dt) {                                             \
        vb0[dt] = *(const bf16x8*)(Vp + (size_t)(dt * 16 + fr) * Lq + (KC) + fg * 8);       \
        vb1[dt] = *(const bf16x8*)(Vp + (size_t)(dt * 16 + fr) * Lq + (KC) + 32 + fg * 8);  \
    }                                                                            \
} while (0)

#define QK(S, K0, K1, B0, B1) do {                                               \
    _Pragma("unroll")                                                            \
    for (int kt = 0; kt < 4; ++kt) {                                             \
        S[kt] = __builtin_amdgcn_mfma_f32_16x16x32_bf16(K0[kt], B0, (f32x4){0.f,0.f,0.f,0.f}, 0, 0, 0); \
        S[kt] = __builtin_amdgcn_mfma_f32_16x16x32_bf16(K1[kt], B1, S[kt], 0, 0, 0); \
    }                                                                            \
} while (0)

// softmax + PV for one tile.  MT/LT/OT per-lane (q = fr).  TI = tile slot.
#define SMPV(S, MT, LT, OT, TI, KC) do {                                         \
    float v_[16];                                                                \
    float pmax = -INFINITY;                                                      \
    _Pragma("unroll")                                                            \
    for (int kt = 0; kt < 4; ++kt) {                                             \
        float4 bb = *(const float4*)&sBias[(KC) + kt * 16 + fg * 4];             \
        _Pragma("unroll")                                                        \
        for (int r = 0; r < 4; ++r) {                                            \
            float vv = S[kt][r] * 0.125f + (&bb.x)[r];                           \
            v_[kt * 4 + r] = vv;                                                 \
            pmax = fmaxf(pmax, vv);                                              \
        }                                                                        \
    }                                                                            \
    pmax = fmaxf(pmax, __shfl_xor(pmax, 16, 64));                                \
    pmax = fmaxf(pmax, __shfl_xor(pmax, 32, 64));                                \
    float mn = fmaxf(MT, pmax);                                                  \
    float sc = __expf(MT - mn);                                                  \
    float cs = 0.f;                                                              \
    _Pragma("unroll")                                                            \
    for (int i = 0; i < 16; ++i) { float e = __expf(v_[i] - mn); v_[i] = e; cs += e; } \
    cs += __shfl_xor(cs, 16, 64);                                                \
    cs += __shfl_xor(cs, 32, 64);                                                \
    LT = LT * sc + cs;                                                           \
    MT = mn;                                                                     \
    _Pragma("unroll")                                                            \
    for (int dt = 0; dt < 4; ++dt)                                               \
        _Pragma("unroll")                                                        \
        for (int r = 0; r < 4; ++r) OT[dt][r] *= sc;                             \
    _Pragma("unroll")                                                            \
    for (int kt = 0; kt < 4; ++kt) {                                             \
        unsigned w0 = pack2(v_[kt * 4 + 0], v_[kt * 4 + 1]);                     \
        unsigned w1 = pack2(v_[kt * 4 + 2], v_[kt * 4 + 3]);                     \
        uint2 pr; pr.x = w0; pr.y = w1;                                          \
        *(uint2*)&Wl[w][TI][fr][2 * ((kt * 8 + fg * 2) ^ swz)] = pr;             \
    }                                                                            \
    bf16x8 pa0 = *(const bf16x8*)&Wl[w][TI][fr][2 * ((fg * 4) ^ swz)];           \
    bf16x8 pa1 = *(const bf16x8*)&Wl[w][TI][fr][2 * ((16 + fg * 4) ^ swz)];      \
    _Pragma("unroll")                                                            \
    for (int dt = 0; dt < 4; ++dt) {                                             \
        OT[dt] = __builtin_amdgcn_mfma_f32_16x16x32_bf16(vb0[dt], pa0, OT[dt], 0, 0, 0); \
        OT[dt] = __builtin_amdgcn_mfma_f32_16x16x32_bf16(vb1[dt], pa1, OT[dt], 0, 0, 0); \
    }                                                                            \
} while (0)

    LOADK(kX0, kX1, 0);
#pragma unroll 1
    for (int c = 0; c < 16; c += 2) {
        f32x4 SA[4], SB[4];
        // ---- chunk c (K in X) ----
        QK(SA, kX0, kX1, qA0, qA1);
        QK(SB, kX0, kX1, qB0, qB1);
        LOADK(kY0, kY1, (c + 1) * 64);     // lands under softmax below
        LOADV(c * 64);                     // lands under softmax below
        SMPV(SA, mA, lA, OA, 0, c * 64);
        SMPV(SB, mB, lB, OB, 1, c * 64);
        // ---- chunk c+1 (K in Y) ----
        QK(SA, kY0, kY1, qA0, qA1);
        QK(SB, kY0, kY1, qB0, qB1);
        if (c + 2 < 16) LOADK(kX0, kX1, (c + 2) * 64);
        LOADV((c + 1) * 64);
        SMPV(SA, mA, lA, OA, 0, (c + 1) * 64);
        SMPV(SB, mB, lB, OB, 1, (c + 1) * 64);
    }
#undef LOADK
#undef LOADV
#undef QK
#undef SMPV

    float liA = 1.f / lA, liB = 1.f / lB;
#pragma unroll
    for (int dt = 0; dt < 4; ++dt) {
#pragma unroll
        for (int r = 0; r < 4; ++r) { OA[dt][r] *= liA; OB[dt][r] *= liB; }
    }
    // O^T layout: lane holds q = fr, d = dt*16 + fg*4 + r  (4 consecutive d)
#pragma unroll
    for (int dt = 0; dt < 4; ++dt) {
        uint2 pa; pa.x = pack2(OA[dt][0], OA[dt][1]); pa.y = pack2(OA[dt][2], OA[dt][3]);
        *(uint2*)(ctx + ((size_t)(b * Lq + q0A + fr)) * Emb + h * Dd + dt * 16 + fg * 4) = pa;
        uint2 pb; pb.x = pack2(OB[dt][0], OB[dt][1]); pb.y = pack2(OB[dt][2], OB[dt][3]);
        *(uint2*)(ctx + ((size_t)(b * Lq + q0B + fr)) * Emb + h * Dd + dt * 16 + fg * 4) = pb;
    }

    if (lane < 16) {
        mstats[(size_t)(b * Hh + h) * Lq + q0A + lane] = mA;
        lstats[(size_t)(b * Hh + h) * Lq + q0A + lane] = liA;
        mstats[(size_t)(b * Hh + h) * Lq + q0B + lane] = mB;
        lstats[(size_t)(b * Hh + h) * Lq + q0B + lane] = liB;
    }
}

// ---------------------------------------------------------------------------
// Pass B: out2 = mean_h softmax weights.  Block = (qt32, kc128, b), 256 thr.
// Recomputes QK^T per head and applies exp(s+bias-m)*linv straight from MFMA
// output registers (stats from pass C) -- no reductions, no main-loop barriers.
// ---------------------------------------------------------------------------
__global__ __launch_bounds__(256) void attn_out2(const unsigned short* __restrict__ Qh,
                                                 const unsigned short* __restrict__ Kh,
                                                 const float* __restrict__ mbias,
                                                 const float* __restrict__ mstats,
                                                 const float* __restrict__ lstats,
                                                 float* __restrict__ out2)
{
    __shared__ float sM[16][32];
    __shared__ float sLi[16][32];
    int tid = threadIdx.x;
    int w = tid >> 6, lane = tid & 63;
    int fr = lane & 15, fg = lane >> 4;
    int q0 = blockIdx.x * 32;
    int kc = blockIdx.y * 128;
    int b  = blockIdx.z;

    for (int i = tid; i < 512; i += 256) {
        int h = i >> 5, qq = i & 31;
        sM[h][qq]  = mstats[(size_t)(b * Hh + h) * Lq + q0 + qq];
        sLi[h][qq] = lstats[(size_t)(b * Hh + h) * Lq + q0 + qq];
    }
    __syncthreads();

    float bias0 = mbias[b * Lq + kc + w * 32 + fr];
    float bias1 = mbias[b * Lq + kc + w * 32 + 16 + fr];

    float o2[2][2][4];
#pragma unroll
    for (int rt = 0; rt < 2; ++rt)
#pragma unroll
        for (int ct = 0; ct < 2; ++ct)
#pragma unroll
            for (int r = 0; r < 4; ++r) o2[rt][ct][r] = 0.f;

    for (int h = 0; h < Hh; ++h) {
        const unsigned short* Qp = Qh + ((size_t)(b * Hh + h)) * Lq * Dd;
        const unsigned short* Kp = Kh + ((size_t)(b * Hh + h)) * Lq * Dd;
        bf16x8 aq[2][2], bk[2][2];
#pragma unroll
        for (int rt = 0; rt < 2; ++rt)
#pragma unroll
            for (int ks = 0; ks < 2; ++ks)
                aq[rt][ks] = *(const bf16x8*)(Qp + (size_t)(q0 + rt * 16 + fr) * Dd + ks * 32 + fg * 8);
#pragma unroll
        for (int ct = 0; ct < 2; ++ct)
#pragma unroll
            for (int ks = 0; ks < 2; ++ks)
                bk[ct][ks] = *(const bf16x8*)(Kp + (size_t)(kc + w * 32 + ct * 16 + fr) * Dd + ks * 32 + fg * 8);
        float4 mrow[2], lirow[2];
#pragma unroll
        for (int rt = 0; rt < 2; ++rt) {
            mrow[rt]  = *(const float4*)&sM[h][rt * 16 + fg * 4];
            lirow[rt] = *(const float4*)&sLi[h][rt * 16 + fg * 4];
        }
#pragma unroll
        for (int rt = 0; rt < 2; ++rt)
#pragma unroll
            for (int ct = 0; ct < 2; ++ct) {
                f32x4 s = __builtin_amdgcn_mfma_f32_16x16x32_bf16(aq[rt][0], bk[ct][0], (f32x4){0.f, 0.f, 0.f, 0.f}, 0, 0, 0);
                s = __builtin_amdgcn_mfma_f32_16x16x32_bf16(aq[rt][1], bk[ct][1], s, 0, 0, 0);
                float bia = ct ? bias1 : bias0;
#pragma unroll
                for (int r = 0; r < 4; ++r)
                    o2[rt][ct][r] += __expf(s[r] * 0.125f + bia - mrow[rt][r]) * lirow[rt][r];
            }
    }

#pragma unroll
    for (int rt = 0; rt < 2; ++rt)
#pragma unroll
        for (int ct = 0; ct < 2; ++ct)
#pragma unroll
            for (int r = 0; r < 4; ++r)
                out2[((size_t)(b * Lq + q0 + rt * 16 + fg * 4 + r)) * Lq + kc + w * 32 + ct * 16 + fr]
                    = o2[rt][ct][r] * 0.0625f;
}

// ---------------------------------------------------------------------------
extern "C" void kernel_launch(void* const* d_in, const int* in_sizes, int n_in,
                              void* d_out, int out_size, void* d_ws, size_t ws_size,
                              hipStream_t stream)
{
    const float* query = (const float*)d_in[0];
    const float* key   = (const float*)d_in[1];
    const float* value = (const float*)d_in[2];
    const float* amask = (const float*)d_in[3];
    const int*   kpm   = (const int*)d_in[4];
    const float* Wq = (const float*)d_in[5];
    const float* bq = (const float*)d_in[6];
    const float* Wk = (const float*)d_in[7];
    const float* bk = (const float*)d_in[8];
    const float* Wv = (const float*)d_in[9];
    const float* bv = (const float*)d_in[10];
    const float* Wo = (const float*)d_in[11];
    const float* bo = (const float*)d_in[12];

    float* out1 = (float*)d_out;                       // (B,L,E) f32
    float* out2 = out1 + (size_t)Bsz * Lq * Emb;       // (B,L,L) f32

    const size_t MB = 1u << 20;
    char* ws = (char*)d_ws;
    unsigned short* qbf = (unsigned short*)(ws + 0 * MB);
    unsigned short* kbf = (unsigned short*)(ws + 8 * MB);
    unsigned short* vbf = (unsigned short*)(ws + 16 * MB);
    unsigned short* wqb = (unsigned short*)(ws + 24 * MB);
    unsigned short* wkb = (unsigned short*)(ws + 26 * MB);
    unsigned short* wvb = (unsigned short*)(ws + 28 * MB);
    unsigned short* wob = (unsigned short*)(ws + 30 * MB);
    unsigned short* QhB = (unsigned short*)(ws + 32 * MB);  // (B,H,L,D) bf16
    unsigned short* KhB = (unsigned short*)(ws + 40 * MB);
    unsigned short* VtB = (unsigned short*)(ws + 48 * MB);  // (B,H,D,L) bf16
    unsigned short* ctxB = (unsigned short*)(ws + 56 * MB); // (B,L,E) bf16
    float* mbias  = (float*)(ws + 64 * MB);                 // 16 KB
    // stats alias the qbf region (dead after the Q-projection GEMM)
    float* mstats = (float*)(ws + 0 * MB);                  // 256 KB
    float* lstats = (float*)(ws + 0 * MB + 256 * 1024);     // 256 KB

    bias_kernel<<<16, 256, 0, stream>>>(amask, kpm, mbias, Bsz * Lq);

    cvt_bf16<<<4096, 256, 0, stream>>>(query, qbf, 1048576);
    cvt_bf16<<<4096, 256, 0, stream>>>(key,   kbf, 1048576);
    cvt_bf16<<<4096, 256, 0, stream>>>(value, vbf, 1048576);
    cvt_bf16<<<1024, 256, 0, stream>>>(Wq, wqb, 262144);
    cvt_bf16<<<1024, 256, 0, stream>>>(Wk, wkb, 262144);
    cvt_bf16<<<1024, 256, 0, stream>>>(Wv, wvb, 262144);
    cvt_bf16<<<1024, 256, 0, stream>>>(Wo, wob, 262144);

    dim3 gg(8, 32), gb(256);
    gemm_bf16<0><<<gg, gb, 0, stream>>>(qbf, wqb, bq, QhB);
    gemm_bf16<0><<<gg, gb, 0, stream>>>(kbf, wkb, bk, KhB);
    gemm_bf16<2><<<gg, gb, 0, stream>>>(vbf, wvb, bv, VtB);

    attn_flash<<<512, 256, 0, stream>>>(QhB, KhB, VtB, mbias, ctxB, mstats, lstats);
    attn_out2<<<dim3(32, 8, 4), 256, 0, stream>>>(QhB, KhB, mbias, mstats, lstats, out2);

    gemm_bf16<1><<<gg, gb, 0, stream>>>(ctxB, wob, bo, out1);
}

// Round 6
// 238.585 us; speedup vs baseline: 1.3422x; 1.1095x over previous
//
#include <hip/hip_runtime.h>
#include <math.h>

#define Bsz 4
#define Lq  1024
#define Emb 1024
#define Hh  16
#define Dd  64

typedef short bf16x8 __attribute__((ext_vector_type(8)));
typedef float f32x4 __attribute__((ext_vector_type(4)));

static __device__ __forceinline__ unsigned short f2bf(float f) {
    unsigned u = __float_as_uint(f);
    return (unsigned short)((u + 0x7FFFu + ((u >> 16) & 1u)) >> 16);
}
// pack two f32 -> two bf16 (round-half-up) in one v_perm
static __device__ __forceinline__ unsigned pack2(float lo, float hi) {
    return __builtin_amdgcn_perm(__float_as_uint(hi) + 0x8000u,
                                 __float_as_uint(lo) + 0x8000u, 0x07060302u);
}

// global -> LDS direct copy, 16 B per lane.  LDS dest must be wave-uniform;
// HW writes lane l's 16 B at lds + 16*l.
#define GLOAD_LDS16(gp, lp) __builtin_amdgcn_global_load_lds(                  \
    (const __attribute__((address_space(1))) void*)(gp),                       \
    (__attribute__((address_space(3))) void*)(lp), 16, 0, 0)

// ---------------------------------------------------------------------------
__global__ __launch_bounds__(256) void bias_kernel(const float* __restrict__ mask,
                                                   const int* __restrict__ kpm,
                                                   float* __restrict__ bias, int n)
{
    int i = blockIdx.x * 256 + threadIdx.x;
    if (i < n) {
        float b = 8.0f * logf(fmaxf(mask[i], 1e-6f));
        bias[i] = kpm[i] ? -INFINITY : b;
    }
}

// ---------------------------------------------------------------------------
// One launch converts q,k,v (3 x 1048576 float4 regions).
__global__ __launch_bounds__(256) void cvt_qkv(const float* __restrict__ q,
                                               const float* __restrict__ k,
                                               const float* __restrict__ v,
                                               unsigned short* __restrict__ qo,
                                               unsigned short* __restrict__ ko,
                                               unsigned short* __restrict__ vo)
{
    int i = blockIdx.x * 256 + threadIdx.x;
    const float* src; unsigned short* dst; int off;
    if (i < 1048576)      { src = q; dst = qo; off = i; }
    else if (i < 2097152) { src = k; dst = ko; off = i - 1048576; }
    else                  { src = v; dst = vo; off = i - 2097152; }
    float4 x = ((const float4*)src)[off];
    ushort4 o;
    o.x = f2bf(x.x); o.y = f2bf(x.y); o.z = f2bf(x.z); o.w = f2bf(x.w);
    ((ushort4*)dst)[off] = o;
}

// One launch converts the 4 weight matrices (4 x 262144 float4 regions).
__global__ __launch_bounds__(256) void cvt_w4(const float* __restrict__ w0,
                                              const float* __restrict__ w1,
                                              const float* __restrict__ w2,
                                              const float* __restrict__ w3,
                                              unsigned short* __restrict__ o0,
                                              unsigned short* __restrict__ o1,
                                              unsigned short* __restrict__ o2,
                                              unsigned short* __restrict__ o3)
{
    int i = blockIdx.x * 256 + threadIdx.x;
    int reg = i >> 18, off = i & 262143;
    const float* src = (reg == 0) ? w0 : (reg == 1) ? w1 : (reg == 2) ? w2 : w3;
    unsigned short* dst = (reg == 0) ? o0 : (reg == 1) ? o1 : (reg == 2) ? o2 : o3;
    float4 x = ((const float4*)src)[off];
    ushort4 o;
    o.x = f2bf(x.x); o.y = f2bf(x.y); o.z = f2bf(x.z); o.w = f2bf(x.w);
    ((ushort4*)dst)[off] = o;
}

// ---------------------------------------------------------------------------
// C = A(M,K) @ B(N,K)^T + bias, m97 structure: 128x128 tile, BK=32, linear
// LDS [128][32], global_load_lds dwordx4 staging, 2-barrier K-loop.
// 1D grid 256, XCD-swizzled: each XCD owns 4 bm-rows x 8 bn-cols (3 MB < L2).
// MODE 0: bf16 out scattered to (B,H,L,D). MODE 1: f32 out (M,N).
// MODE 2: bf16 out scattered to (B,H,D,L)  (transposed V for PV frags).
// ---------------------------------------------------------------------------
template<int MODE>
__global__ __launch_bounds__(256) void gemm_dl(const unsigned short* __restrict__ A,
                                               const unsigned short* __restrict__ Bw,
                                               const float* __restrict__ bias,
                                               void* __restrict__ outp)
{
    const int K = 1024;
    __shared__ unsigned short sA[128][32];
    __shared__ unsigned short sB[128][32];
    int tid = threadIdx.x;
    int w = tid >> 6, lane = tid & 63;

    // XCD swizzle: lin&7 = xcd; each XCD gets bm in [xcd*4, xcd*4+4), all bn.
    int lin = blockIdx.x;
    int xcd = lin & 7, idx = lin >> 3;
    int bm = (xcd * 4 + (idx >> 3)) * 128;
    int bn = (idx & 7) * 128;

    int wr = (w >> 1) * 64, wc = (w & 1) * 64;
    int fr = lane & 15, fk = (lane >> 4) * 8;

    // staging: wave w owns rows [w*32, w*32+32) of each tile; one issue moves
    // 16 rows (64 lanes x 16 B), lane l -> row l>>2, bytes (l&3)*16.
    const unsigned short* Ag = A + (size_t)(bm + w * 32 + (lane >> 2)) * K + (lane & 3) * 8;
    const unsigned short* Bg = Bw + (size_t)(bn + w * 32 + (lane >> 2)) * K + (lane & 3) * 8;
    unsigned short* lA0 = &sA[w * 32][0];
    unsigned short* lA1 = &sA[w * 32 + 16][0];
    unsigned short* lB0 = &sB[w * 32][0];
    unsigned short* lB1 = &sB[w * 32 + 16][0];

    f32x4 acc[4][4];
#pragma unroll
    for (int i = 0; i < 4; ++i)
#pragma unroll
        for (int j = 0; j < 4; ++j) acc[i][j] = (f32x4){0.f, 0.f, 0.f, 0.f};

    for (int k0 = 0; k0 < K; k0 += 32) {
        __syncthreads();
        GLOAD_LDS16(Ag + k0,          lA0);
        GLOAD_LDS16(Ag + 16 * K + k0, lA1);
        GLOAD_LDS16(Bg + k0,          lB0);
        GLOAD_LDS16(Bg + 16 * K + k0, lB1);
        __syncthreads();
        bf16x8 af[4], bfv[4];
#pragma unroll
        for (int i = 0; i < 4; ++i) af[i]  = *(const bf16x8*)&sA[wr + i * 16 + fr][fk];
#pragma unroll
        for (int j = 0; j < 4; ++j) bfv[j] = *(const bf16x8*)&sB[wc + j * 16 + fr][fk];
#pragma unroll
        for (int i = 0; i < 4; ++i)
#pragma unroll
            for (int j = 0; j < 4; ++j)
                acc[i][j] = __builtin_amdgcn_mfma_f32_16x16x32_bf16(af[i], bfv[j], acc[i][j], 0, 0, 0);
    }

    int rb = (lane >> 4) * 4;
#pragma unroll
    for (int j = 0; j < 4; ++j) {
        int n = bn + wc + j * 16 + fr;
        float bia = bias[n];
#pragma unroll
        for (int i = 0; i < 4; ++i) {
#pragma unroll
            for (int r = 0; r < 4; ++r) {
                int m = bm + wr + i * 16 + rb + r;
                float v = acc[i][j][r] + bia;
                if (MODE == 0) {
                    int b = m >> 10, l = m & 1023, h = n >> 6, d = n & 63;
                    ((unsigned short*)outp)[(((size_t)(b * Hh + h)) * Lq + l) * Dd + d] = f2bf(v);
                } else if (MODE == 1) {
                    ((float*)outp)[(size_t)m * 1024 + n] = v;
                } else {
                    int b = m >> 10, l = m & 1023, h = n >> 6, d = n & 63;
                    ((unsigned short*)outp)[(((size_t)(b * Hh + h)) * Dd + d) * Lq + l] = f2bf(v);
                }
            }
        }
    }
}

// ---------------------------------------------------------------------------
// Pass C: flash attention, ILP edition (unchanged from round 5).
// ---------------------------------------------------------------------------
__global__ __launch_bounds__(256, 2) void attn_flash(const unsigned short* __restrict__ Qh,
                                                     const unsigned short* __restrict__ Kh,
                                                     const unsigned short* __restrict__ Vt,
                                                     const float* __restrict__ mbias,
                                                     unsigned short* __restrict__ ctx,
                                                     float* __restrict__ mstats,
                                                     float* __restrict__ lstats)
{
    __shared__ float sBias[1024];
    __shared__ unsigned short Wl[4][2][16][64];   // per-wave, per-tile P, swizzled

    int tid = threadIdx.x;
    int w = tid >> 6, lane = tid & 63;
    int fr = lane & 15, fg = lane >> 4;

    // XCD-colocation: all 8 qt-blocks of one (b,h) share an XCD.
    int lin = blockIdx.x;
    int xcd = lin & 7, jj = lin >> 3;          // jj in [0,64)
    int pair = xcd * 8 + (jj >> 3);            // 0..63 == h*4 + b
    int qt = jj & 7;
    int b = pair & 3, h = pair >> 2;

    int q0A = qt * 128 + w * 32;
    int q0B = q0A + 16;
    int swz = (fr & 7) << 2;                   // XOR on 4-byte-word index

    for (int i = tid; i < 1024; i += 256) sBias[i] = mbias[b * Lq + i];
    __syncthreads();

    const unsigned short* Qp = Qh + ((size_t)(b * Hh + h)) * Lq * Dd;
    const unsigned short* Kp = Kh + ((size_t)(b * Hh + h)) * Lq * Dd;
    const unsigned short* Vp = Vt + ((size_t)(b * Hh + h)) * Dd * Lq;

    bf16x8 qA0 = *(const bf16x8*)(Qp + (size_t)(q0A + fr) * Dd + fg * 8);
    bf16x8 qA1 = *(const bf16x8*)(Qp + (size_t)(q0A + fr) * Dd + 32 + fg * 8);
    bf16x8 qB0 = *(const bf16x8*)(Qp + (size_t)(q0B + fr) * Dd + fg * 8);
    bf16x8 qB1 = *(const bf16x8*)(Qp + (size_t)(q0B + fr) * Dd + 32 + fg * 8);

    f32x4 OA[4], OB[4];
#pragma unroll
    for (int dt = 0; dt < 4; ++dt) { OA[dt] = (f32x4){0.f,0.f,0.f,0.f}; OB[dt] = (f32x4){0.f,0.f,0.f,0.f}; }
    float mA = -INFINITY, lA = 0.f, mB = -INFINITY, lB = 0.f;

    bf16x8 kX0[4], kX1[4], kY0[4], kY1[4];
    bf16x8 vb0[4], vb1[4];

#define LOADK(K0, K1, KC) do {                                                   \
    _Pragma("unroll")                                                            \
    for (int kt = 0; kt < 4; ++kt) {                                             \
        K0[kt] = *(const bf16x8*)(Kp + (size_t)((KC) + kt * 16 + fr) * Dd + fg * 8);        \
        K1[kt] = *(const bf16x8*)(Kp + (size_t)((KC) + kt * 16 + fr) * Dd + 32 + fg * 8);   \
    }                                                                            \
} while (0)

#define LOADV(KC) do {                                                           \
    _Pragma("unroll")                                                            \
    for (int dt = 0; dt < 4; ++dt) {                                             \
        vb0[dt] = *(const bf16x8*)(Vp + (size_t)(dt * 16 + fr) * Lq + (KC) + fg * 8);       \
        vb1[dt] = *(const bf16x8*)(Vp + (size_t)(dt * 16 + fr) * Lq + (KC) + 32 + fg * 8);  \
    }                                                                            \
} while (0)

#define QK(S, K0, K1, B0, B1) do {                                               \
    _Pragma("unroll")                                                            \
    for (int kt = 0; kt < 4; ++kt) {                                             \
        S[kt] = __builtin_amdgcn_mfma_f32_16x16x32_bf16(K0[kt], B0, (f32x4){0.f,0.f,0.f,0.f}, 0, 0, 0); \
        S[kt] = __builtin_amdgcn_mfma_f32_16x16x32_bf16(K1[kt], B1, S[kt], 0, 0, 0); \
    }                                                                            \
} while (0)

// softmax + PV for one tile.  MT/LT/OT per-lane (q = fr).  TI = tile slot.
#define SMPV(S, MT, LT, OT, TI, KC) do {                                         \
    float v_[16];                                                                \
    float pmax = -INFINITY;                                                      \
    _Pragma("unroll")                                                            \
    for (int kt = 0; kt < 4; ++kt) {                                             \
        float4 bb = *(const float4*)&sBias[(KC) + kt * 16 + fg * 4];             \
        _Pragma("unroll")                                                        \
        for (int r = 0; r < 4; ++r) {                                            \
            float vv = S[kt][r] * 0.125f + (&bb.x)[r];                           \
            v_[kt * 4 + r] = vv;                                                 \
            pmax = fmaxf(pmax, vv);                                              \
        }                                                                        \
    }                                                                            \
    pmax = fmaxf(pmax, __shfl_xor(pmax, 16, 64));                                \
    pmax = fmaxf(pmax, __shfl_xor(pmax, 32, 64));                                \
    float mn = fmaxf(MT, pmax);                                                  \
    float sc = __expf(MT - mn);                                                  \
    float cs = 0.f;                                                              \
    _Pragma("unroll")                                                            \
    for (int i = 0; i < 16; ++i) { float e = __expf(v_[i] - mn); v_[i] = e; cs += e; } \
    cs += __shfl_xor(cs, 16, 64);                                                \
    cs += __shfl_xor(cs, 32, 64);                                                \
    LT = LT * sc + cs;                                                           \
    MT = mn;                                                                     \
    _Pragma("unroll")                                                            \
    for (int dt = 0; dt < 4; ++dt)                                               \
        _Pragma("unroll")                                                        \
        for (int r = 0; r < 4; ++r) OT[dt][r] *= sc;                             \
    _Pragma("unroll")                                                            \
    for (int kt = 0; kt < 4; ++kt) {                                             \
        unsigned w0 = pack2(v_[kt * 4 + 0], v_[kt * 4 + 1]);                     \
        unsigned w1 = pack2(v_[kt * 4 + 2], v_[kt * 4 + 3]);                     \
        uint2 pr; pr.x = w0; pr.y = w1;                                          \
        *(uint2*)&Wl[w][TI][fr][2 * ((kt * 8 + fg * 2) ^ swz)] = pr;             \
    }                                                                            \
    bf16x8 pa0 = *(const bf16x8*)&Wl[w][TI][fr][2 * ((fg * 4) ^ swz)];           \
    bf16x8 pa1 = *(const bf16x8*)&Wl[w][TI][fr][2 * ((16 + fg * 4) ^ swz)];      \
    _Pragma("unroll")                                                            \
    for (int dt = 0; dt < 4; ++dt) {                                             \
        OT[dt] = __builtin_amdgcn_mfma_f32_16x16x32_bf16(vb0[dt], pa0, OT[dt], 0, 0, 0); \
        OT[dt] = __builtin_amdgcn_mfma_f32_16x16x32_bf16(vb1[dt], pa1, OT[dt], 0, 0, 0); \
    }                                                                            \
} while (0)

    LOADK(kX0, kX1, 0);
#pragma unroll 1
    for (int c = 0; c < 16; c += 2) {
        f32x4 SA[4], SB[4];
        // ---- chunk c (K in X) ----
        QK(SA, kX0, kX1, qA0, qA1);
        QK(SB, kX0, kX1, qB0, qB1);
        LOADK(kY0, kY1, (c + 1) * 64);     // lands under softmax below
        LOADV(c * 64);                     // lands under softmax below
        SMPV(SA, mA, lA, OA, 0, c * 64);
        SMPV(SB, mB, lB, OB, 1, c * 64);
        // ---- chunk c+1 (K in Y) ----
        QK(SA, kY0, kY1, qA0, qA1);
        QK(SB, kY0, kY1, qB0, qB1);
        if (c + 2 < 16) LOADK(kX0, kX1, (c + 2) * 64);
        LOADV((c + 1) * 64);
        SMPV(SA, mA, lA, OA, 0, (c + 1) * 64);
        SMPV(SB, mB, lB, OB, 1, (c + 1) * 64);
    }
#undef LOADK
#undef LOADV
#undef QK
#undef SMPV

    float liA = 1.f / lA, liB = 1.f / lB;
#pragma unroll
    for (int dt = 0; dt < 4; ++dt) {
#pragma unroll
        for (int r = 0; r < 4; ++r) { OA[dt][r] *= liA; OB[dt][r] *= liB; }
    }
    // O^T layout: lane holds q = fr, d = dt*16 + fg*4 + r  (4 consecutive d)
#pragma unroll
    for (int dt = 0; dt < 4; ++dt) {
        uint2 pa; pa.x = pack2(OA[dt][0], OA[dt][1]); pa.y = pack2(OA[dt][2], OA[dt][3]);
        *(uint2*)(ctx + ((size_t)(b * Lq + q0A + fr)) * Emb + h * Dd + dt * 16 + fg * 4) = pa;
        uint2 pb; pb.x = pack2(OB[dt][0], OB[dt][1]); pb.y = pack2(OB[dt][2], OB[dt][3]);
        *(uint2*)(ctx + ((size_t)(b * Lq + q0B + fr)) * Emb + h * Dd + dt * 16 + fg * 4) = pb;
    }

    if (lane < 16) {
        mstats[(size_t)(b * Hh + h) * Lq + q0A + lane] = mA;
        lstats[(size_t)(b * Hh + h) * Lq + q0A + lane] = liA;
        mstats[(size_t)(b * Hh + h) * Lq + q0B + lane] = mB;
        lstats[(size_t)(b * Hh + h) * Lq + q0B + lane] = liB;
    }
}

// ---------------------------------------------------------------------------
// Pass B: out2 = mean_h softmax weights (unchanged from round 5).
// ---------------------------------------------------------------------------
__global__ __launch_bounds__(256) void attn_out2(const unsigned short* __restrict__ Qh,
                                                 const unsigned short* __restrict__ Kh,
                                                 const float* __restrict__ mbias,
                                                 const float* __restrict__ mstats,
                                                 const float* __restrict__ lstats,
                                                 float* __restrict__ out2)
{
    __shared__ float sM[16][32];
    __shared__ float sLi[16][32];
    int tid = threadIdx.x;
    int w = tid >> 6, lane = tid & 63;
    int fr = lane & 15, fg = lane >> 4;
    int q0 = blockIdx.x * 32;
    int kc = blockIdx.y * 128;
    int b  = blockIdx.z;

    for (int i = tid; i < 512; i += 256) {
        int h = i >> 5, qq = i & 31;
        sM[h][qq]  = mstats[(size_t)(b * Hh + h) * Lq + q0 + qq];
        sLi[h][qq] = lstats[(size_t)(b * Hh + h) * Lq + q0 + qq];
    }
    __syncthreads();

    float bias0 = mbias[b * Lq + kc + w * 32 + fr];
    float bias1 = mbias[b * Lq + kc + w * 32 + 16 + fr];

    float o2[2][2][4];
#pragma unroll
    for (int rt = 0; rt < 2; ++rt)
#pragma unroll
        for (int ct = 0; ct < 2; ++ct)
#pragma unroll
            for (int r = 0; r < 4; ++r) o2[rt][ct][r] = 0.f;

    for (int h = 0; h < Hh; ++h) {
        const unsigned short* Qp = Qh + ((size_t)(b * Hh + h)) * Lq * Dd;
        const unsigned short* Kp = Kh + ((size_t)(b * Hh + h)) * Lq * Dd;
        bf16x8 aq[2][2], bk[2][2];
#pragma unroll
        for (int rt = 0; rt < 2; ++rt)
#pragma unroll
            for (int ks = 0; ks < 2; ++ks)
                aq[rt][ks] = *(const bf16x8*)(Qp + (size_t)(q0 + rt * 16 + fr) * Dd + ks * 32 + fg * 8);
#pragma unroll
        for (int ct = 0; ct < 2; ++ct)
#pragma unroll
            for (int ks = 0; ks < 2; ++ks)
                bk[ct][ks] = *(const bf16x8*)(Kp + (size_t)(kc + w * 32 + ct * 16 + fr) * Dd + ks * 32 + fg * 8);
        float4 mrow[2], lirow[2];
#pragma unroll
        for (int rt = 0; rt < 2; ++rt) {
            mrow[rt]  = *(const float4*)&sM[h][rt * 16 + fg * 4];
            lirow[rt] = *(const float4*)&sLi[h][rt * 16 + fg * 4];
        }
#pragma unroll
        for (int rt = 0; rt < 2; ++rt)
#pragma unroll
            for (int ct = 0; ct < 2; ++ct) {
                f32x4 s = __builtin_amdgcn_mfma_f32_16x16x32_bf16(aq[rt][0], bk[ct][0], (f32x4){0.f, 0.f, 0.f, 0.f}, 0, 0, 0);
                s = __builtin_amdgcn_mfma_f32_16x16x32_bf16(aq[rt][1], bk[ct][1], s, 0, 0, 0);
                float bia = ct ? bias1 : bias0;
#pragma unroll
                for (int r = 0; r < 4; ++r)
                    o2[rt][ct][r] += __expf(s[r] * 0.125f + bia - mrow[rt][r]) * lirow[rt][r];
            }
    }

#pragma unroll
    for (int rt = 0; rt < 2; ++rt)
#pragma unroll
        for (int ct = 0; ct < 2; ++ct)
#pragma unroll
            for (int r = 0; r < 4; ++r)
                out2[((size_t)(b * Lq + q0 + rt * 16 + fg * 4 + r)) * Lq + kc + w * 32 + ct * 16 + fr]
                    = o2[rt][ct][r] * 0.0625f;
}

// ---------------------------------------------------------------------------
extern "C" void kernel_launch(void* const* d_in, const int* in_sizes, int n_in,
                              void* d_out, int out_size, void* d_ws, size_t ws_size,
                              hipStream_t stream)
{
    const float* query = (const float*)d_in[0];
    const float* key   = (const float*)d_in[1];
    const float* value = (const float*)d_in[2];
    const float* amask = (const float*)d_in[3];
    const int*   kpm   = (const int*)d_in[4];
    const float* Wq = (const float*)d_in[5];
    const float* bq = (const float*)d_in[6];
    const float* Wk = (const float*)d_in[7];
    const float* bk = (const float*)d_in[8];
    const float* Wv = (const float*)d_in[9];
    const float* bv = (const float*)d_in[10];
    const float* Wo = (const float*)d_in[11];
    const float* bo = (const float*)d_in[12];

    float* out1 = (float*)d_out;                       // (B,L,E) f32
    float* out2 = out1 + (size_t)Bsz * Lq * Emb;       // (B,L,L) f32

    const size_t MB = 1u << 20;
    char* ws = (char*)d_ws;
    unsigned short* qbf = (unsigned short*)(ws + 0 * MB);
    unsigned short* kbf = (unsigned short*)(ws + 8 * MB);
    unsigned short* vbf = (unsigned short*)(ws + 16 * MB);
    unsigned short* wqb = (unsigned short*)(ws + 24 * MB);
    unsigned short* wkb = (unsigned short*)(ws + 26 * MB);
    unsigned short* wvb = (unsigned short*)(ws + 28 * MB);
    unsigned short* wob = (unsigned short*)(ws + 30 * MB);
    unsigned short* QhB = (unsigned short*)(ws + 32 * MB);  // (B,H,L,D) bf16
    unsigned short* KhB = (unsigned short*)(ws + 40 * MB);
    unsigned short* VtB = (unsigned short*)(ws + 48 * MB);  // (B,H,D,L) bf16
    unsigned short* ctxB = (unsigned short*)(ws + 56 * MB); // (B,L,E) bf16
    float* mbias  = (float*)(ws + 64 * MB);                 // 16 KB
    // stats alias the qbf region (dead after the Q-projection GEMM)
    float* mstats = (float*)(ws + 0 * MB);                  // 256 KB
    float* lstats = (float*)(ws + 0 * MB + 256 * 1024);     // 256 KB

    bias_kernel<<<16, 256, 0, stream>>>(amask, kpm, mbias, Bsz * Lq);

    cvt_qkv<<<12288, 256, 0, stream>>>(query, key, value, qbf, kbf, vbf);
    cvt_w4<<<4096, 256, 0, stream>>>(Wq, Wk, Wv, Wo, wqb, wkb, wvb, wob);

    gemm_dl<0><<<256, 256, 0, stream>>>(qbf, wqb, bq, QhB);
    gemm_dl<0><<<256, 256, 0, stream>>>(kbf, wkb, bk, KhB);
    gemm_dl<2><<<256, 256, 0, stream>>>(vbf, wvb, bv, VtB);

    attn_flash<<<512, 256, 0, stream>>>(QhB, KhB, VtB, mbias, ctxB, mstats, lstats);
    attn_out2<<<dim3(32, 8, 4), 256, 0, stream>>>(QhB, KhB, mbias, mstats, lstats, out2);

    gemm_dl<1><<<256, 256, 0, stream>>>(ctxB, wob, bo, out1);
}

// Round 7
// 233.935 us; speedup vs baseline: 1.3689x; 1.0199x over previous
//
#include <hip/hip_runtime.h>
#include <math.h>

#define Bsz 4
#define Lq  1024
#define Emb 1024
#define Hh  16
#define Dd  64

typedef short bf16x8 __attribute__((ext_vector_type(8)));
typedef float f32x4 __attribute__((ext_vector_type(4)));

static __device__ __forceinline__ unsigned short f2bf(float f) {
    unsigned u = __float_as_uint(f);
    return (unsigned short)((u + 0x7FFFu + ((u >> 16) & 1u)) >> 16);
}
// pack two f32 -> two bf16 (round-half-up) in one v_perm
static __device__ __forceinline__ unsigned pack2(float lo, float hi) {
    return __builtin_amdgcn_perm(__float_as_uint(hi) + 0x8000u,
                                 __float_as_uint(lo) + 0x8000u, 0x07060302u);
}

// global -> LDS direct copy, 16 B per lane.  LDS dest wave-uniform; HW writes
// lane l's 16 B at lds + 16*l.
#define GLOAD_LDS16(gp, lp) __builtin_amdgcn_global_load_lds(                  \
    (const __attribute__((address_space(1))) void*)(gp),                       \
    (__attribute__((address_space(3))) void*)(lp), 16, 0, 0)

// ---------------------------------------------------------------------------
__global__ __launch_bounds__(256) void bias_kernel(const float* __restrict__ mask,
                                                   const int* __restrict__ kpm,
                                                   float* __restrict__ bias, int n)
{
    int i = blockIdx.x * 256 + threadIdx.x;
    if (i < n) {
        float b = 8.0f * logf(fmaxf(mask[i], 1e-6f));
        bias[i] = kpm[i] ? -INFINITY : b;
    }
}

// ---------------------------------------------------------------------------
__global__ __launch_bounds__(256) void cvt_qkv(const float* __restrict__ q,
                                               const float* __restrict__ k,
                                               const float* __restrict__ v,
                                               unsigned short* __restrict__ qo,
                                               unsigned short* __restrict__ ko,
                                               unsigned short* __restrict__ vo)
{
    int i = blockIdx.x * 256 + threadIdx.x;
    const float* src; unsigned short* dst; int off;
    if (i < 1048576)      { src = q; dst = qo; off = i; }
    else if (i < 2097152) { src = k; dst = ko; off = i - 1048576; }
    else                  { src = v; dst = vo; off = i - 2097152; }
    float4 x = ((const float4*)src)[off];
    ushort4 o;
    o.x = f2bf(x.x); o.y = f2bf(x.y); o.z = f2bf(x.z); o.w = f2bf(x.w);
    ((ushort4*)dst)[off] = o;
}

__global__ __launch_bounds__(256) void cvt_w4(const float* __restrict__ w0,
                                              const float* __restrict__ w1,
                                              const float* __restrict__ w2,
                                              const float* __restrict__ w3,
                                              unsigned short* __restrict__ o0,
                                              unsigned short* __restrict__ o1,
                                              unsigned short* __restrict__ o2,
                                              unsigned short* __restrict__ o3)
{
    int i = blockIdx.x * 256 + threadIdx.x;
    int reg = i >> 18, off = i & 262143;
    const float* src = (reg == 0) ? w0 : (reg == 1) ? w1 : (reg == 2) ? w2 : w3;
    unsigned short* dst = (reg == 0) ? o0 : (reg == 1) ? o1 : (reg == 2) ? o2 : o3;
    float4 x = ((const float4*)src)[off];
    ushort4 o;
    o.x = f2bf(x.x); o.y = f2bf(x.y); o.z = f2bf(x.z); o.w = f2bf(x.w);
    ((ushort4*)dst)[off] = o;
}

// ---------------------------------------------------------------------------
// Fused Q/K/V projections.  which = bid>>9 selects {Q,K,V}; 512 blocks each,
// 64x128 tile, BK=32, global_load_lds staging, 2 blocks/CU when one `which`
// is active.  XCD swizzle: each XCD owns 8 bm x 8 bn (A 1MB + W 2MB < L2).
// Q,K write (B,H,L,D) bf16; V writes (B,H,D,L) bf16 (transposed for PV).
// ---------------------------------------------------------------------------
__global__ __launch_bounds__(256) void gemm_qkv(const unsigned short* __restrict__ Aq,
                                                const unsigned short* __restrict__ Ak,
                                                const unsigned short* __restrict__ Av,
                                                const unsigned short* __restrict__ Wq,
                                                const unsigned short* __restrict__ Wk,
                                                const unsigned short* __restrict__ Wv,
                                                const float* __restrict__ biq,
                                                const float* __restrict__ bik,
                                                const float* __restrict__ biv,
                                                unsigned short* __restrict__ Oq,
                                                unsigned short* __restrict__ Ok,
                                                unsigned short* __restrict__ Ov)
{
    const int K = 1024;
    __shared__ unsigned short sA[64][32];
    __shared__ unsigned short sB[128][32];
    int tid = threadIdx.x;
    int w = tid >> 6, lane = tid & 63;

    int bid = blockIdx.x;
    int which = bid >> 9;              // 0=Q 1=K 2=V
    int lin = bid & 511;
    int xcd = lin & 7, idx = lin >> 3; // idx in [0,64)
    int bm = (xcd * 8 + (idx >> 3)) * 64;
    int bn = (idx & 7) * 128;

    const unsigned short* A = (which == 0) ? Aq : (which == 1) ? Ak : Av;
    const unsigned short* Bw = (which == 0) ? Wq : (which == 1) ? Wk : Wv;
    const float* bias = (which == 0) ? biq : (which == 1) ? bik : biv;
    unsigned short* outp = (which == 0) ? Oq : (which == 1) ? Ok : Ov;

    int wr = (w >> 1) * 32, wc = (w & 1) * 64;
    int fr = lane & 15, fk = (lane >> 4) * 8;

    // staging: A wave w -> rows [w*16,w*16+16) (1 issue); B rows [w*32,+32) (2)
    const unsigned short* Ag = A + (size_t)(bm + w * 16 + (lane >> 2)) * K + (lane & 3) * 8;
    const unsigned short* Bg = Bw + (size_t)(bn + w * 32 + (lane >> 2)) * K + (lane & 3) * 8;
    unsigned short* lA0 = &sA[w * 16][0];
    unsigned short* lB0 = &sB[w * 32][0];
    unsigned short* lB1 = &sB[w * 32 + 16][0];

    f32x4 acc[2][4];
#pragma unroll
    for (int i = 0; i < 2; ++i)
#pragma unroll
        for (int j = 0; j < 4; ++j) acc[i][j] = (f32x4){0.f, 0.f, 0.f, 0.f};

    for (int k0 = 0; k0 < K; k0 += 32) {
        __syncthreads();
        GLOAD_LDS16(Ag + k0,          lA0);
        GLOAD_LDS16(Bg + k0,          lB0);
        GLOAD_LDS16(Bg + 16 * K + k0, lB1);
        __syncthreads();
        bf16x8 af[2], bfv[4];
#pragma unroll
        for (int i = 0; i < 2; ++i) af[i]  = *(const bf16x8*)&sA[wr + i * 16 + fr][fk];
#pragma unroll
        for (int j = 0; j < 4; ++j) bfv[j] = *(const bf16x8*)&sB[wc + j * 16 + fr][fk];
#pragma unroll
        for (int i = 0; i < 2; ++i)
#pragma unroll
            for (int j = 0; j < 4; ++j)
                acc[i][j] = __builtin_amdgcn_mfma_f32_16x16x32_bf16(af[i], bfv[j], acc[i][j], 0, 0, 0);
    }

    int rb = (lane >> 4) * 4;
#pragma unroll
    for (int j = 0; j < 4; ++j) {
        int n = bn + wc + j * 16 + fr;
        float bia = bias[n];
#pragma unroll
        for (int i = 0; i < 2; ++i) {
#pragma unroll
            for (int r = 0; r < 4; ++r) {
                int m = bm + wr + i * 16 + rb + r;
                float v = acc[i][j][r] + bia;
                int b = m >> 10, l = m & 1023, h = n >> 6, d = n & 63;
                if (which == 2)
                    outp[(((size_t)(b * Hh + h)) * Dd + d) * Lq + l] = f2bf(v);
                else
                    outp[(((size_t)(b * Hh + h)) * Lq + l) * Dd + d] = f2bf(v);
            }
        }
    }
}

// ---------------------------------------------------------------------------
// Output projection: C = ctx(4096,1024) @ Wo^T + bo, f32 out (M,N).
// 64x128 tile, grid 512 (2 blocks/CU), same staging structure.
// ---------------------------------------------------------------------------
__global__ __launch_bounds__(256) void gemm_o(const unsigned short* __restrict__ A,
                                              const unsigned short* __restrict__ Bw,
                                              const float* __restrict__ bias,
                                              float* __restrict__ outp)
{
    const int K = 1024;
    __shared__ unsigned short sA[64][32];
    __shared__ unsigned short sB[128][32];
    int tid = threadIdx.x;
    int w = tid >> 6, lane = tid & 63;

    int lin = blockIdx.x;
    int xcd = lin & 7, idx = lin >> 3;
    int bm = (xcd * 8 + (idx >> 3)) * 64;
    int bn = (idx & 7) * 128;

    int wr = (w >> 1) * 32, wc = (w & 1) * 64;
    int fr = lane & 15, fk = (lane >> 4) * 8;

    const unsigned short* Ag = A + (size_t)(bm + w * 16 + (lane >> 2)) * K + (lane & 3) * 8;
    const unsigned short* Bg = Bw + (size_t)(bn + w * 32 + (lane >> 2)) * K + (lane & 3) * 8;
    unsigned short* lA0 = &sA[w * 16][0];
    unsigned short* lB0 = &sB[w * 32][0];
    unsigned short* lB1 = &sB[w * 32 + 16][0];

    f32x4 acc[2][4];
#pragma unroll
    for (int i = 0; i < 2; ++i)
#pragma unroll
        for (int j = 0; j < 4; ++j) acc[i][j] = (f32x4){0.f, 0.f, 0.f, 0.f};

    for (int k0 = 0; k0 < K; k0 += 32) {
        __syncthreads();
        GLOAD_LDS16(Ag + k0,          lA0);
        GLOAD_LDS16(Bg + k0,          lB0);
        GLOAD_LDS16(Bg + 16 * K + k0, lB1);
        __syncthreads();
        bf16x8 af[2], bfv[4];
#pragma unroll
        for (int i = 0; i < 2; ++i) af[i]  = *(const bf16x8*)&sA[wr + i * 16 + fr][fk];
#pragma unroll
        for (int j = 0; j < 4; ++j) bfv[j] = *(const bf16x8*)&sB[wc + j * 16 + fr][fk];
#pragma unroll
        for (int i = 0; i < 2; ++i)
#pragma unroll
            for (int j = 0; j < 4; ++j)
                acc[i][j] = __builtin_amdgcn_mfma_f32_16x16x32_bf16(af[i], bfv[j], acc[i][j], 0, 0, 0);
    }

    int rb = (lane >> 4) * 4;
#pragma unroll
    for (int j = 0; j < 4; ++j) {
        int n = bn + wc + j * 16 + fr;
        float bia = bias[n];
#pragma unroll
        for (int i = 0; i < 2; ++i)
#pragma unroll
            for (int r = 0; r < 4; ++r) {
                int m = bm + wr + i * 16 + rb + r;
                outp[(size_t)m * 1024 + n] = acc[i][j][r] + bia;
            }
    }
}

// ---------------------------------------------------------------------------
// Pass C: flash attention, split-K x2.  Grid 1024: s = bid>>9 selects k-range
// [s*512, s*512+512); rest decoded XCD-colocated per (b,h).  Emits RAW
// partials (O f32 un-normalized, m, l) -- combine pass merges.
// ---------------------------------------------------------------------------
__global__ __launch_bounds__(256, 2) void attn_flash(const unsigned short* __restrict__ Qh,
                                                     const unsigned short* __restrict__ Kh,
                                                     const unsigned short* __restrict__ Vt,
                                                     const float* __restrict__ mbias,
                                                     float* __restrict__ pO0,
                                                     float* __restrict__ pO1,
                                                     float* __restrict__ mp0,
                                                     float* __restrict__ lp0,
                                                     float* __restrict__ mp1,
                                                     float* __restrict__ lp1)
{
    __shared__ float sBias[1024];
    __shared__ unsigned short Wl[4][2][16][64];   // per-wave, per-tile P, swizzled

    int tid = threadIdx.x;
    int w = tid >> 6, lane = tid & 63;
    int fr = lane & 15, fg = lane >> 4;

    int lin = blockIdx.x;
    int s = lin >> 9;                   // k-split
    int rest = lin & 511;
    int xcd = rest & 7, jj = rest >> 3; // jj in [0,64)
    int pair = xcd * 8 + (jj >> 3);     // 0..63 == h*4 + b
    int qt = jj & 7;
    int b = pair & 3, h = pair >> 2;
    int c0 = s * 8;

    float* pO = s ? pO1 : pO0;
    float* mp = s ? mp1 : mp0;
    float* lp = s ? lp1 : lp0;

    int q0A = qt * 128 + w * 32;
    int q0B = q0A + 16;
    int swz = (fr & 7) << 2;            // XOR on 4-byte-word index

    for (int i = tid; i < 1024; i += 256) sBias[i] = mbias[b * Lq + i];
    __syncthreads();

    const unsigned short* Qp = Qh + ((size_t)(b * Hh + h)) * Lq * Dd;
    const unsigned short* Kp = Kh + ((size_t)(b * Hh + h)) * Lq * Dd;
    const unsigned short* Vp = Vt + ((size_t)(b * Hh + h)) * Dd * Lq;

    bf16x8 qA0 = *(const bf16x8*)(Qp + (size_t)(q0A + fr) * Dd + fg * 8);
    bf16x8 qA1 = *(const bf16x8*)(Qp + (size_t)(q0A + fr) * Dd + 32 + fg * 8);
    bf16x8 qB0 = *(const bf16x8*)(Qp + (size_t)(q0B + fr) * Dd + fg * 8);
    bf16x8 qB1 = *(const bf16x8*)(Qp + (size_t)(q0B + fr) * Dd + 32 + fg * 8);

    f32x4 OA[4], OB[4];
#pragma unroll
    for (int dt = 0; dt < 4; ++dt) { OA[dt] = (f32x4){0.f,0.f,0.f,0.f}; OB[dt] = (f32x4){0.f,0.f,0.f,0.f}; }
    float mA = -INFINITY, lA = 0.f, mB = -INFINITY, lB = 0.f;

    bf16x8 kX0[4], kX1[4], kY0[4], kY1[4];
    bf16x8 vb0[4], vb1[4];

#define LOADK(K0, K1, KC) do {                                                   \
    _Pragma("unroll")                                                            \
    for (int kt = 0; kt < 4; ++kt) {                                             \
        K0[kt] = *(const bf16x8*)(Kp + (size_t)((KC) + kt * 16 + fr) * Dd + fg * 8);        \
        K1[kt] = *(const bf16x8*)(Kp + (size_t)((KC) + kt * 16 + fr) * Dd + 32 + fg * 8);   \
    }                                                                            \
} while (0)

#define LOADV(KC) do {                                                           \
    _Pragma("unroll")                                                            \
    for (int dt = 0; dt < 4; ++dt) {                                             \
        vb0[dt] = *(const bf16x8*)(Vp + (size_t)(dt * 16 + fr) * Lq + (KC) + fg * 8);       \
        vb1[dt] = *(const bf16x8*)(Vp + (size_t)(dt * 16 + fr) * Lq + (KC) + 32 + fg * 8);  \
    }                                                                            \
} while (0)

#define QK(S, K0, K1, B0, B1) do {                                               \
    _Pragma("unroll")                                                            \
    for (int kt = 0; kt < 4; ++kt) {                                             \
        S[kt] = __builtin_amdgcn_mfma_f32_16x16x32_bf16(K0[kt], B0, (f32x4){0.f,0.f,0.f,0.f}, 0, 0, 0); \
        S[kt] = __builtin_amdgcn_mfma_f32_16x16x32_bf16(K1[kt], B1, S[kt], 0, 0, 0); \
    }                                                                            \
} while (0)

#define SMPV(S, MT, LT, OT, TI, KC) do {                                         \
    float v_[16];                                                                \
    float pmax = -INFINITY;                                                      \
    _Pragma("unroll")                                                            \
    for (int kt = 0; kt < 4; ++kt) {                                             \
        float4 bb = *(const float4*)&sBias[(KC) + kt * 16 + fg * 4];             \
        _Pragma("unroll")                                                        \
        for (int r = 0; r < 4; ++r) {                                            \
            float vv = S[kt][r] * 0.125f + (&bb.x)[r];                           \
            v_[kt * 4 + r] = vv;                                                 \
            pmax = fmaxf(pmax, vv);                                              \
        }                                                                        \
    }                                                                            \
    pmax = fmaxf(pmax, __shfl_xor(pmax, 16, 64));                                \
    pmax = fmaxf(pmax, __shfl_xor(pmax, 32, 64));                                \
    float mn = fmaxf(MT, pmax);                                                  \
    float sc = __expf(MT - mn);                                                  \
    float cs = 0.f;                                                              \
    _Pragma("unroll")                                                            \
    for (int i = 0; i < 16; ++i) { float e = __expf(v_[i] - mn); v_[i] = e; cs += e; } \
    cs += __shfl_xor(cs, 16, 64);                                                \
    cs += __shfl_xor(cs, 32, 64);                                                \
    LT = LT * sc + cs;                                                           \
    MT = mn;                                                                     \
    _Pragma("unroll")                                                            \
    for (int dt = 0; dt < 4; ++dt)                                               \
        _Pragma("unroll")                                                        \
        for (int r = 0; r < 4; ++r) OT[dt][r] *= sc;                             \
    _Pragma("unroll")                                                            \
    for (int kt = 0; kt < 4; ++kt) {                                             \
        unsigned w0 = pack2(v_[kt * 4 + 0], v_[kt * 4 + 1]);                     \
        unsigned w1 = pack2(v_[kt * 4 + 2], v_[kt * 4 + 3]);                     \
        uint2 pr; pr.x = w0; pr.y = w1;                                          \
        *(uint2*)&Wl[w][TI][fr][2 * ((kt * 8 + fg * 2) ^ swz)] = pr;             \
    }                                                                            \
    bf16x8 pa0 = *(const bf16x8*)&Wl[w][TI][fr][2 * ((fg * 4) ^ swz)];           \
    bf16x8 pa1 = *(const bf16x8*)&Wl[w][TI][fr][2 * ((16 + fg * 4) ^ swz)];      \
    _Pragma("unroll")                                                            \
    for (int dt = 0; dt < 4; ++dt) {                                             \
        OT[dt] = __builtin_amdgcn_mfma_f32_16x16x32_bf16(vb0[dt], pa0, OT[dt], 0, 0, 0); \
        OT[dt] = __builtin_amdgcn_mfma_f32_16x16x32_bf16(vb1[dt], pa1, OT[dt], 0, 0, 0); \
    }                                                                            \
} while (0)

    LOADK(kX0, kX1, c0 * 64);
#pragma unroll 1
    for (int c = c0; c < c0 + 8; c += 2) {
        f32x4 SA[4], SB[4];
        QK(SA, kX0, kX1, qA0, qA1);
        QK(SB, kX0, kX1, qB0, qB1);
        LOADK(kY0, kY1, (c + 1) * 64);
        LOADV(c * 64);
        SMPV(SA, mA, lA, OA, 0, c * 64);
        SMPV(SB, mB, lB, OB, 1, c * 64);
        QK(SA, kY0, kY1, qA0, qA1);
        QK(SB, kY0, kY1, qB0, qB1);
        if (c + 2 < c0 + 8) LOADK(kX0, kX1, (c + 2) * 64);
        LOADV((c + 1) * 64);
        SMPV(SA, mA, lA, OA, 0, (c + 1) * 64);
        SMPV(SB, mB, lB, OB, 1, (c + 1) * 64);
    }
#undef LOADK
#undef LOADV
#undef QK
#undef SMPV

    // ---- raw partial O (f32), q = fr, d = dt*16 + fg*4 + r ----
    size_t bh1024 = (size_t)(b * Hh + h) * Lq;
#pragma unroll
    for (int dt = 0; dt < 4; ++dt) {
        *(f32x4*)(pO + (bh1024 + q0A + fr) * 64 + dt * 16 + fg * 4) = OA[dt];
        *(f32x4*)(pO + (bh1024 + q0B + fr) * 64 + dt * 16 + fg * 4) = OB[dt];
    }
    if (lane < 16) {
        mp[bh1024 + q0A + lane] = mA;
        lp[bh1024 + q0A + lane] = lA;
        mp[bh1024 + q0B + lane] = mB;
        lp[bh1024 + q0B + lane] = lB;
    }
}

// ---------------------------------------------------------------------------
// Combine: merge the two k-split partials; write ctx (bf16) and final stats.
// Elementwise over 4M (row,d): row = (b*16+h)*1024 + q.
// ---------------------------------------------------------------------------
__global__ __launch_bounds__(256) void attn_combine(const float* __restrict__ pO0,
                                                    const float* __restrict__ pO1,
                                                    const float* __restrict__ mp0,
                                                    const float* __restrict__ lp0,
                                                    const float* __restrict__ mp1,
                                                    const float* __restrict__ lp1,
                                                    unsigned short* __restrict__ ctx,
                                                    float* __restrict__ mstats,
                                                    float* __restrict__ lstats)
{
    int t = blockIdx.x * 256 + threadIdx.x;   // over 4M
    int row = t >> 6, d = t & 63;
    float m0 = mp0[row], m1 = mp1[row];
    float l0 = lp0[row], l1 = lp1[row];
    float m = fmaxf(m0, m1);
    float w0 = __expf(m0 - m), w1 = __expf(m1 - m);
    float li = 1.f / (l0 * w0 + l1 * w1);
    float o = (pO0[t] * w0 + pO1[t] * w1) * li;
    int q = row & 1023, bh = row >> 10;
    int b = bh >> 4, h = bh & 15;
    ctx[((size_t)(b * Lq + q)) * Emb + h * Dd + d] = f2bf(o);
    if (d == 0) { mstats[row] = m; lstats[row] = li; }
}

// ---------------------------------------------------------------------------
// Pass B: out2 = mean_h softmax weights; per-head Q/K frags double-buffered.
// ---------------------------------------------------------------------------
__global__ __launch_bounds__(256) void attn_out2(const unsigned short* __restrict__ Qh,
                                                 const unsigned short* __restrict__ Kh,
                                                 const float* __restrict__ mbias,
                                                 const float* __restrict__ mstats,
                                                 const float* __restrict__ lstats,
                                                 float* __restrict__ out2)
{
    __shared__ float sM[16][32];
    __shared__ float sLi[16][32];
    int tid = threadIdx.x;
    int w = tid >> 6, lane = tid & 63;
    int fr = lane & 15, fg = lane >> 4;
    int q0 = blockIdx.x * 32;
    int kc = blockIdx.y * 128;
    int b  = blockIdx.z;

    for (int i = tid; i < 512; i += 256) {
        int h = i >> 5, qq = i & 31;
        sM[h][qq]  = mstats[(size_t)(b * Hh + h) * Lq + q0 + qq];
        sLi[h][qq] = lstats[(size_t)(b * Hh + h) * Lq + q0 + qq];
    }
    __syncthreads();

    float bias0 = mbias[b * Lq + kc + w * 32 + fr];
    float bias1 = mbias[b * Lq + kc + w * 32 + 16 + fr];

    float o2[2][2][4];
#pragma unroll
    for (int rt = 0; rt < 2; ++rt)
#pragma unroll
        for (int ct = 0; ct < 2; ++ct)
#pragma unroll
            for (int r = 0; r < 4; ++r) o2[rt][ct][r] = 0.f;

    bf16x8 aqA[2][2], bkA[2][2], aqB[2][2], bkB[2][2];

#define LOADH(AQ, BKk, H) do {                                                   \
    const unsigned short* Qp_ = Qh + ((size_t)(b * Hh + (H))) * Lq * Dd;         \
    const unsigned short* Kp_ = Kh + ((size_t)(b * Hh + (H))) * Lq * Dd;         \
    _Pragma("unroll")                                                            \
    for (int rt = 0; rt < 2; ++rt)                                               \
        _Pragma("unroll")                                                        \
        for (int ks = 0; ks < 2; ++ks)                                           \
            AQ[rt][ks] = *(const bf16x8*)(Qp_ + (size_t)(q0 + rt * 16 + fr) * Dd + ks * 32 + fg * 8); \
    _Pragma("unroll")                                                            \
    for (int ct = 0; ct < 2; ++ct)                                               \
        _Pragma("unroll")                                                        \
        for (int ks = 0; ks < 2; ++ks)                                           \
            BKk[ct][ks] = *(const bf16x8*)(Kp_ + (size_t)(kc + w * 32 + ct * 16 + fr) * Dd + ks * 32 + fg * 8); \
} while (0)

#define COMPH(AQ, BKk, H) do {                                                   \
    float4 mrow[2], lirow[2];                                                    \
    _Pragma("unroll")                                                            \
    for (int rt = 0; rt < 2; ++rt) {                                             \
        mrow[rt]  = *(const float4*)&sM[(H)][rt * 16 + fg * 4];                  \
        lirow[rt] = *(const float4*)&sLi[(H)][rt * 16 + fg * 4];                 \
    }                                                                            \
    _Pragma("unroll")                                                            \
    for (int rt = 0; rt < 2; ++rt)                                               \
        _Pragma("unroll")                                                        \
        for (int ct = 0; ct < 2; ++ct) {                                         \
            f32x4 s_ = __builtin_amdgcn_mfma_f32_16x16x32_bf16(AQ[rt][0], BKk[ct][0], (f32x4){0.f,0.f,0.f,0.f}, 0, 0, 0); \
            s_ = __builtin_amdgcn_mfma_f32_16x16x32_bf16(AQ[rt][1], BKk[ct][1], s_, 0, 0, 0); \
            float bia = ct ? bias1 : bias0;                                      \
            _Pragma("unroll")                                                    \
            for (int r = 0; r < 4; ++r)                                          \
                o2[rt][ct][r] += __expf(s_[r] * 0.125f + bia - mrow[rt][r]) * lirow[rt][r]; \
        }                                                                        \
} while (0)

    LOADH(aqA, bkA, 0);
#pragma unroll 1
    for (int h = 0; h < Hh; h += 2) {
        LOADH(aqB, bkB, h + 1);
        COMPH(aqA, bkA, h);
        if (h + 2 < Hh) LOADH(aqA, bkA, h + 2);
        COMPH(aqB, bkB, h + 1);
    }
#undef LOADH
#undef COMPH

#pragma unroll
    for (int rt = 0; rt < 2; ++rt)
#pragma unroll
        for (int ct = 0; ct < 2; ++ct)
#pragma unroll
            for (int r = 0; r < 4; ++r)
                out2[((size_t)(b * Lq + q0 + rt * 16 + fg * 4 + r)) * Lq + kc + w * 32 + ct * 16 + fr]
                    = o2[rt][ct][r] * 0.0625f;
}

// ---------------------------------------------------------------------------
extern "C" void kernel_launch(void* const* d_in, const int* in_sizes, int n_in,
                              void* d_out, int out_size, void* d_ws, size_t ws_size,
                              hipStream_t stream)
{
    const float* query = (const float*)d_in[0];
    const float* key   = (const float*)d_in[1];
    const float* value = (const float*)d_in[2];
    const float* amask = (const float*)d_in[3];
    const int*   kpm   = (const int*)d_in[4];
    const float* Wq = (const float*)d_in[5];
    const float* bq = (const float*)d_in[6];
    const float* Wk = (const float*)d_in[7];
    const float* bk = (const float*)d_in[8];
    const float* Wv = (const float*)d_in[9];
    const float* bv = (const float*)d_in[10];
    const float* Wo = (const float*)d_in[11];
    const float* bo = (const float*)d_in[12];

    float* out1 = (float*)d_out;                       // (B,L,E) f32
    float* out2 = out1 + (size_t)Bsz * Lq * Emb;       // (B,L,L) f32

    const size_t MB = 1u << 20;
    char* ws = (char*)d_ws;
    unsigned short* qbf = (unsigned short*)(ws + 0 * MB);
    unsigned short* kbf = (unsigned short*)(ws + 8 * MB);
    unsigned short* vbf = (unsigned short*)(ws + 16 * MB);
    unsigned short* wqb = (unsigned short*)(ws + 24 * MB);
    unsigned short* wkb = (unsigned short*)(ws + 26 * MB);
    unsigned short* wvb = (unsigned short*)(ws + 28 * MB);
    unsigned short* wob = (unsigned short*)(ws + 30 * MB);
    unsigned short* QhB = (unsigned short*)(ws + 32 * MB);  // (B,H,L,D) bf16
    unsigned short* KhB = (unsigned short*)(ws + 40 * MB);
    unsigned short* VtB = (unsigned short*)(ws + 48 * MB);  // (B,H,D,L) bf16
    unsigned short* ctxB = (unsigned short*)(ws + 56 * MB); // (B,L,E) bf16
    float* mbias  = (float*)(ws + 64 * MB);                 // 16 KB

    // flash scratch (regions dead by the time flash runs):
    float* pO0 = (float*)(ws + 0 * MB);                 // 16 MB over qbf/kbf
    float* pO1 = out2;                                  // 16 MB, d_out scratch
    float* mp0 = (float*)(ws + 16 * MB);                // 256 KB (vbf region)
    float* lp0 = (float*)(ws + 16 * MB + 256 * 1024);
    float* mp1 = (float*)(ws + 16 * MB + 512 * 1024);
    float* lp1 = (float*)(ws + 16 * MB + 768 * 1024);
    float* mstats = (float*)(ws + 17 * MB);             // 256 KB
    float* lstats = (float*)(ws + 17 * MB + 256 * 1024);

    bias_kernel<<<16, 256, 0, stream>>>(amask, kpm, mbias, Bsz * Lq);

    cvt_qkv<<<12288, 256, 0, stream>>>(query, key, value, qbf, kbf, vbf);
    cvt_w4<<<4096, 256, 0, stream>>>(Wq, Wk, Wv, Wo, wqb, wkb, wvb, wob);

    gemm_qkv<<<1536, 256, 0, stream>>>(qbf, kbf, vbf, wqb, wkb, wvb,
                                       bq, bk, bv, QhB, KhB, VtB);

    attn_flash<<<1024, 256, 0, stream>>>(QhB, KhB, VtB, mbias,
                                         pO0, pO1, mp0, lp0, mp1, lp1);
    attn_combine<<<16384, 256, 0, stream>>>(pO0, pO1, mp0, lp0, mp1, lp1,
                                            ctxB, mstats, lstats);
    attn_out2<<<dim3(32, 8, 4), 256, 0, stream>>>(QhB, KhB, mbias, mstats, lstats, out2);

    gemm_o<<<512, 256, 0, stream>>>(ctxB, wob, bo, out1);
}

// Round 9
// 223.390 us; speedup vs baseline: 1.4335x; 1.0472x over previous
//
#include <hip/hip_runtime.h>
#include <math.h>

#define Bsz 4
#define Lq  1024
#define Emb 1024
#define Hh  16
#define Dd  64

typedef short bf16x8 __attribute__((ext_vector_type(8)));
typedef float f32x4 __attribute__((ext_vector_type(4)));

static __device__ __forceinline__ unsigned short f2bf(float f) {
    unsigned u = __float_as_uint(f);
    return (unsigned short)((u + 0x7FFFu + ((u >> 16) & 1u)) >> 16);
}
// pack two f32 -> two bf16 (round-half-up) in one v_perm
static __device__ __forceinline__ unsigned pack2(float lo, float hi) {
    return __builtin_amdgcn_perm(__float_as_uint(hi) + 0x8000u,
                                 __float_as_uint(lo) + 0x8000u, 0x07060302u);
}

// cross-fg reduces (lanes {l, l^16, l^32, l^48}); proven-correct shfl form.
static __device__ __forceinline__ float cross_max(float x) {
    x = fmaxf(x, __shfl_xor(x, 16, 64));
    x = fmaxf(x, __shfl_xor(x, 32, 64));
    return x;
}
static __device__ __forceinline__ float cross_sum(float x) {
    x += __shfl_xor(x, 16, 64);
    x += __shfl_xor(x, 32, 64);
    return x;
}

// global -> LDS direct copy, 16 B per lane.
#define GLOAD_LDS16(gp, lp) __builtin_amdgcn_global_load_lds(                  \
    (const __attribute__((address_space(1))) void*)(gp),                       \
    (__attribute__((address_space(3))) void*)(lp), 16, 0, 0)

// ---------------------------------------------------------------------------
__global__ __launch_bounds__(256) void bias_kernel(const float* __restrict__ mask,
                                                   const int* __restrict__ kpm,
                                                   float* __restrict__ bias, int n)
{
    int i = blockIdx.x * 256 + threadIdx.x;
    if (i < n) {
        float b = 8.0f * logf(fmaxf(mask[i], 1e-6f));
        bias[i] = kpm[i] ? -INFINITY : b;
    }
}

// ---------------------------------------------------------------------------
__global__ __launch_bounds__(256) void cvt_qkv(const float* __restrict__ q,
                                               const float* __restrict__ k,
                                               const float* __restrict__ v,
                                               unsigned short* __restrict__ qo,
                                               unsigned short* __restrict__ ko,
                                               unsigned short* __restrict__ vo)
{
    int i = blockIdx.x * 256 + threadIdx.x;
    const float* src; unsigned short* dst; int off;
    if (i < 1048576)      { src = q; dst = qo; off = i; }
    else if (i < 2097152) { src = k; dst = ko; off = i - 1048576; }
    else                  { src = v; dst = vo; off = i - 2097152; }
    float4 x = ((const float4*)src)[off];
    ushort4 o;
    o.x = f2bf(x.x); o.y = f2bf(x.y); o.z = f2bf(x.z); o.w = f2bf(x.w);
    ((ushort4*)dst)[off] = o;
}

__global__ __launch_bounds__(256) void cvt_w4(const float* __restrict__ w0,
                                              const float* __restrict__ w1,
                                              const float* __restrict__ w2,
                                              const float* __restrict__ w3,
                                              unsigned short* __restrict__ o0,
                                              unsigned short* __restrict__ o1,
                                              unsigned short* __restrict__ o2,
                                              unsigned short* __restrict__ o3)
{
    int i = blockIdx.x * 256 + threadIdx.x;
    int reg = i >> 18, off = i & 262143;
    const float* src = (reg == 0) ? w0 : (reg == 1) ? w1 : (reg == 2) ? w2 : w3;
    unsigned short* dst = (reg == 0) ? o0 : (reg == 1) ? o1 : (reg == 2) ? o2 : o3;
    float4 x = ((const float4*)src)[off];
    ushort4 o;
    o.x = f2bf(x.x); o.y = f2bf(x.y); o.z = f2bf(x.z); o.w = f2bf(x.w);
    ((ushort4*)dst)[off] = o;
}

// ---------------------------------------------------------------------------
// Fused Q/K/V projections (unchanged).
// ---------------------------------------------------------------------------
__global__ __launch_bounds__(256) void gemm_qkv(const unsigned short* __restrict__ Aq,
                                                const unsigned short* __restrict__ Ak,
                                                const unsigned short* __restrict__ Av,
                                                const unsigned short* __restrict__ Wq,
                                                const unsigned short* __restrict__ Wk,
                                                const unsigned short* __restrict__ Wv,
                                                const float* __restrict__ biq,
                                                const float* __restrict__ bik,
                                                const float* __restrict__ biv,
                                                unsigned short* __restrict__ Oq,
                                                unsigned short* __restrict__ Ok,
                                                unsigned short* __restrict__ Ov)
{
    const int K = 1024;
    __shared__ unsigned short sA[64][32];
    __shared__ unsigned short sB[128][32];
    int tid = threadIdx.x;
    int w = tid >> 6, lane = tid & 63;

    int bid = blockIdx.x;
    int which = bid >> 9;              // 0=Q 1=K 2=V
    int lin = bid & 511;
    int xcd = lin & 7, idx = lin >> 3; // idx in [0,64)
    int bm = (xcd * 8 + (idx >> 3)) * 64;
    int bn = (idx & 7) * 128;

    const unsigned short* A = (which == 0) ? Aq : (which == 1) ? Ak : Av;
    const unsigned short* Bw = (which == 0) ? Wq : (which == 1) ? Wk : Wv;
    const float* bias = (which == 0) ? biq : (which == 1) ? bik : biv;
    unsigned short* outp = (which == 0) ? Oq : (which == 1) ? Ok : Ov;

    int wr = (w >> 1) * 32, wc = (w & 1) * 64;
    int fr = lane & 15, fk = (lane >> 4) * 8;

    const unsigned short* Ag = A + (size_t)(bm + w * 16 + (lane >> 2)) * K + (lane & 3) * 8;
    const unsigned short* Bg = Bw + (size_t)(bn + w * 32 + (lane >> 2)) * K + (lane & 3) * 8;
    unsigned short* lA0 = &sA[w * 16][0];
    unsigned short* lB0 = &sB[w * 32][0];
    unsigned short* lB1 = &sB[w * 32 + 16][0];

    f32x4 acc[2][4];
#pragma unroll
    for (int i = 0; i < 2; ++i)
#pragma unroll
        for (int j = 0; j < 4; ++j) acc[i][j] = (f32x4){0.f, 0.f, 0.f, 0.f};

    for (int k0 = 0; k0 < K; k0 += 32) {
        __syncthreads();
        GLOAD_LDS16(Ag + k0,          lA0);
        GLOAD_LDS16(Bg + k0,          lB0);
        GLOAD_LDS16(Bg + 16 * K + k0, lB1);
        __syncthreads();
        bf16x8 af[2], bfv[4];
#pragma unroll
        for (int i = 0; i < 2; ++i) af[i]  = *(const bf16x8*)&sA[wr + i * 16 + fr][fk];
#pragma unroll
        for (int j = 0; j < 4; ++j) bfv[j] = *(const bf16x8*)&sB[wc + j * 16 + fr][fk];
#pragma unroll
        for (int i = 0; i < 2; ++i)
#pragma unroll
            for (int j = 0; j < 4; ++j)
                acc[i][j] = __builtin_amdgcn_mfma_f32_16x16x32_bf16(af[i], bfv[j], acc[i][j], 0, 0, 0);
    }

    int rb = (lane >> 4) * 4;
#pragma unroll
    for (int j = 0; j < 4; ++j) {
        int n = bn + wc + j * 16 + fr;
        float bia = bias[n];
#pragma unroll
        for (int i = 0; i < 2; ++i) {
#pragma unroll
            for (int r = 0; r < 4; ++r) {
                int m = bm + wr + i * 16 + rb + r;
                float v = acc[i][j][r] + bia;
                int b = m >> 10, l = m & 1023, h = n >> 6, d = n & 63;
                if (which == 2)
                    outp[(((size_t)(b * Hh + h)) * Dd + d) * Lq + l] = f2bf(v);
                else
                    outp[(((size_t)(b * Hh + h)) * Lq + l) * Dd + d] = f2bf(v);
            }
        }
    }
}

// ---------------------------------------------------------------------------
// Output projection (unchanged).
// ---------------------------------------------------------------------------
__global__ __launch_bounds__(256) void gemm_o(const unsigned short* __restrict__ A,
                                              const unsigned short* __restrict__ Bw,
                                              const float* __restrict__ bias,
                                              float* __restrict__ outp)
{
    const int K = 1024;
    __shared__ unsigned short sA[64][32];
    __shared__ unsigned short sB[128][32];
    int tid = threadIdx.x;
    int w = tid >> 6, lane = tid & 63;

    int lin = blockIdx.x;
    int xcd = lin & 7, idx = lin >> 3;
    int bm = (xcd * 8 + (idx >> 3)) * 64;
    int bn = (idx & 7) * 128;

    int wr = (w >> 1) * 32, wc = (w & 1) * 64;
    int fr = lane & 15, fk = (lane >> 4) * 8;

    const unsigned short* Ag = A + (size_t)(bm + w * 16 + (lane >> 2)) * K + (lane & 3) * 8;
    const unsigned short* Bg = Bw + (size_t)(bn + w * 32 + (lane >> 2)) * K + (lane & 3) * 8;
    unsigned short* lA0 = &sA[w * 16][0];
    unsigned short* lB0 = &sB[w * 32][0];
    unsigned short* lB1 = &sB[w * 32 + 16][0];

    f32x4 acc[2][4];
#pragma unroll
    for (int i = 0; i < 2; ++i)
#pragma unroll
        for (int j = 0; j < 4; ++j) acc[i][j] = (f32x4){0.f, 0.f, 0.f, 0.f};

    for (int k0 = 0; k0 < K; k0 += 32) {
        __syncthreads();
        GLOAD_LDS16(Ag + k0,          lA0);
        GLOAD_LDS16(Bg + k0,          lB0);
        GLOAD_LDS16(Bg + 16 * K + k0, lB1);
        __syncthreads();
        bf16x8 af[2], bfv[4];
#pragma unroll
        for (int i = 0; i < 2; ++i) af[i]  = *(const bf16x8*)&sA[wr + i * 16 + fr][fk];
#pragma unroll
        for (int j = 0; j < 4; ++j) bfv[j] = *(const bf16x8*)&sB[wc + j * 16 + fr][fk];
#pragma unroll
        for (int i = 0; i < 2; ++i)
#pragma unroll
            for (int j = 0; j < 4; ++j)
                acc[i][j] = __builtin_amdgcn_mfma_f32_16x16x32_bf16(af[i], bfv[j], acc[i][j], 0, 0, 0);
    }

    int rb = (lane >> 4) * 4;
#pragma unroll
    for (int j = 0; j < 4; ++j) {
        int n = bn + wc + j * 16 + fr;
        float bia = bias[n];
#pragma unroll
        for (int i = 0; i < 2; ++i)
#pragma unroll
            for (int r = 0; r < 4; ++r) {
                int m = bm + wr + i * 16 + rb + r;
                outp[(size_t)m * 1024 + n] = acc[i][j][r] + bia;
            }
    }
}

// ---------------------------------------------------------------------------
// Pass C: flash attention.  512 blocks (XCD-colocated per (b,h)), 4 waves,
// 32 q-rows per wave (two 16-q tiles A/B).  No launch-bounds VGPR cap: the
// K double-buffer + hoisted V fragments must stay live across chunks.
// ---------------------------------------------------------------------------
__global__ __launch_bounds__(256) void attn_flash(const unsigned short* __restrict__ Qh,
                                                  const unsigned short* __restrict__ Kh,
                                                  const unsigned short* __restrict__ Vt,
                                                  const float* __restrict__ mbias,
                                                  unsigned short* __restrict__ ctx,
                                                  float* __restrict__ mstats,
                                                  float* __restrict__ lstats)
{
    __shared__ float sBias[1024];
    __shared__ unsigned short Wl[4][2][16][64];   // per-wave, per-tile P, swizzled

    int tid = threadIdx.x;
    int w = tid >> 6, lane = tid & 63;
    int fr = lane & 15, fg = lane >> 4;

    // XCD-colocation: all 8 qt-blocks of one (b,h) share an XCD.
    int lin = blockIdx.x;
    int xcd = lin & 7, jj = lin >> 3;          // jj in [0,64)
    int pair = xcd * 8 + (jj >> 3);            // 0..63 == h*4 + b
    int qt = jj & 7;
    int b = pair & 3, h = pair >> 2;

    int q0A = qt * 128 + w * 32;
    int q0B = q0A + 16;
    int swz = (fr & 7) << 2;                   // XOR on 4-byte-word index

    for (int i = tid; i < 1024; i += 256) sBias[i] = mbias[b * Lq + i];
    __syncthreads();

    const unsigned short* Qp = Qh + ((size_t)(b * Hh + h)) * Lq * Dd;
    const unsigned short* Kp = Kh + ((size_t)(b * Hh + h)) * Lq * Dd;
    const unsigned short* Vp = Vt + ((size_t)(b * Hh + h)) * Dd * Lq;

    bf16x8 qA0 = *(const bf16x8*)(Qp + (size_t)(q0A + fr) * Dd + fg * 8);
    bf16x8 qA1 = *(const bf16x8*)(Qp + (size_t)(q0A + fr) * Dd + 32 + fg * 8);
    bf16x8 qB0 = *(const bf16x8*)(Qp + (size_t)(q0B + fr) * Dd + fg * 8);
    bf16x8 qB1 = *(const bf16x8*)(Qp + (size_t)(q0B + fr) * Dd + 32 + fg * 8);

    f32x4 OA[4], OB[4];
#pragma unroll
    for (int dt = 0; dt < 4; ++dt) { OA[dt] = (f32x4){0.f,0.f,0.f,0.f}; OB[dt] = (f32x4){0.f,0.f,0.f,0.f}; }
    float mA = -INFINITY, lA = 0.f, mB = -INFINITY, lB = 0.f;

    bf16x8 kX0[4], kX1[4], kY0[4], kY1[4];
    bf16x8 vb0[4], vb1[4];

#define LOADK(K0, K1, KC) do {                                                   \
    _Pragma("unroll")                                                            \
    for (int kt = 0; kt < 4; ++kt) {                                             \
        K0[kt] = *(const bf16x8*)(Kp + (size_t)((KC) + kt * 16 + fr) * Dd + fg * 8);        \
        K1[kt] = *(const bf16x8*)(Kp + (size_t)((KC) + kt * 16 + fr) * Dd + 32 + fg * 8);   \
    }                                                                            \
} while (0)

#define LOADV(KC) do {                                                           \
    _Pragma("unroll")                                                            \
    for (int dt = 0; dt < 4; ++dt) {                                             \
        vb0[dt] = *(const bf16x8*)(Vp + (size_t)(dt * 16 + fr) * Lq + (KC) + fg * 8);       \
        vb1[dt] = *(const bf16x8*)(Vp + (size_t)(dt * 16 + fr) * Lq + (KC) + 32 + fg * 8);  \
    }                                                                            \
} while (0)

#define QK(S, K0, K1, B0, B1) do {                                               \
    _Pragma("unroll")                                                            \
    for (int kt = 0; kt < 4; ++kt) {                                             \
        S[kt] = __builtin_amdgcn_mfma_f32_16x16x32_bf16(K0[kt], B0, (f32x4){0.f,0.f,0.f,0.f}, 0, 0, 0); \
        S[kt] = __builtin_amdgcn_mfma_f32_16x16x32_bf16(K1[kt], B1, S[kt], 0, 0, 0); \
    }                                                                            \
} while (0)

// softmax + PV for one tile.  In-lane tree + cross-fg shfl reduces.
#define SMPV(S, MT, LT, OT, TI, KC) do {                                         \
    float v_[16];                                                                \
    _Pragma("unroll")                                                            \
    for (int kt = 0; kt < 4; ++kt) {                                             \
        float4 bb = *(const float4*)&sBias[(KC) + kt * 16 + fg * 4];             \
        _Pragma("unroll")                                                        \
        for (int r = 0; r < 4; ++r)                                              \
            v_[kt * 4 + r] = S[kt][r] * 0.125f + (&bb.x)[r];                     \
    }                                                                            \
    float t8[8];                                                                 \
    _Pragma("unroll")                                                            \
    for (int i = 0; i < 8; ++i) t8[i] = fmaxf(v_[i], v_[i + 8]);                 \
    float t4[4];                                                                 \
    _Pragma("unroll")                                                            \
    for (int i = 0; i < 4; ++i) t4[i] = fmaxf(t8[i], t8[i + 4]);                 \
    float pmax = fmaxf(fmaxf(t4[0], t4[1]), fmaxf(t4[2], t4[3]));                \
    pmax = cross_max(pmax);                                                      \
    float mn = fmaxf(MT, pmax);                                                  \
    float sc = __expf(MT - mn);                                                  \
    _Pragma("unroll")                                                            \
    for (int i = 0; i < 16; ++i) v_[i] = __expf(v_[i] - mn);                     \
    _Pragma("unroll")                                                            \
    for (int i = 0; i < 8; ++i) t8[i] = v_[i] + v_[i + 8];                       \
    _Pragma("unroll")                                                            \
    for (int i = 0; i < 4; ++i) t4[i] = t8[i] + t8[i + 4];                       \
    float cs = (t4[0] + t4[1]) + (t4[2] + t4[3]);                                \
    cs = cross_sum(cs);                                                          \
    LT = LT * sc + cs;                                                           \
    MT = mn;                                                                     \
    _Pragma("unroll")                                                            \
    for (int dt = 0; dt < 4; ++dt)                                               \
        _Pragma("unroll")                                                        \
        for (int r = 0; r < 4; ++r) OT[dt][r] *= sc;                             \
    _Pragma("unroll")                                                            \
    for (int kt = 0; kt < 4; ++kt) {                                             \
        unsigned w0 = pack2(v_[kt * 4 + 0], v_[kt * 4 + 1]);                     \
        unsigned w1 = pack2(v_[kt * 4 + 2], v_[kt * 4 + 3]);                     \
        uint2 pr; pr.x = w0; pr.y = w1;                                          \
        *(uint2*)&Wl[w][TI][fr][2 * ((kt * 8 + fg * 2) ^ swz)] = pr;             \
    }                                                                            \
    bf16x8 pa0 = *(const bf16x8*)&Wl[w][TI][fr][2 * ((fg * 4) ^ swz)];           \
    bf16x8 pa1 = *(const bf16x8*)&Wl[w][TI][fr][2 * ((16 + fg * 4) ^ swz)];      \
    _Pragma("unroll")                                                            \
    for (int dt = 0; dt < 4; ++dt) {                                             \
        OT[dt] = __builtin_amdgcn_mfma_f32_16x16x32_bf16(vb0[dt], pa0, OT[dt], 0, 0, 0); \
        OT[dt] = __builtin_amdgcn_mfma_f32_16x16x32_bf16(vb1[dt], pa1, OT[dt], 0, 0, 0); \
    }                                                                            \
} while (0)

    LOADK(kX0, kX1, 0);
#pragma unroll 1
    for (int c = 0; c < 16; c += 2) {
        f32x4 SA[4], SB[4];
        // ---- chunk c (K in X) ----
        QK(SA, kX0, kX1, qA0, qA1);
        QK(SB, kX0, kX1, qB0, qB1);
        LOADK(kY0, kY1, (c + 1) * 64);     // lands under softmax below
        LOADV(c * 64);
        SMPV(SA, mA, lA, OA, 0, c * 64);
        SMPV(SB, mB, lB, OB, 1, c * 64);
        // ---- chunk c+1 (K in Y) ----
        QK(SA, kY0, kY1, qA0, qA1);
        QK(SB, kY0, kY1, qB0, qB1);
        if (c + 2 < 16) LOADK(kX0, kX1, (c + 2) * 64);
        LOADV((c + 1) * 64);
        SMPV(SA, mA, lA, OA, 0, (c + 1) * 64);
        SMPV(SB, mB, lB, OB, 1, (c + 1) * 64);
    }
#undef LOADK
#undef LOADV
#undef QK
#undef SMPV

    float liA = 1.f / lA, liB = 1.f / lB;
#pragma unroll
    for (int dt = 0; dt < 4; ++dt) {
#pragma unroll
        for (int r = 0; r < 4; ++r) { OA[dt][r] *= liA; OB[dt][r] *= liB; }
    }
    // O^T layout: lane holds q = fr, d = dt*16 + fg*4 + r  (4 consecutive d)
#pragma unroll
    for (int dt = 0; dt < 4; ++dt) {
        uint2 pa; pa.x = pack2(OA[dt][0], OA[dt][1]); pa.y = pack2(OA[dt][2], OA[dt][3]);
        *(uint2*)(ctx + ((size_t)(b * Lq + q0A + fr)) * Emb + h * Dd + dt * 16 + fg * 4) = pa;
        uint2 pb; pb.x = pack2(OB[dt][0], OB[dt][1]); pb.y = pack2(OB[dt][2], OB[dt][3]);
        *(uint2*)(ctx + ((size_t)(b * Lq + q0B + fr)) * Emb + h * Dd + dt * 16 + fg * 4) = pb;
    }

    if (lane < 16) {
        mstats[(size_t)(b * Hh + h) * Lq + q0A + lane] = mA;
        lstats[(size_t)(b * Hh + h) * Lq + q0A + lane] = liA;
        mstats[(size_t)(b * Hh + h) * Lq + q0B + lane] = mB;
        lstats[(size_t)(b * Hh + h) * Lq + q0B + lane] = liB;
    }
}

// ---------------------------------------------------------------------------
// Pass B: out2 = mean_h softmax weights; per-head Q/K frags double-buffered.
// ---------------------------------------------------------------------------
__global__ __launch_bounds__(256) void attn_out2(const unsigned short* __restrict__ Qh,
                                                 const unsigned short* __restrict__ Kh,
                                                 const float* __restrict__ mbias,
                                                 const float* __restrict__ mstats,
                                                 const float* __restrict__ lstats,
                                                 float* __restrict__ out2)
{
    __shared__ float sM[16][32];
    __shared__ float sLi[16][32];
    int tid = threadIdx.x;
    int w = tid >> 6, lane = tid & 63;
    int fr = lane & 15, fg = lane >> 4;
    int q0 = blockIdx.x * 32;
    int kc = blockIdx.y * 128;
    int b  = blockIdx.z;

    for (int i = tid; i < 512; i += 256) {
        int h = i >> 5, qq = i & 31;
        sM[h][qq]  = mstats[(size_t)(b * Hh + h) * Lq + q0 + qq];
        sLi[h][qq] = lstats[(size_t)(b * Hh + h) * Lq + q0 + qq];
    }
    __syncthreads();

    float bias0 = mbias[b * Lq + kc + w * 32 + fr];
    float bias1 = mbias[b * Lq + kc + w * 32 + 16 + fr];

    float o2[2][2][4];
#pragma unroll
    for (int rt = 0; rt < 2; ++rt)
#pragma unroll
        for (int ct = 0; ct < 2; ++ct)
#pragma unroll
            for (int r = 0; r < 4; ++r) o2[rt][ct][r] = 0.f;

    bf16x8 aqA[2][2], bkA[2][2], aqB[2][2], bkB[2][2];

#define LOADH(AQ, BKk, H) do {                                                   \
    const unsigned short* Qp_ = Qh + ((size_t)(b * Hh + (H))) * Lq * Dd;         \
    const unsigned short* Kp_ = Kh + ((size_t)(b * Hh + (H))) * Lq * Dd;         \
    _Pragma("unroll")                                                            \
    for (int rt = 0; rt < 2; ++rt)                                               \
        _Pragma("unroll")                                                        \
        for (int ks = 0; ks < 2; ++ks)                                           \
            AQ[rt][ks] = *(const bf16x8*)(Qp_ + (size_t)(q0 + rt * 16 + fr) * Dd + ks * 32 + fg * 8); \
    _Pragma("unroll")                                                            \
    for (int ct = 0; ct < 2; ++ct)                                               \
        _Pragma("unroll")                                                        \
        for (int ks = 0; ks < 2; ++ks)                                           \
            BKk[ct][ks] = *(const bf16x8*)(Kp_ + (size_t)(kc + w * 32 + ct * 16 + fr) * Dd + ks * 32 + fg * 8); \
} while (0)

#define COMPH(AQ, BKk, H) do {                                                   \
    float4 mrow[2], lirow[2];                                                    \
    _Pragma("unroll")                                                            \
    for (int rt = 0; rt < 2; ++rt) {                                             \
        mrow[rt]  = *(const float4*)&sM[(H)][rt * 16 + fg * 4];                  \
        lirow[rt] = *(const float4*)&sLi[(H)][rt * 16 + fg * 4];                 \
    }                                                                            \
    _Pragma("unroll")                                                            \
    for (int rt = 0; rt < 2; ++rt)                                               \
        _Pragma("unroll")                                                        \
        for (int ct = 0; ct < 2; ++ct) {                                         \
            f32x4 s_ = __builtin_amdgcn_mfma_f32_16x16x32_bf16(AQ[rt][0], BKk[ct][0], (f32x4){0.f,0.f,0.f,0.f}, 0, 0, 0); \
            s_ = __builtin_amdgcn_mfma_f32_16x16x32_bf16(AQ[rt][1], BKk[ct][1], s_, 0, 0, 0); \
            float bia = ct ? bias1 : bias0;                                      \
            _Pragma("unroll")                                                    \
            for (int r = 0; r < 4; ++r)                                          \
                o2[rt][ct][r] += __expf(s_[r] * 0.125f + bia - mrow[rt][r]) * lirow[rt][r]; \
        }                                                                        \
} while (0)

    LOADH(aqA, bkA, 0);
#pragma unroll 1
    for (int h = 0; h < Hh; h += 2) {
        LOADH(aqB, bkB, h + 1);
        COMPH(aqA, bkA, h);
        if (h + 2 < Hh) LOADH(aqA, bkA, h + 2);
        COMPH(aqB, bkB, h + 1);
    }
#undef LOADH
#undef COMPH

#pragma unroll
    for (int rt = 0; rt < 2; ++rt)
#pragma unroll
        for (int ct = 0; ct < 2; ++ct)
#pragma unroll
            for (int r = 0; r < 4; ++r)
                out2[((size_t)(b * Lq + q0 + rt * 16 + fg * 4 + r)) * Lq + kc + w * 32 + ct * 16 + fr]
                    = o2[rt][ct][r] * 0.0625f;
}

// ---------------------------------------------------------------------------
extern "C" void kernel_launch(void* const* d_in, const int* in_sizes, int n_in,
                              void* d_out, int out_size, void* d_ws, size_t ws_size,
                              hipStream_t stream)
{
    const float* query = (const float*)d_in[0];
    const float* key   = (const float*)d_in[1];
    const float* value = (const float*)d_in[2];
    const float* amask = (const float*)d_in[3];
    const int*   kpm   = (const int*)d_in[4];
    const float* Wq = (const float*)d_in[5];
    const float* bq = (const float*)d_in[6];
    const float* Wk = (const float*)d_in[7];
    const float* bk = (const float*)d_in[8];
    const float* Wv = (const float*)d_in[9];
    const float* bv = (const float*)d_in[10];
    const float* Wo = (const float*)d_in[11];
    const float* bo = (const float*)d_in[12];

    float* out1 = (float*)d_out;                       // (B,L,E) f32
    float* out2 = out1 + (size_t)Bsz * Lq * Emb;       // (B,L,L) f32

    const size_t MB = 1u << 20;
    char* ws = (char*)d_ws;
    unsigned short* qbf = (unsigned short*)(ws + 0 * MB);
    unsigned short* kbf = (unsigned short*)(ws + 8 * MB);
    unsigned short* vbf = (unsigned short*)(ws + 16 * MB);
    unsigned short* wqb = (unsigned short*)(ws + 24 * MB);
    unsigned short* wkb = (unsigned short*)(ws + 26 * MB);
    unsigned short* wvb = (unsigned short*)(ws + 28 * MB);
    unsigned short* wob = (unsigned short*)(ws + 30 * MB);
    unsigned short* QhB = (unsigned short*)(ws + 32 * MB);  // (B,H,L,D) bf16
    unsigned short* KhB = (unsigned short*)(ws + 40 * MB);
    unsigned short* VtB = (unsigned short*)(ws + 48 * MB);  // (B,H,D,L) bf16
    unsigned short* ctxB = (unsigned short*)(ws + 56 * MB); // (B,L,E) bf16
    float* mbias  = (float*)(ws + 64 * MB);                 // 16 KB
    // stats alias the qbf region (dead after gemm_qkv)
    float* mstats = (float*)(ws + 0 * MB);                  // 256 KB
    float* lstats = (float*)(ws + 0 * MB + 256 * 1024);     // 256 KB

    bias_kernel<<<16, 256, 0, stream>>>(amask, kpm, mbias, Bsz * Lq);

    cvt_qkv<<<12288, 256, 0, stream>>>(query, key, value, qbf, kbf, vbf);
    cvt_w4<<<4096, 256, 0, stream>>>(Wq, Wk, Wv, Wo, wqb, wkb, wvb, wob);

    gemm_qkv<<<1536, 256, 0, stream>>>(qbf, kbf, vbf, wqb, wkb, wvb,
                                       bq, bk, bv, QhB, KhB, VtB);

    attn_flash<<<512, 256, 0, stream>>>(QhB, KhB, VtB, mbias, ctxB, mstats, lstats);
    attn_out2<<<dim3(32, 8, 4), 256, 0, stream>>>(QhB, KhB, mbias, mstats, lstats, out2);

    gemm_o<<<512, 256, 0, stream>>>(ctxB, wob, bo, out1);
}

// Round 10
// 198.713 us; speedup vs baseline: 1.6115x; 1.1242x over previous
//
#include <hip/hip_runtime.h>
#include <math.h>

#define Bsz 4
#define Lq  1024
#define Emb 1024
#define Hh  16
#define Dd  64

typedef short bf16x8 __attribute__((ext_vector_type(8)));
typedef float f32x4 __attribute__((ext_vector_type(4)));

static __device__ __forceinline__ unsigned short f2bf(float f) {
    unsigned u = __float_as_uint(f);
    return (unsigned short)((u + 0x7FFFu + ((u >> 16) & 1u)) >> 16);
}
// pack two f32 -> two bf16 (round-half-up) in one v_perm
static __device__ __forceinline__ unsigned pack2(float lo, float hi) {
    return __builtin_amdgcn_perm(__float_as_uint(hi) + 0x8000u,
                                 __float_as_uint(lo) + 0x8000u, 0x07060302u);
}

// cross-fg reduces (lanes {l, l^16, l^32, l^48}); proven-correct shfl form.
static __device__ __forceinline__ float cross_max(float x) {
    x = fmaxf(x, __shfl_xor(x, 16, 64));
    x = fmaxf(x, __shfl_xor(x, 32, 64));
    return x;
}
static __device__ __forceinline__ float cross_sum(float x) {
    x += __shfl_xor(x, 16, 64);
    x += __shfl_xor(x, 32, 64);
    return x;
}

// global -> LDS direct copy, 16 B per lane.
#define GLOAD_LDS16(gp, lp) __builtin_amdgcn_global_load_lds(                  \
    (const __attribute__((address_space(1))) void*)(gp),                       \
    (__attribute__((address_space(3))) void*)(lp), 16, 0, 0)

// ---------------------------------------------------------------------------
__global__ __launch_bounds__(256) void bias_kernel(const float* __restrict__ mask,
                                                   const int* __restrict__ kpm,
                                                   float* __restrict__ bias, int n)
{
    int i = blockIdx.x * 256 + threadIdx.x;
    if (i < n) {
        float b = 8.0f * logf(fmaxf(mask[i], 1e-6f));
        bias[i] = kpm[i] ? -INFINITY : b;
    }
}

// ---------------------------------------------------------------------------
__global__ __launch_bounds__(256) void cvt_qkv(const float* __restrict__ q,
                                               const float* __restrict__ k,
                                               const float* __restrict__ v,
                                               unsigned short* __restrict__ qo,
                                               unsigned short* __restrict__ ko,
                                               unsigned short* __restrict__ vo)
{
    int i = blockIdx.x * 256 + threadIdx.x;
    const float* src; unsigned short* dst; int off;
    if (i < 1048576)      { src = q; dst = qo; off = i; }
    else if (i < 2097152) { src = k; dst = ko; off = i - 1048576; }
    else                  { src = v; dst = vo; off = i - 2097152; }
    float4 x = ((const float4*)src)[off];
    ushort4 o;
    o.x = f2bf(x.x); o.y = f2bf(x.y); o.z = f2bf(x.z); o.w = f2bf(x.w);
    ((ushort4*)dst)[off] = o;
}

__global__ __launch_bounds__(256) void cvt_w4(const float* __restrict__ w0,
                                              const float* __restrict__ w1,
                                              const float* __restrict__ w2,
                                              const float* __restrict__ w3,
                                              unsigned short* __restrict__ o0,
                                              unsigned short* __restrict__ o1,
                                              unsigned short* __restrict__ o2,
                                              unsigned short* __restrict__ o3)
{
    int i = blockIdx.x * 256 + threadIdx.x;
    int reg = i >> 18, off = i & 262143;
    const float* src = (reg == 0) ? w0 : (reg == 1) ? w1 : (reg == 2) ? w2 : w3;
    unsigned short* dst = (reg == 0) ? o0 : (reg == 1) ? o1 : (reg == 2) ? o2 : o3;
    float4 x = ((const float4*)src)[off];
    ushort4 o;
    o.x = f2bf(x.x); o.y = f2bf(x.y); o.z = f2bf(x.z); o.w = f2bf(x.w);
    ((ushort4*)dst)[off] = o;
}

// ---------------------------------------------------------------------------
// Fused Q/K/V projections (unchanged).
// ---------------------------------------------------------------------------
__global__ __launch_bounds__(256) void gemm_qkv(const unsigned short* __restrict__ Aq,
                                                const unsigned short* __restrict__ Ak,
                                                const unsigned short* __restrict__ Av,
                                                const unsigned short* __restrict__ Wq,
                                                const unsigned short* __restrict__ Wk,
                                                const unsigned short* __restrict__ Wv,
                                                const float* __restrict__ biq,
                                                const float* __restrict__ bik,
                                                const float* __restrict__ biv,
                                                unsigned short* __restrict__ Oq,
                                                unsigned short* __restrict__ Ok,
                                                unsigned short* __restrict__ Ov)
{
    const int K = 1024;
    __shared__ unsigned short sA[64][32];
    __shared__ unsigned short sB[128][32];
    int tid = threadIdx.x;
    int w = tid >> 6, lane = tid & 63;

    int bid = blockIdx.x;
    int which = bid >> 9;              // 0=Q 1=K 2=V
    int lin = bid & 511;
    int xcd = lin & 7, idx = lin >> 3; // idx in [0,64)
    int bm = (xcd * 8 + (idx >> 3)) * 64;
    int bn = (idx & 7) * 128;

    const unsigned short* A = (which == 0) ? Aq : (which == 1) ? Ak : Av;
    const unsigned short* Bw = (which == 0) ? Wq : (which == 1) ? Wk : Wv;
    const float* bias = (which == 0) ? biq : (which == 1) ? bik : biv;
    unsigned short* outp = (which == 0) ? Oq : (which == 1) ? Ok : Ov;

    int wr = (w >> 1) * 32, wc = (w & 1) * 64;
    int fr = lane & 15, fk = (lane >> 4) * 8;

    const unsigned short* Ag = A + (size_t)(bm + w * 16 + (lane >> 2)) * K + (lane & 3) * 8;
    const unsigned short* Bg = Bw + (size_t)(bn + w * 32 + (lane >> 2)) * K + (lane & 3) * 8;
    unsigned short* lA0 = &sA[w * 16][0];
    unsigned short* lB0 = &sB[w * 32][0];
    unsigned short* lB1 = &sB[w * 32 + 16][0];

    f32x4 acc[2][4];
#pragma unroll
    for (int i = 0; i < 2; ++i)
#pragma unroll
        for (int j = 0; j < 4; ++j) acc[i][j] = (f32x4){0.f, 0.f, 0.f, 0.f};

    for (int k0 = 0; k0 < K; k0 += 32) {
        __syncthreads();
        GLOAD_LDS16(Ag + k0,          lA0);
        GLOAD_LDS16(Bg + k0,          lB0);
        GLOAD_LDS16(Bg + 16 * K + k0, lB1);
        __syncthreads();
        bf16x8 af[2], bfv[4];
#pragma unroll
        for (int i = 0; i < 2; ++i) af[i]  = *(const bf16x8*)&sA[wr + i * 16 + fr][fk];
#pragma unroll
        for (int j = 0; j < 4; ++j) bfv[j] = *(const bf16x8*)&sB[wc + j * 16 + fr][fk];
#pragma unroll
        for (int i = 0; i < 2; ++i)
#pragma unroll
            for (int j = 0; j < 4; ++j)
                acc[i][j] = __builtin_amdgcn_mfma_f32_16x16x32_bf16(af[i], bfv[j], acc[i][j], 0, 0, 0);
    }

    int rb = (lane >> 4) * 4;
#pragma unroll
    for (int j = 0; j < 4; ++j) {
        int n = bn + wc + j * 16 + fr;
        float bia = bias[n];
#pragma unroll
        for (int i = 0; i < 2; ++i) {
#pragma unroll
            for (int r = 0; r < 4; ++r) {
                int m = bm + wr + i * 16 + rb + r;
                float v = acc[i][j][r] + bia;
                int b = m >> 10, l = m & 1023, h = n >> 6, d = n & 63;
                if (which == 2)
                    outp[(((size_t)(b * Hh + h)) * Dd + d) * Lq + l] = f2bf(v);
                else
                    outp[(((size_t)(b * Hh + h)) * Lq + l) * Dd + d] = f2bf(v);
            }
        }
    }
}

// ---------------------------------------------------------------------------
// Output projection (unchanged).
// ---------------------------------------------------------------------------
__global__ __launch_bounds__(256) void gemm_o(const unsigned short* __restrict__ A,
                                              const unsigned short* __restrict__ Bw,
                                              const float* __restrict__ bias,
                                              float* __restrict__ outp)
{
    const int K = 1024;
    __shared__ unsigned short sA[64][32];
    __shared__ unsigned short sB[128][32];
    int tid = threadIdx.x;
    int w = tid >> 6, lane = tid & 63;

    int lin = blockIdx.x;
    int xcd = lin & 7, idx = lin >> 3;
    int bm = (xcd * 8 + (idx >> 3)) * 64;
    int bn = (idx & 7) * 128;

    int wr = (w >> 1) * 32, wc = (w & 1) * 64;
    int fr = lane & 15, fk = (lane >> 4) * 8;

    const unsigned short* Ag = A + (size_t)(bm + w * 16 + (lane >> 2)) * K + (lane & 3) * 8;
    const unsigned short* Bg = Bw + (size_t)(bn + w * 32 + (lane >> 2)) * K + (lane & 3) * 8;
    unsigned short* lA0 = &sA[w * 16][0];
    unsigned short* lB0 = &sB[w * 32][0];
    unsigned short* lB1 = &sB[w * 32 + 16][0];

    f32x4 acc[2][4];
#pragma unroll
    for (int i = 0; i < 2; ++i)
#pragma unroll
        for (int j = 0; j < 4; ++j) acc[i][j] = (f32x4){0.f, 0.f, 0.f, 0.f};

    for (int k0 = 0; k0 < K; k0 += 32) {
        __syncthreads();
        GLOAD_LDS16(Ag + k0,          lA0);
        GLOAD_LDS16(Bg + k0,          lB0);
        GLOAD_LDS16(Bg + 16 * K + k0, lB1);
        __syncthreads();
        bf16x8 af[2], bfv[4];
#pragma unroll
        for (int i = 0; i < 2; ++i) af[i]  = *(const bf16x8*)&sA[wr + i * 16 + fr][fk];
#pragma unroll
        for (int j = 0; j < 4; ++j) bfv[j] = *(const bf16x8*)&sB[wc + j * 16 + fr][fk];
#pragma unroll
        for (int i = 0; i < 2; ++i)
#pragma unroll
            for (int j = 0; j < 4; ++j)
                acc[i][j] = __builtin_amdgcn_mfma_f32_16x16x32_bf16(af[i], bfv[j], acc[i][j], 0, 0, 0);
    }

    int rb = (lane >> 4) * 4;
#pragma unroll
    for (int j = 0; j < 4; ++j) {
        int n = bn + wc + j * 16 + fr;
        float bia = bias[n];
#pragma unroll
        for (int i = 0; i < 2; ++i)
#pragma unroll
            for (int r = 0; r < 4; ++r) {
                int m = bm + wr + i * 16 + rb + r;
                outp[(size_t)m * 1024 + n] = acc[i][j][r] + bia;
            }
    }
}

// ---------------------------------------------------------------------------
// Pass C: flash attention, LDS-staged K/V (T3 2-phase).
// 512 blocks (XCD-colocated per (b,h)), 4 waves, 32 q-rows per wave.
// K/V chunks (64x64 bf16 each) double-buffered in LDS via global_load_lds
// with pre-swizzled SOURCE addresses (col16 ^= row&7) so frag ds_read_b128
// is ~2-way conflict-free.  Staging issues for chunk c+1 fly during chunk
// c's compute; the barrier's vmcnt(0) drain lands after ~3K cy of work.
// ---------------------------------------------------------------------------
__global__ __launch_bounds__(256) void attn_flash(const unsigned short* __restrict__ Qh,
                                                  const unsigned short* __restrict__ Kh,
                                                  const unsigned short* __restrict__ Vt,
                                                  const float* __restrict__ mbias,
                                                  unsigned short* __restrict__ ctx,
                                                  float* __restrict__ mstats,
                                                  float* __restrict__ lstats)
{
    __shared__ float sBias[1024];                 // 4 KB
    __shared__ unsigned short Wl[4][2][16][64];   // 16 KB  per-wave P tiles
    __shared__ unsigned short Kl[2][64][64];      // 16 KB  K chunk dbuf (swizzled)
    __shared__ unsigned short Vl[2][64][64];      // 16 KB  V chunk dbuf (swizzled)

    int tid = threadIdx.x;
    int w = tid >> 6, lane = tid & 63;
    int fr = lane & 15, fg = lane >> 4;

    // XCD-colocation: all 8 qt-blocks of one (b,h) share an XCD.
    int lin = blockIdx.x;
    int xcd = lin & 7, jj = lin >> 3;          // jj in [0,64)
    int pair = xcd * 8 + (jj >> 3);            // 0..63 == h*4 + b
    int qt = jj & 7;
    int b = pair & 3, h = pair >> 2;

    int q0A = qt * 128 + w * 32;
    int q0B = q0A + 16;
    int swz = (fr & 7) << 2;                   // XOR on 4-byte-word index (P tile)
    int csw = fr & 7;                          // XOR on col16 index (K/V tiles)

    const unsigned short* Qp = Qh + ((size_t)(b * Hh + h)) * Lq * Dd;
    const unsigned short* Kp = Kh + ((size_t)(b * Hh + h)) * Lq * Dd;
    const unsigned short* Vp = Vt + ((size_t)(b * Hh + h)) * Dd * Lq;

    // staging address helpers: issue covers 8 rows x 128 B; lane l ->
    // local row l>>3, logical col16 (l&7)^(l>>3) (inverse-swizzled source).
    int srl = lane >> 3;                       // 0..7
    int scb = (lane & 7) ^ srl;                // pre-swizzled col16

#define STAGEK(BUF, KC) do {                                                     \
    _Pragma("unroll")                                                            \
    for (int i = 0; i < 2; ++i)                                                  \
        GLOAD_LDS16(Kp + (size_t)((KC) + w * 16 + i * 8 + srl) * Dd + scb * 8,   \
                    &Kl[BUF][w * 16 + i * 8][0]);                                \
} while (0)
#define STAGEV(BUF, KC) do {                                                     \
    _Pragma("unroll")                                                            \
    for (int i = 0; i < 2; ++i)                                                  \
        GLOAD_LDS16(Vp + (size_t)(w * 16 + i * 8 + srl) * Lq + (KC) + scb * 8,   \
                    &Vl[BUF][w * 16 + i * 8][0]);                                \
} while (0)

    for (int i = tid; i < 1024; i += 256) sBias[i] = mbias[b * Lq + i];

    bf16x8 qA0 = *(const bf16x8*)(Qp + (size_t)(q0A + fr) * Dd + fg * 8);
    bf16x8 qA1 = *(const bf16x8*)(Qp + (size_t)(q0A + fr) * Dd + 32 + fg * 8);
    bf16x8 qB0 = *(const bf16x8*)(Qp + (size_t)(q0B + fr) * Dd + fg * 8);
    bf16x8 qB1 = *(const bf16x8*)(Qp + (size_t)(q0B + fr) * Dd + 32 + fg * 8);

    f32x4 OA[4], OB[4];
#pragma unroll
    for (int dt = 0; dt < 4; ++dt) { OA[dt] = (f32x4){0.f,0.f,0.f,0.f}; OB[dt] = (f32x4){0.f,0.f,0.f,0.f}; }
    float mA = -INFINITY, lA = 0.f, mB = -INFINITY, lB = 0.f;

    bf16x8 vb0[4], vb1[4];

#define RDK(K0, K1, BUF) do {                                                    \
    _Pragma("unroll")                                                            \
    for (int kt = 0; kt < 4; ++kt) {                                             \
        K0[kt] = *(const bf16x8*)&Kl[BUF][kt * 16 + fr][(fg ^ csw) * 8];         \
        K1[kt] = *(const bf16x8*)&Kl[BUF][kt * 16 + fr][((4 + fg) ^ csw) * 8];   \
    }                                                                            \
} while (0)
#define RDV(BUF) do {                                                            \
    _Pragma("unroll")                                                            \
    for (int dt = 0; dt < 4; ++dt) {                                             \
        vb0[dt] = *(const bf16x8*)&Vl[BUF][dt * 16 + fr][(fg ^ csw) * 8];        \
        vb1[dt] = *(const bf16x8*)&Vl[BUF][dt * 16 + fr][((4 + fg) ^ csw) * 8];  \
    }                                                                            \
} while (0)

#define QK(S, K0, K1, B0, B1) do {                                               \
    _Pragma("unroll")                                                            \
    for (int kt = 0; kt < 4; ++kt) {                                             \
        S[kt] = __builtin_amdgcn_mfma_f32_16x16x32_bf16(K0[kt], B0, (f32x4){0.f,0.f,0.f,0.f}, 0, 0, 0); \
        S[kt] = __builtin_amdgcn_mfma_f32_16x16x32_bf16(K1[kt], B1, S[kt], 0, 0, 0); \
    }                                                                            \
} while (0)

// softmax + PV for one tile.  In-lane tree + cross-fg shfl reduces.
#define SMPV(S, MT, LT, OT, TI, KC) do {                                         \
    float v_[16];                                                                \
    _Pragma("unroll")                                                            \
    for (int kt = 0; kt < 4; ++kt) {                                             \
        float4 bb = *(const float4*)&sBias[(KC) + kt * 16 + fg * 4];             \
        _Pragma("unroll")                                                        \
        for (int r = 0; r < 4; ++r)                                              \
            v_[kt * 4 + r] = S[kt][r] * 0.125f + (&bb.x)[r];                     \
    }                                                                            \
    float t8[8];                                                                 \
    _Pragma("unroll")                                                            \
    for (int i = 0; i < 8; ++i) t8[i] = fmaxf(v_[i], v_[i + 8]);                 \
    float t4[4];                                                                 \
    _Pragma("unroll")                                                            \
    for (int i = 0; i < 4; ++i) t4[i] = fmaxf(t8[i], t8[i + 4]);                 \
    float pmax = fmaxf(fmaxf(t4[0], t4[1]), fmaxf(t4[2], t4[3]));                \
    pmax = cross_max(pmax);                                                      \
    float mn = fmaxf(MT, pmax);                                                  \
    float sc = __expf(MT - mn);                                                  \
    _Pragma("unroll")                                                            \
    for (int i = 0; i < 16; ++i) v_[i] = __expf(v_[i] - mn);                     \
    _Pragma("unroll")                                                            \
    for (int i = 0; i < 8; ++i) t8[i] = v_[i] + v_[i + 8];                       \
    _Pragma("unroll")                                                            \
    for (int i = 0; i < 4; ++i) t4[i] = t8[i] + t8[i + 4];                       \
    float cs = (t4[0] + t4[1]) + (t4[2] + t4[3]);                                \
    cs = cross_sum(cs);                                                          \
    LT = LT * sc + cs;                                                           \
    MT = mn;                                                                     \
    _Pragma("unroll")                                                            \
    for (int dt = 0; dt < 4; ++dt)                                               \
        _Pragma("unroll")                                                        \
        for (int r = 0; r < 4; ++r) OT[dt][r] *= sc;                             \
    _Pragma("unroll")                                                            \
    for (int kt = 0; kt < 4; ++kt) {                                             \
        unsigned w0 = pack2(v_[kt * 4 + 0], v_[kt * 4 + 1]);                     \
        unsigned w1 = pack2(v_[kt * 4 + 2], v_[kt * 4 + 3]);                     \
        uint2 pr; pr.x = w0; pr.y = w1;                                          \
        *(uint2*)&Wl[w][TI][fr][2 * ((kt * 8 + fg * 2) ^ swz)] = pr;             \
    }                                                                            \
    bf16x8 pa0 = *(const bf16x8*)&Wl[w][TI][fr][2 * ((fg * 4) ^ swz)];           \
    bf16x8 pa1 = *(const bf16x8*)&Wl[w][TI][fr][2 * ((16 + fg * 4) ^ swz)];      \
    _Pragma("unroll")                                                            \
    for (int dt = 0; dt < 4; ++dt) {                                             \
        OT[dt] = __builtin_amdgcn_mfma_f32_16x16x32_bf16(vb0[dt], pa0, OT[dt], 0, 0, 0); \
        OT[dt] = __builtin_amdgcn_mfma_f32_16x16x32_bf16(vb1[dt], pa1, OT[dt], 0, 0, 0); \
    }                                                                            \
} while (0)

    // prologue: stage chunk 0 into buf 0 (drained by the barrier)
    STAGEK(0, 0);
    STAGEV(0, 0);
    __syncthreads();

#pragma unroll 1
    for (int c = 0; c < 16; ++c) {
        int cur = c & 1;
        if (c < 15) {                           // stage chunk c+1 into the other buf
            STAGEK(cur ^ 1, (c + 1) * 64);
            STAGEV(cur ^ 1, (c + 1) * 64);
        }
        bf16x8 k0[4], k1[4];
        RDK(k0, k1, cur);
        f32x4 SA[4], SB[4];
        QK(SA, k0, k1, qA0, qA1);
        QK(SB, k0, k1, qB0, qB1);
        RDV(cur);
        SMPV(SA, mA, lA, OA, 0, c * 64);
        SMPV(SB, mB, lB, OB, 1, c * 64);
        __syncthreads();                        // drains staging + guards dbuf
    }
#undef STAGEK
#undef STAGEV
#undef RDK
#undef RDV
#undef QK
#undef SMPV

    float liA = 1.f / lA, liB = 1.f / lB;
#pragma unroll
    for (int dt = 0; dt < 4; ++dt) {
#pragma unroll
        for (int r = 0; r < 4; ++r) { OA[dt][r] *= liA; OB[dt][r] *= liB; }
    }
    // O^T layout: lane holds q = fr, d = dt*16 + fg*4 + r  (4 consecutive d)
#pragma unroll
    for (int dt = 0; dt < 4; ++dt) {
        uint2 pa; pa.x = pack2(OA[dt][0], OA[dt][1]); pa.y = pack2(OA[dt][2], OA[dt][3]);
        *(uint2*)(ctx + ((size_t)(b * Lq + q0A + fr)) * Emb + h * Dd + dt * 16 + fg * 4) = pa;
        uint2 pb; pb.x = pack2(OB[dt][0], OB[dt][1]); pb.y = pack2(OB[dt][2], OB[dt][3]);
        *(uint2*)(ctx + ((size_t)(b * Lq + q0B + fr)) * Emb + h * Dd + dt * 16 + fg * 4) = pb;
    }

    if (lane < 16) {
        mstats[(size_t)(b * Hh + h) * Lq + q0A + lane] = mA;
        lstats[(size_t)(b * Hh + h) * Lq + q0A + lane] = liA;
        mstats[(size_t)(b * Hh + h) * Lq + q0B + lane] = mB;
        lstats[(size_t)(b * Hh + h) * Lq + q0B + lane] = liB;
    }
}

// ---------------------------------------------------------------------------
// Pass B: out2 = mean_h softmax weights; per-head Q/K frags double-buffered.
// ---------------------------------------------------------------------------
__global__ __launch_bounds__(256) void attn_out2(const unsigned short* __restrict__ Qh,
                                                 const unsigned short* __restrict__ Kh,
                                                 const float* __restrict__ mbias,
                                                 const float* __restrict__ mstats,
                                                 const float* __restrict__ lstats,
                                                 float* __restrict__ out2)
{
    __shared__ float sM[16][32];
    __shared__ float sLi[16][32];
    int tid = threadIdx.x;
    int w = tid >> 6, lane = tid & 63;
    int fr = lane & 15, fg = lane >> 4;
    int q0 = blockIdx.x * 32;
    int kc = blockIdx.y * 128;
    int b  = blockIdx.z;

    for (int i = tid; i < 512; i += 256) {
        int h = i >> 5, qq = i & 31;
        sM[h][qq]  = mstats[(size_t)(b * Hh + h) * Lq + q0 + qq];
        sLi[h][qq] = lstats[(size_t)(b * Hh + h) * Lq + q0 + qq];
    }
    __syncthreads();

    float bias0 = mbias[b * Lq + kc + w * 32 + fr];
    float bias1 = mbias[b * Lq + kc + w * 32 + 16 + fr];

    float o2[2][2][4];
#pragma unroll
    for (int rt = 0; rt < 2; ++rt)
#pragma unroll
        for (int ct = 0; ct < 2; ++ct)
#pragma unroll
            for (int r = 0; r < 4; ++r) o2[rt][ct][r] = 0.f;

    bf16x8 aqA[2][2], bkA[2][2], aqB[2][2], bkB[2][2];

#define LOADH(AQ, BKk, H) do {                                                   \
    const unsigned short* Qp_ = Qh + ((size_t)(b * Hh + (H))) * Lq * Dd;         \
    const unsigned short* Kp_ = Kh + ((size_t)(b * Hh + (H))) * Lq * Dd;         \
    _Pragma("unroll")                                                            \
    for (int rt = 0; rt < 2; ++rt)                                               \
        _Pragma("unroll")                                                        \
        for (int ks = 0; ks < 2; ++ks)                                           \
            AQ[rt][ks] = *(const bf16x8*)(Qp_ + (size_t)(q0 + rt * 16 + fr) * Dd + ks * 32 + fg * 8); \
    _Pragma("unroll")                                                            \
    for (int ct = 0; ct < 2; ++ct)                                               \
        _Pragma("unroll")                                                        \
        for (int ks = 0; ks < 2; ++ks)                                           \
            BKk[ct][ks] = *(const bf16x8*)(Kp_ + (size_t)(kc + w * 32 + ct * 16 + fr) * Dd + ks * 32 + fg * 8); \
} while (0)

#define COMPH(AQ, BKk, H) do {                                                   \
    float4 mrow[2], lirow[2];                                                    \
    _Pragma("unroll")                                                            \
    for (int rt = 0; rt < 2; ++rt) {                                             \
        mrow[rt]  = *(const float4*)&sM[(H)][rt * 16 + fg * 4];                  \
        lirow[rt] = *(const float4*)&sLi[(H)][rt * 16 + fg * 4];                 \
    }                                                                            \
    _Pragma("unroll")                                                            \
    for (int rt = 0; rt < 2; ++rt)                                               \
        _Pragma("unroll")                                                        \
        for (int ct = 0; ct < 2; ++ct) {                                         \
            f32x4 s_ = __builtin_amdgcn_mfma_f32_16x16x32_bf16(AQ[rt][0], BKk[ct][0], (f32x4){0.f,0.f,0.f,0.f}, 0, 0, 0); \
            s_ = __builtin_amdgcn_mfma_f32_16x16x32_bf16(AQ[rt][1], BKk[ct][1], s_, 0, 0, 0); \
            float bia = ct ? bias1 : bias0;                                      \
            _Pragma("unroll")                                                    \
            for (int r = 0; r < 4; ++r)                                          \
                o2[rt][ct][r] += __expf(s_[r] * 0.125f + bia - mrow[rt][r]) * lirow[rt][r]; \
        }                                                                        \
} while (0)

    LOADH(aqA, bkA, 0);
#pragma unroll 1
    for (int h = 0; h < Hh; h += 2) {
        LOADH(aqB, bkB, h + 1);
        COMPH(aqA, bkA, h);
        if (h + 2 < Hh) LOADH(aqA, bkA, h + 2);
        COMPH(aqB, bkB, h + 1);
    }
#undef LOADH
#undef COMPH

#pragma unroll
    for (int rt = 0; rt < 2; ++rt)
#pragma unroll
        for (int ct = 0; ct < 2; ++ct)
#pragma unroll
            for (int r = 0; r < 4; ++r)
                out2[((size_t)(b * Lq + q0 + rt * 16 + fg * 4 + r)) * Lq + kc + w * 32 + ct * 16 + fr]
                    = o2[rt][ct][r] * 0.0625f;
}

// ---------------------------------------------------------------------------
extern "C" void kernel_launch(void* const* d_in, const int* in_sizes, int n_in,
                              void* d_out, int out_size, void* d_ws, size_t ws_size,
                              hipStream_t stream)
{
    const float* query = (const float*)d_in[0];
    const float* key   = (const float*)d_in[1];
    const float* value = (const float*)d_in[2];
    const float* amask = (const float*)d_in[3];
    const int*   kpm   = (const int*)d_in[4];
    const float* Wq = (const float*)d_in[5];
    const float* bq = (const float*)d_in[6];
    const float* Wk = (const float*)d_in[7];
    const float* bk = (const float*)d_in[8];
    const float* Wv = (const float*)d_in[9];
    const float* bv = (const float*)d_in[10];
    const float* Wo = (const float*)d_in[11];
    const float* bo = (const float*)d_in[12];

    float* out1 = (float*)d_out;                       // (B,L,E) f32
    float* out2 = out1 + (size_t)Bsz * Lq * Emb;       // (B,L,L) f32

    const size_t MB = 1u << 20;
    char* ws = (char*)d_ws;
    unsigned short* qbf = (unsigned short*)(ws + 0 * MB);
    unsigned short* kbf = (unsigned short*)(ws + 8 * MB);
    unsigned short* vbf = (unsigned short*)(ws + 16 * MB);
    unsigned short* wqb = (unsigned short*)(ws + 24 * MB);
    unsigned short* wkb = (unsigned short*)(ws + 26 * MB);
    unsigned short* wvb = (unsigned short*)(ws + 28 * MB);
    unsigned short* wob = (unsigned short*)(ws + 30 * MB);
    unsigned short* QhB = (unsigned short*)(ws + 32 * MB);  // (B,H,L,D) bf16
    unsigned short* KhB = (unsigned short*)(ws + 40 * MB);
    unsigned short* VtB = (unsigned short*)(ws + 48 * MB);  // (B,H,D,L) bf16
    unsigned short* ctxB = (unsigned short*)(ws + 56 * MB); // (B,L,E) bf16
    float* mbias  = (float*)(ws + 64 * MB);                 // 16 KB
    // stats alias the qbf region (dead after gemm_qkv)
    float* mstats = (float*)(ws + 0 * MB);                  // 256 KB
    float* lstats = (float*)(ws + 0 * MB + 256 * 1024);     // 256 KB

    bias_kernel<<<16, 256, 0, stream>>>(amask, kpm, mbias, Bsz * Lq);

    cvt_qkv<<<12288, 256, 0, stream>>>(query, key, value, qbf, kbf, vbf);
    cvt_w4<<<4096, 256, 0, stream>>>(Wq, Wk, Wv, Wo, wqb, wkb, wvb, wob);

    gemm_qkv<<<1536, 256, 0, stream>>>(qbf, kbf, vbf, wqb, wkb, wvb,
                                       bq, bk, bv, QhB, KhB, VtB);

    attn_flash<<<512, 256, 0, stream>>>(QhB, KhB, VtB, mbias, ctxB, mstats, lstats);
    attn_out2<<<dim3(32, 8, 4), 256, 0, stream>>>(QhB, KhB, mbias, mstats, lstats, out2);

    gemm_o<<<512, 256, 0, stream>>>(ctxB, wob, bo, out1);
}

// Round 11
// 171.335 us; speedup vs baseline: 1.8690x; 1.1598x over previous
//
#include <hip/hip_runtime.h>
#include <math.h>

#define Bsz 4
#define Lq  1024
#define Emb 1024
#define Hh  16
#define Dd  64

typedef short bf16x8 __attribute__((ext_vector_type(8)));
typedef float f32x4 __attribute__((ext_vector_type(4)));

static __device__ __forceinline__ unsigned short f2bf(float f) {
    unsigned u = __float_as_uint(f);
    return (unsigned short)((u + 0x7FFFu + ((u >> 16) & 1u)) >> 16);
}
// pack two f32 -> two bf16 (round-half-up) in one v_perm
static __device__ __forceinline__ unsigned pack2(float lo, float hi) {
    return __builtin_amdgcn_perm(__float_as_uint(hi) + 0x8000u,
                                 __float_as_uint(lo) + 0x8000u, 0x07060302u);
}

// cross-fg reduces (lanes {l, l^16, l^32, l^48}); proven-correct shfl form.
static __device__ __forceinline__ float cross_max(float x) {
    x = fmaxf(x, __shfl_xor(x, 16, 64));
    x = fmaxf(x, __shfl_xor(x, 32, 64));
    return x;
}
static __device__ __forceinline__ float cross_sum(float x) {
    x += __shfl_xor(x, 16, 64);
    x += __shfl_xor(x, 32, 64);
    return x;
}

// global -> LDS direct copy, 16 B per lane.
#define GLOAD_LDS16(gp, lp) __builtin_amdgcn_global_load_lds(                  \
    (const __attribute__((address_space(1))) void*)(gp),                       \
    (__attribute__((address_space(3))) void*)(lp), 16, 0, 0)

// ---------------------------------------------------------------------------
__global__ __launch_bounds__(256) void bias_kernel(const float* __restrict__ mask,
                                                   const int* __restrict__ kpm,
                                                   float* __restrict__ bias, int n)
{
    int i = blockIdx.x * 256 + threadIdx.x;
    if (i < n) {
        float b = 8.0f * logf(fmaxf(mask[i], 1e-6f));
        bias[i] = kpm[i] ? -INFINITY : b;
    }
}

// ---------------------------------------------------------------------------
__global__ __launch_bounds__(256) void cvt_qkv(const float* __restrict__ q,
                                               const float* __restrict__ k,
                                               const float* __restrict__ v,
                                               unsigned short* __restrict__ qo,
                                               unsigned short* __restrict__ ko,
                                               unsigned short* __restrict__ vo)
{
    int i = blockIdx.x * 256 + threadIdx.x;
    const float* src; unsigned short* dst; int off;
    if (i < 1048576)      { src = q; dst = qo; off = i; }
    else if (i < 2097152) { src = k; dst = ko; off = i - 1048576; }
    else                  { src = v; dst = vo; off = i - 2097152; }
    float4 x = ((const float4*)src)[off];
    ushort4 o;
    o.x = f2bf(x.x); o.y = f2bf(x.y); o.z = f2bf(x.z); o.w = f2bf(x.w);
    ((ushort4*)dst)[off] = o;
}

__global__ __launch_bounds__(256) void cvt_w4(const float* __restrict__ w0,
                                              const float* __restrict__ w1,
                                              const float* __restrict__ w2,
                                              const float* __restrict__ w3,
                                              unsigned short* __restrict__ o0,
                                              unsigned short* __restrict__ o1,
                                              unsigned short* __restrict__ o2,
                                              unsigned short* __restrict__ o3)
{
    int i = blockIdx.x * 256 + threadIdx.x;
    int reg = i >> 18, off = i & 262143;
    const float* src = (reg == 0) ? w0 : (reg == 1) ? w1 : (reg == 2) ? w2 : w3;
    unsigned short* dst = (reg == 0) ? o0 : (reg == 1) ? o1 : (reg == 2) ? o2 : o3;
    float4 x = ((const float4*)src)[off];
    ushort4 o;
    o.x = f2bf(x.x); o.y = f2bf(x.y); o.z = f2bf(x.z); o.w = f2bf(x.w);
    ((ushort4*)dst)[off] = o;
}

// ---------------------------------------------------------------------------
// Fused Q/K/V projections (unchanged).
// ---------------------------------------------------------------------------
__global__ __launch_bounds__(256) void gemm_qkv(const unsigned short* __restrict__ Aq,
                                                const unsigned short* __restrict__ Ak,
                                                const unsigned short* __restrict__ Av,
                                                const unsigned short* __restrict__ Wq,
                                                const unsigned short* __restrict__ Wk,
                                                const unsigned short* __restrict__ Wv,
                                                const float* __restrict__ biq,
                                                const float* __restrict__ bik,
                                                const float* __restrict__ biv,
                                                unsigned short* __restrict__ Oq,
                                                unsigned short* __restrict__ Ok,
                                                unsigned short* __restrict__ Ov)
{
    const int K = 1024;
    __shared__ unsigned short sA[64][32];
    __shared__ unsigned short sB[128][32];
    int tid = threadIdx.x;
    int w = tid >> 6, lane = tid & 63;

    int bid = blockIdx.x;
    int which = bid >> 9;              // 0=Q 1=K 2=V
    int lin = bid & 511;
    int xcd = lin & 7, idx = lin >> 3; // idx in [0,64)
    int bm = (xcd * 8 + (idx >> 3)) * 64;
    int bn = (idx & 7) * 128;

    const unsigned short* A = (which == 0) ? Aq : (which == 1) ? Ak : Av;
    const unsigned short* Bw = (which == 0) ? Wq : (which == 1) ? Wk : Wv;
    const float* bias = (which == 0) ? biq : (which == 1) ? bik : biv;
    unsigned short* outp = (which == 0) ? Oq : (which == 1) ? Ok : Ov;

    int wr = (w >> 1) * 32, wc = (w & 1) * 64;
    int fr = lane & 15, fk = (lane >> 4) * 8;

    const unsigned short* Ag = A + (size_t)(bm + w * 16 + (lane >> 2)) * K + (lane & 3) * 8;
    const unsigned short* Bg = Bw + (size_t)(bn + w * 32 + (lane >> 2)) * K + (lane & 3) * 8;
    unsigned short* lA0 = &sA[w * 16][0];
    unsigned short* lB0 = &sB[w * 32][0];
    unsigned short* lB1 = &sB[w * 32 + 16][0];

    f32x4 acc[2][4];
#pragma unroll
    for (int i = 0; i < 2; ++i)
#pragma unroll
        for (int j = 0; j < 4; ++j) acc[i][j] = (f32x4){0.f, 0.f, 0.f, 0.f};

    for (int k0 = 0; k0 < K; k0 += 32) {
        __syncthreads();
        GLOAD_LDS16(Ag + k0,          lA0);
        GLOAD_LDS16(Bg + k0,          lB0);
        GLOAD_LDS16(Bg + 16 * K + k0, lB1);
        __syncthreads();
        bf16x8 af[2], bfv[4];
#pragma unroll
        for (int i = 0; i < 2; ++i) af[i]  = *(const bf16x8*)&sA[wr + i * 16 + fr][fk];
#pragma unroll
        for (int j = 0; j < 4; ++j) bfv[j] = *(const bf16x8*)&sB[wc + j * 16 + fr][fk];
#pragma unroll
        for (int i = 0; i < 2; ++i)
#pragma unroll
            for (int j = 0; j < 4; ++j)
                acc[i][j] = __builtin_amdgcn_mfma_f32_16x16x32_bf16(af[i], bfv[j], acc[i][j], 0, 0, 0);
    }

    int rb = (lane >> 4) * 4;
#pragma unroll
    for (int j = 0; j < 4; ++j) {
        int n = bn + wc + j * 16 + fr;
        float bia = bias[n];
#pragma unroll
        for (int i = 0; i < 2; ++i) {
#pragma unroll
            for (int r = 0; r < 4; ++r) {
                int m = bm + wr + i * 16 + rb + r;
                float v = acc[i][j][r] + bia;
                int b = m >> 10, l = m & 1023, h = n >> 6, d = n & 63;
                if (which == 2)
                    outp[(((size_t)(b * Hh + h)) * Dd + d) * Lq + l] = f2bf(v);
                else
                    outp[(((size_t)(b * Hh + h)) * Lq + l) * Dd + d] = f2bf(v);
            }
        }
    }
}

// ---------------------------------------------------------------------------
// Output projection (unchanged).
// ---------------------------------------------------------------------------
__global__ __launch_bounds__(256) void gemm_o(const unsigned short* __restrict__ A,
                                              const unsigned short* __restrict__ Bw,
                                              const float* __restrict__ bias,
                                              float* __restrict__ outp)
{
    const int K = 1024;
    __shared__ unsigned short sA[64][32];
    __shared__ unsigned short sB[128][32];
    int tid = threadIdx.x;
    int w = tid >> 6, lane = tid & 63;

    int lin = blockIdx.x;
    int xcd = lin & 7, idx = lin >> 3;
    int bm = (xcd * 8 + (idx >> 3)) * 64;
    int bn = (idx & 7) * 128;

    int wr = (w >> 1) * 32, wc = (w & 1) * 64;
    int fr = lane & 15, fk = (lane >> 4) * 8;

    const unsigned short* Ag = A + (size_t)(bm + w * 16 + (lane >> 2)) * K + (lane & 3) * 8;
    const unsigned short* Bg = Bw + (size_t)(bn + w * 32 + (lane >> 2)) * K + (lane & 3) * 8;
    unsigned short* lA0 = &sA[w * 16][0];
    unsigned short* lB0 = &sB[w * 32][0];
    unsigned short* lB1 = &sB[w * 32 + 16][0];

    f32x4 acc[2][4];
#pragma unroll
    for (int i = 0; i < 2; ++i)
#pragma unroll
        for (int j = 0; j < 4; ++j) acc[i][j] = (f32x4){0.f, 0.f, 0.f, 0.f};

    for (int k0 = 0; k0 < K; k0 += 32) {
        __syncthreads();
        GLOAD_LDS16(Ag + k0,          lA0);
        GLOAD_LDS16(Bg + k0,          lB0);
        GLOAD_LDS16(Bg + 16 * K + k0, lB1);
        __syncthreads();
        bf16x8 af[2], bfv[4];
#pragma unroll
        for (int i = 0; i < 2; ++i) af[i]  = *(const bf16x8*)&sA[wr + i * 16 + fr][fk];
#pragma unroll
        for (int j = 0; j < 4; ++j) bfv[j] = *(const bf16x8*)&sB[wc + j * 16 + fr][fk];
#pragma unroll
        for (int i = 0; i < 2; ++i)
#pragma unroll
            for (int j = 0; j < 4; ++j)
                acc[i][j] = __builtin_amdgcn_mfma_f32_16x16x32_bf16(af[i], bfv[j], acc[i][j], 0, 0, 0);
    }

    int rb = (lane >> 4) * 4;
#pragma unroll
    for (int j = 0; j < 4; ++j) {
        int n = bn + wc + j * 16 + fr;
        float bia = bias[n];
#pragma unroll
        for (int i = 0; i < 2; ++i)
#pragma unroll
            for (int r = 0; r < 4; ++r) {
                int m = bm + wr + i * 16 + rb + r;
                outp[(size_t)m * 1024 + n] = acc[i][j][r] + bia;
            }
    }
}

// ---------------------------------------------------------------------------
// Pass C: flash attention, LDS-staged K/V (unchanged from round 10).
// ---------------------------------------------------------------------------
__global__ __launch_bounds__(256) void attn_flash(const unsigned short* __restrict__ Qh,
                                                  const unsigned short* __restrict__ Kh,
                                                  const unsigned short* __restrict__ Vt,
                                                  const float* __restrict__ mbias,
                                                  unsigned short* __restrict__ ctx,
                                                  float* __restrict__ mstats,
                                                  float* __restrict__ lstats)
{
    __shared__ float sBias[1024];                 // 4 KB
    __shared__ unsigned short Wl[4][2][16][64];   // 16 KB  per-wave P tiles
    __shared__ unsigned short Kl[2][64][64];      // 16 KB  K chunk dbuf (swizzled)
    __shared__ unsigned short Vl[2][64][64];      // 16 KB  V chunk dbuf (swizzled)

    int tid = threadIdx.x;
    int w = tid >> 6, lane = tid & 63;
    int fr = lane & 15, fg = lane >> 4;

    // XCD-colocation: all 8 qt-blocks of one (b,h) share an XCD.
    int lin = blockIdx.x;
    int xcd = lin & 7, jj = lin >> 3;          // jj in [0,64)
    int pair = xcd * 8 + (jj >> 3);            // 0..63 == h*4 + b
    int qt = jj & 7;
    int b = pair & 3, h = pair >> 2;

    int q0A = qt * 128 + w * 32;
    int q0B = q0A + 16;
    int swz = (fr & 7) << 2;                   // XOR on 4-byte-word index (P tile)
    int csw = fr & 7;                          // XOR on col16 index (K/V tiles)

    const unsigned short* Qp = Qh + ((size_t)(b * Hh + h)) * Lq * Dd;
    const unsigned short* Kp = Kh + ((size_t)(b * Hh + h)) * Lq * Dd;
    const unsigned short* Vp = Vt + ((size_t)(b * Hh + h)) * Dd * Lq;

    int srl = lane >> 3;                       // 0..7
    int scb = (lane & 7) ^ srl;                // pre-swizzled col16

#define STAGEK(BUF, KC) do {                                                     \
    _Pragma("unroll")                                                            \
    for (int i = 0; i < 2; ++i)                                                  \
        GLOAD_LDS16(Kp + (size_t)((KC) + w * 16 + i * 8 + srl) * Dd + scb * 8,   \
                    &Kl[BUF][w * 16 + i * 8][0]);                                \
} while (0)
#define STAGEV(BUF, KC) do {                                                     \
    _Pragma("unroll")                                                            \
    for (int i = 0; i < 2; ++i)                                                  \
        GLOAD_LDS16(Vp + (size_t)(w * 16 + i * 8 + srl) * Lq + (KC) + scb * 8,   \
                    &Vl[BUF][w * 16 + i * 8][0]);                                \
} while (0)

    for (int i = tid; i < 1024; i += 256) sBias[i] = mbias[b * Lq + i];

    bf16x8 qA0 = *(const bf16x8*)(Qp + (size_t)(q0A + fr) * Dd + fg * 8);
    bf16x8 qA1 = *(const bf16x8*)(Qp + (size_t)(q0A + fr) * Dd + 32 + fg * 8);
    bf16x8 qB0 = *(const bf16x8*)(Qp + (size_t)(q0B + fr) * Dd + fg * 8);
    bf16x8 qB1 = *(const bf16x8*)(Qp + (size_t)(q0B + fr) * Dd + 32 + fg * 8);

    f32x4 OA[4], OB[4];
#pragma unroll
    for (int dt = 0; dt < 4; ++dt) { OA[dt] = (f32x4){0.f,0.f,0.f,0.f}; OB[dt] = (f32x4){0.f,0.f,0.f,0.f}; }
    float mA = -INFINITY, lA = 0.f, mB = -INFINITY, lB = 0.f;

    bf16x8 vb0[4], vb1[4];

#define RDK(K0, K1, BUF) do {                                                    \
    _Pragma("unroll")                                                            \
    for (int kt = 0; kt < 4; ++kt) {                                             \
        K0[kt] = *(const bf16x8*)&Kl[BUF][kt * 16 + fr][(fg ^ csw) * 8];         \
        K1[kt] = *(const bf16x8*)&Kl[BUF][kt * 16 + fr][((4 + fg) ^ csw) * 8];   \
    }                                                                            \
} while (0)
#define RDV(BUF) do {                                                            \
    _Pragma("unroll")                                                            \
    for (int dt = 0; dt < 4; ++dt) {                                             \
        vb0[dt] = *(const bf16x8*)&Vl[BUF][dt * 16 + fr][(fg ^ csw) * 8];        \
        vb1[dt] = *(const bf16x8*)&Vl[BUF][dt * 16 + fr][((4 + fg) ^ csw) * 8];  \
    }                                                                            \
} while (0)

#define QK(S, K0, K1, B0, B1) do {                                               \
    _Pragma("unroll")                                                            \
    for (int kt = 0; kt < 4; ++kt) {                                             \
        S[kt] = __builtin_amdgcn_mfma_f32_16x16x32_bf16(K0[kt], B0, (f32x4){0.f,0.f,0.f,0.f}, 0, 0, 0); \
        S[kt] = __builtin_amdgcn_mfma_f32_16x16x32_bf16(K1[kt], B1, S[kt], 0, 0, 0); \
    }                                                                            \
} while (0)

#define SMPV(S, MT, LT, OT, TI, KC) do {                                         \
    float v_[16];                                                                \
    _Pragma("unroll")                                                            \
    for (int kt = 0; kt < 4; ++kt) {                                             \
        float4 bb = *(const float4*)&sBias[(KC) + kt * 16 + fg * 4];             \
        _Pragma("unroll")                                                        \
        for (int r = 0; r < 4; ++r)                                              \
            v_[kt * 4 + r] = S[kt][r] * 0.125f + (&bb.x)[r];                     \
    }                                                                            \
    float t8[8];                                                                 \
    _Pragma("unroll")                                                            \
    for (int i = 0; i < 8; ++i) t8[i] = fmaxf(v_[i], v_[i + 8]);                 \
    float t4[4];                                                                 \
    _Pragma("unroll")                                                            \
    for (int i = 0; i < 4; ++i) t4[i] = fmaxf(t8[i], t8[i + 4]);                 \
    float pmax = fmaxf(fmaxf(t4[0], t4[1]), fmaxf(t4[2], t4[3]));                \
    pmax = cross_max(pmax);                                                      \
    float mn = fmaxf(MT, pmax);                                                  \
    float sc = __expf(MT - mn);                                                  \
    _Pragma("unroll")                                                            \
    for (int i = 0; i < 16; ++i) v_[i] = __expf(v_[i] - mn);                     \
    _Pragma("unroll")                                                            \
    for (int i = 0; i < 8; ++i) t8[i] = v_[i] + v_[i + 8];                       \
    _Pragma("unroll")                                                            \
    for (int i = 0; i < 4; ++i) t4[i] = t8[i] + t8[i + 4];                       \
    float cs = (t4[0] + t4[1]) + (t4[2] + t4[3]);                                \
    cs = cross_sum(cs);                                                          \
    LT = LT * sc + cs;                                                           \
    MT = mn;                                                                     \
    _Pragma("unroll")                                                            \
    for (int dt = 0; dt < 4; ++dt)                                               \
        _Pragma("unroll")                                                        \
        for (int r = 0; r < 4; ++r) OT[dt][r] *= sc;                             \
    _Pragma("unroll")                                                            \
    for (int kt = 0; kt < 4; ++kt) {                                             \
        unsigned w0 = pack2(v_[kt * 4 + 0], v_[kt * 4 + 1]);                     \
        unsigned w1 = pack2(v_[kt * 4 + 2], v_[kt * 4 + 3]);                     \
        uint2 pr; pr.x = w0; pr.y = w1;                                          \
        *(uint2*)&Wl[w][TI][fr][2 * ((kt * 8 + fg * 2) ^ swz)] = pr;             \
    }                                                                            \
    bf16x8 pa0 = *(const bf16x8*)&Wl[w][TI][fr][2 * ((fg * 4) ^ swz)];           \
    bf16x8 pa1 = *(const bf16x8*)&Wl[w][TI][fr][2 * ((16 + fg * 4) ^ swz)];      \
    _Pragma("unroll")                                                            \
    for (int dt = 0; dt < 4; ++dt) {                                             \
        OT[dt] = __builtin_amdgcn_mfma_f32_16x16x32_bf16(vb0[dt], pa0, OT[dt], 0, 0, 0); \
        OT[dt] = __builtin_amdgcn_mfma_f32_16x16x32_bf16(vb1[dt], pa1, OT[dt], 0, 0, 0); \
    }                                                                            \
} while (0)

    // prologue: stage chunk 0 into buf 0 (drained by the barrier)
    STAGEK(0, 0);
    STAGEV(0, 0);
    __syncthreads();

#pragma unroll 1
    for (int c = 0; c < 16; ++c) {
        int cur = c & 1;
        if (c < 15) {                           // stage chunk c+1 into the other buf
            STAGEK(cur ^ 1, (c + 1) * 64);
            STAGEV(cur ^ 1, (c + 1) * 64);
        }
        bf16x8 k0[4], k1[4];
        RDK(k0, k1, cur);
        f32x4 SA[4], SB[4];
        QK(SA, k0, k1, qA0, qA1);
        QK(SB, k0, k1, qB0, qB1);
        RDV(cur);
        SMPV(SA, mA, lA, OA, 0, c * 64);
        SMPV(SB, mB, lB, OB, 1, c * 64);
        __syncthreads();                        // drains staging + guards dbuf
    }
#undef STAGEK
#undef STAGEV
#undef RDK
#undef RDV
#undef QK
#undef SMPV

    float liA = 1.f / lA, liB = 1.f / lB;
#pragma unroll
    for (int dt = 0; dt < 4; ++dt) {
#pragma unroll
        for (int r = 0; r < 4; ++r) { OA[dt][r] *= liA; OB[dt][r] *= liB; }
    }
    // O^T layout: lane holds q = fr, d = dt*16 + fg*4 + r  (4 consecutive d)
#pragma unroll
    for (int dt = 0; dt < 4; ++dt) {
        uint2 pa; pa.x = pack2(OA[dt][0], OA[dt][1]); pa.y = pack2(OA[dt][2], OA[dt][3]);
        *(uint2*)(ctx + ((size_t)(b * Lq + q0A + fr)) * Emb + h * Dd + dt * 16 + fg * 4) = pa;
        uint2 pb; pb.x = pack2(OB[dt][0], OB[dt][1]); pb.y = pack2(OB[dt][2], OB[dt][3]);
        *(uint2*)(ctx + ((size_t)(b * Lq + q0B + fr)) * Emb + h * Dd + dt * 16 + fg * 4) = pb;
    }

    if (lane < 16) {
        mstats[(size_t)(b * Hh + h) * Lq + q0A + lane] = mA;
        lstats[(size_t)(b * Hh + h) * Lq + q0A + lane] = liA;
        mstats[(size_t)(b * Hh + h) * Lq + q0B + lane] = mB;
        lstats[(size_t)(b * Hh + h) * Lq + q0B + lane] = liB;
    }
}

// ---------------------------------------------------------------------------
// Pass B: out2 = mean_h softmax weights, LDS-staged per-head Q/K (T3 2-phase,
// same staging/swizzle structure as attn_flash).  Block = (qt32, kc128, b).
// Per head: Q tile 32x64 (4 KB) + K tile 128x64 (16 KB) double-buffered in
// LDS; frag reads ds_read_b128 with col16 ^= row&7 swizzle (conflict-free).
// ---------------------------------------------------------------------------
__global__ __launch_bounds__(256) void attn_out2(const unsigned short* __restrict__ Qh,
                                                 const unsigned short* __restrict__ Kh,
                                                 const float* __restrict__ mbias,
                                                 const float* __restrict__ mstats,
                                                 const float* __restrict__ lstats,
                                                 float* __restrict__ out2)
{
    __shared__ unsigned short sQ[2][32][64];    // 8 KB  Q tile dbuf (swizzled)
    __shared__ unsigned short sK[2][128][64];   // 32 KB K tile dbuf (swizzled)
    __shared__ float sM[16][32];
    __shared__ float sLi[16][32];

    int tid = threadIdx.x;
    int w = tid >> 6, lane = tid & 63;
    int fr = lane & 15, fg = lane >> 4;
    int q0 = blockIdx.x * 32;
    int kc = blockIdx.y * 128;
    int b  = blockIdx.z;

    for (int i = tid; i < 512; i += 256) {
        int h = i >> 5, qq = i & 31;
        sM[h][qq]  = mstats[(size_t)(b * Hh + h) * Lq + q0 + qq];
        sLi[h][qq] = lstats[(size_t)(b * Hh + h) * Lq + q0 + qq];
    }

    int srl = lane >> 3;           // 0..7
    int scb = (lane & 7) ^ srl;    // pre-swizzled col16
    int csw = fr & 7;              // read-side XOR

#define STAGEH(BUF, H) do {                                                      \
    const unsigned short* Qp_ = Qh + ((size_t)(b * Hh + (H))) * Lq * Dd;         \
    const unsigned short* Kp_ = Kh + ((size_t)(b * Hh + (H))) * Lq * Dd;         \
    GLOAD_LDS16(Qp_ + (size_t)(q0 + w * 8 + srl) * Dd + scb * 8, &sQ[BUF][w * 8][0]); \
    _Pragma("unroll")                                                            \
    for (int i = 0; i < 4; ++i)                                                  \
        GLOAD_LDS16(Kp_ + (size_t)(kc + w * 32 + i * 8 + srl) * Dd + scb * 8,    \
                    &sK[BUF][w * 32 + i * 8][0]);                                \
} while (0)

#define RDH(AQ, BKk, BUF) do {                                                   \
    _Pragma("unroll")                                                            \
    for (int rt = 0; rt < 2; ++rt)                                               \
        _Pragma("unroll")                                                        \
        for (int ks = 0; ks < 2; ++ks)                                           \
            AQ[rt][ks] = *(const bf16x8*)&sQ[BUF][rt * 16 + fr][((ks * 4 + fg) ^ csw) * 8]; \
    _Pragma("unroll")                                                            \
    for (int ct = 0; ct < 2; ++ct)                                               \
        _Pragma("unroll")                                                        \
        for (int ks = 0; ks < 2; ++ks)                                           \
            BKk[ct][ks] = *(const bf16x8*)&sK[BUF][w * 32 + ct * 16 + fr][((ks * 4 + fg) ^ csw) * 8]; \
} while (0)

#define COMPH(AQ, BKk, H) do {                                                   \
    float4 mrow[2], lirow[2];                                                    \
    _Pragma("unroll")                                                            \
    for (int rt = 0; rt < 2; ++rt) {                                             \
        mrow[rt]  = *(const float4*)&sM[(H)][rt * 16 + fg * 4];                  \
        lirow[rt] = *(const float4*)&sLi[(H)][rt * 16 + fg * 4];                 \
    }                                                                            \
    _Pragma("unroll")                                                            \
    for (int rt = 0; rt < 2; ++rt)                                               \
        _Pragma("unroll")                                                        \
        for (int ct = 0; ct < 2; ++ct) {                                         \
            f32x4 s_ = __builtin_amdgcn_mfma_f32_16x16x32_bf16(AQ[rt][0], BKk[ct][0], (f32x4){0.f,0.f,0.f,0.f}, 0, 0, 0); \
            s_ = __builtin_amdgcn_mfma_f32_16x16x32_bf16(AQ[rt][1], BKk[ct][1], s_, 0, 0, 0); \
            float bia = ct ? bias1 : bias0;                                      \
            _Pragma("unroll")                                                    \
            for (int r = 0; r < 4; ++r)                                          \
                o2[rt][ct][r] += __expf(s_[r] * 0.125f + bia - mrow[rt][r]) * lirow[rt][r]; \
        }                                                                        \
} while (0)

    float bias0 = mbias[b * Lq + kc + w * 32 + fr];
    float bias1 = mbias[b * Lq + kc + w * 32 + 16 + fr];

    float o2[2][2][4];
#pragma unroll
    for (int rt = 0; rt < 2; ++rt)
#pragma unroll
        for (int ct = 0; ct < 2; ++ct)
#pragma unroll
            for (int r = 0; r < 4; ++r) o2[rt][ct][r] = 0.f;

    STAGEH(0, 0);
    __syncthreads();

#pragma unroll 1
    for (int h = 0; h < Hh; ++h) {
        int cur = h & 1;
        if (h < Hh - 1) STAGEH(cur ^ 1, h + 1);
        bf16x8 aq[2][2], bk[2][2];
        RDH(aq, bk, cur);
        COMPH(aq, bk, h);
        __syncthreads();                        // drains staging + guards dbuf
    }
#undef STAGEH
#undef RDH
#undef COMPH

#pragma unroll
    for (int rt = 0; rt < 2; ++rt)
#pragma unroll
        for (int ct = 0; ct < 2; ++ct)
#pragma unroll
            for (int r = 0; r < 4; ++r)
                out2[((size_t)(b * Lq + q0 + rt * 16 + fg * 4 + r)) * Lq + kc + w * 32 + ct * 16 + fr]
                    = o2[rt][ct][r] * 0.0625f;
}

// ---------------------------------------------------------------------------
extern "C" void kernel_launch(void* const* d_in, const int* in_sizes, int n_in,
                              void* d_out, int out_size, void* d_ws, size_t ws_size,
                              hipStream_t stream)
{
    const float* query = (const float*)d_in[0];
    const float* key   = (const float*)d_in[1];
    const float* value = (const float*)d_in[2];
    const float* amask = (const float*)d_in[3];
    const int*   kpm   = (const int*)d_in[4];
    const float* Wq = (const float*)d_in[5];
    const float* bq = (const float*)d_in[6];
    const float* Wk = (const float*)d_in[7];
    const float* bk = (const float*)d_in[8];
    const float* Wv = (const float*)d_in[9];
    const float* bv = (const float*)d_in[10];
    const float* Wo = (const float*)d_in[11];
    const float* bo = (const float*)d_in[12];

    float* out1 = (float*)d_out;                       // (B,L,E) f32
    float* out2 = out1 + (size_t)Bsz * Lq * Emb;       // (B,L,L) f32

    const size_t MB = 1u << 20;
    char* ws = (char*)d_ws;
    unsigned short* qbf = (unsigned short*)(ws + 0 * MB);
    unsigned short* kbf = (unsigned short*)(ws + 8 * MB);
    unsigned short* vbf = (unsigned short*)(ws + 16 * MB);
    unsigned short* wqb = (unsigned short*)(ws + 24 * MB);
    unsigned short* wkb = (unsigned short*)(ws + 26 * MB);
    unsigned short* wvb = (unsigned short*)(ws + 28 * MB);
    unsigned short* wob = (unsigned short*)(ws + 30 * MB);
    unsigned short* QhB = (unsigned short*)(ws + 32 * MB);  // (B,H,L,D) bf16
    unsigned short* KhB = (unsigned short*)(ws + 40 * MB);
    unsigned short* VtB = (unsigned short*)(ws + 48 * MB);  // (B,H,D,L) bf16
    unsigned short* ctxB = (unsigned short*)(ws + 56 * MB); // (B,L,E) bf16
    float* mbias  = (float*)(ws + 64 * MB);                 // 16 KB
    // stats alias the qbf region (dead after gemm_qkv)
    float* mstats = (float*)(ws + 0 * MB);                  // 256 KB
    float* lstats = (float*)(ws + 0 * MB + 256 * 1024);     // 256 KB

    bias_kernel<<<16, 256, 0, stream>>>(amask, kpm, mbias, Bsz * Lq);

    cvt_qkv<<<12288, 256, 0, stream>>>(query, key, value, qbf, kbf, vbf);
    cvt_w4<<<4096, 256, 0, stream>>>(Wq, Wk, Wv, Wo, wqb, wkb, wvb, wob);

    gemm_qkv<<<1536, 256, 0, stream>>>(qbf, kbf, vbf, wqb, wkb, wvb,
                                       bq, bk, bv, QhB, KhB, VtB);

    attn_flash<<<512, 256, 0, stream>>>(QhB, KhB, VtB, mbias, ctxB, mstats, lstats);
    attn_out2<<<dim3(32, 8, 4), 256, 0, stream>>>(QhB, KhB, mbias, mstats, lstats, out2);

    gemm_o<<<512, 256, 0, stream>>>(ctxB, wob, bo, out1);
}

// Round 12
// 160.374 us; speedup vs baseline: 1.9968x; 1.0683x over previous
//
#include <hip/hip_runtime.h>
#include <math.h>

#define Bsz 4
#define Lq  1024
#define Emb 1024
#define Hh  16
#define Dd  64

typedef short bf16x8 __attribute__((ext_vector_type(8)));
typedef float f32x4 __attribute__((ext_vector_type(4)));

static __device__ __forceinline__ unsigned short f2bf(float f) {
    unsigned u = __float_as_uint(f);
    return (unsigned short)((u + 0x7FFFu + ((u >> 16) & 1u)) >> 16);
}
// pack two f32 -> two bf16 (round-half-up) in one v_perm
static __device__ __forceinline__ unsigned pack2(float lo, float hi) {
    return __builtin_amdgcn_perm(__float_as_uint(hi) + 0x8000u,
                                 __float_as_uint(lo) + 0x8000u, 0x07060302u);
}

// cross-fg reduces (lanes {l, l^16, l^32, l^48}); proven-correct shfl form.
static __device__ __forceinline__ float cross_max(float x) {
    x = fmaxf(x, __shfl_xor(x, 16, 64));
    x = fmaxf(x, __shfl_xor(x, 32, 64));
    return x;
}
static __device__ __forceinline__ float cross_sum(float x) {
    x += __shfl_xor(x, 16, 64);
    x += __shfl_xor(x, 32, 64);
    return x;
}

// global -> LDS direct copy, 16 B per lane.
#define GLOAD_LDS16(gp, lp) __builtin_amdgcn_global_load_lds(                  \
    (const __attribute__((address_space(1))) void*)(gp),                       \
    (__attribute__((address_space(3))) void*)(lp), 16, 0, 0)

// ---------------------------------------------------------------------------
__global__ __launch_bounds__(256) void bias_kernel(const float* __restrict__ mask,
                                                   const int* __restrict__ kpm,
                                                   float* __restrict__ bias, int n)
{
    int i = blockIdx.x * 256 + threadIdx.x;
    if (i < n) {
        float b = 8.0f * logf(fmaxf(mask[i], 1e-6f));
        bias[i] = kpm[i] ? -INFINITY : b;
    }
}

// ---------------------------------------------------------------------------
__global__ __launch_bounds__(256) void cvt_qkv(const float* __restrict__ q,
                                               const float* __restrict__ k,
                                               const float* __restrict__ v,
                                               unsigned short* __restrict__ qo,
                                               unsigned short* __restrict__ ko,
                                               unsigned short* __restrict__ vo)
{
    int i = blockIdx.x * 256 + threadIdx.x;
    const float* src; unsigned short* dst; int off;
    if (i < 1048576)      { src = q; dst = qo; off = i; }
    else if (i < 2097152) { src = k; dst = ko; off = i - 1048576; }
    else                  { src = v; dst = vo; off = i - 2097152; }
    float4 x = ((const float4*)src)[off];
    ushort4 o;
    o.x = f2bf(x.x); o.y = f2bf(x.y); o.z = f2bf(x.z); o.w = f2bf(x.w);
    ((ushort4*)dst)[off] = o;
}

__global__ __launch_bounds__(256) void cvt_w4(const float* __restrict__ w0,
                                              const float* __restrict__ w1,
                                              const float* __restrict__ w2,
                                              const float* __restrict__ w3,
                                              unsigned short* __restrict__ o0,
                                              unsigned short* __restrict__ o1,
                                              unsigned short* __restrict__ o2,
                                              unsigned short* __restrict__ o3)
{
    int i = blockIdx.x * 256 + threadIdx.x;
    int reg = i >> 18, off = i & 262143;
    const float* src = (reg == 0) ? w0 : (reg == 1) ? w1 : (reg == 2) ? w2 : w3;
    unsigned short* dst = (reg == 0) ? o0 : (reg == 1) ? o1 : (reg == 2) ? o2 : o3;
    float4 x = ((const float4*)src)[off];
    ushort4 o;
    o.x = f2bf(x.x); o.y = f2bf(x.y); o.z = f2bf(x.z); o.w = f2bf(x.w);
    ((ushort4*)dst)[off] = o;
}

// ---------------------------------------------------------------------------
// Fused Q/K/V projections, stage-ahead dbuf structure (flash-style T3):
// BK=64, LDS rows 128 B with XOR swizzle (stage scb=(l&7)^(l>>3), read ^fr&7),
// loop = { stage(next buf) -> read frags(cur) -> 16 MFMA -> barrier }.
// 64x128 tile; LDS 48 KB -> 3 blocks/CU.
// ---------------------------------------------------------------------------
__global__ __launch_bounds__(256) void gemm_qkv(const unsigned short* __restrict__ Aq,
                                                const unsigned short* __restrict__ Ak,
                                                const unsigned short* __restrict__ Av,
                                                const unsigned short* __restrict__ Wq,
                                                const unsigned short* __restrict__ Wk,
                                                const unsigned short* __restrict__ Wv,
                                                const float* __restrict__ biq,
                                                const float* __restrict__ bik,
                                                const float* __restrict__ biv,
                                                unsigned short* __restrict__ Oq,
                                                unsigned short* __restrict__ Ok,
                                                unsigned short* __restrict__ Ov)
{
    const int K = 1024;
    __shared__ unsigned short sA[2][64][64];    // 16 KB  dbuf, swizzled
    __shared__ unsigned short sB[2][128][64];   // 32 KB  dbuf, swizzled
    int tid = threadIdx.x;
    int w = tid >> 6, lane = tid & 63;

    int bid = blockIdx.x;
    int which = bid >> 9;              // 0=Q 1=K 2=V
    int lin = bid & 511;
    int xcd = lin & 7, idx = lin >> 3; // idx in [0,64)
    int bm = (xcd * 8 + (idx >> 3)) * 64;
    int bn = (idx & 7) * 128;

    const unsigned short* A = (which == 0) ? Aq : (which == 1) ? Ak : Av;
    const unsigned short* Bw = (which == 0) ? Wq : (which == 1) ? Wk : Wv;
    const float* bias = (which == 0) ? biq : (which == 1) ? bik : biv;
    unsigned short* outp = (which == 0) ? Oq : (which == 1) ? Ok : Ov;

    int wr = (w >> 1) * 32, wc = (w & 1) * 64;
    int fr = lane & 15, fg = lane >> 4;
    int csw = fr & 7;                  // read-side XOR on col16 unit

    int srl = lane >> 3;               // 0..7
    int scb = (lane & 7) ^ srl;        // pre-swizzled col16 on stage

    const unsigned short* Ag = A + (size_t)(bm + w * 16 + srl) * K + scb * 8;
    const unsigned short* Bg = Bw + (size_t)(bn + w * 32 + srl) * K + scb * 8;

#define STAGE(BUF, K0) do {                                                      \
    _Pragma("unroll")                                                            \
    for (int j = 0; j < 2; ++j)                                                  \
        GLOAD_LDS16(Ag + (size_t)j * 8 * K + (K0), &sA[BUF][w * 16 + j * 8][0]); \
    _Pragma("unroll")                                                            \
    for (int j = 0; j < 4; ++j)                                                  \
        GLOAD_LDS16(Bg + (size_t)j * 8 * K + (K0), &sB[BUF][w * 32 + j * 8][0]); \
} while (0)

    f32x4 acc[2][4];
#pragma unroll
    for (int i = 0; i < 2; ++i)
#pragma unroll
        for (int j = 0; j < 4; ++j) acc[i][j] = (f32x4){0.f, 0.f, 0.f, 0.f};

    STAGE(0, 0);
    __syncthreads();

#pragma unroll 1
    for (int k0 = 0; k0 < K; k0 += 64) {
        int cur = (k0 >> 6) & 1;
        if (k0 + 64 < K) STAGE(cur ^ 1, k0 + 64);
        bf16x8 af[2][2], bfv[4][2];
#pragma unroll
        for (int i = 0; i < 2; ++i)
#pragma unroll
            for (int kk = 0; kk < 2; ++kk)
                af[i][kk] = *(const bf16x8*)&sA[cur][wr + i * 16 + fr][((kk * 4 + fg) ^ csw) * 8];
#pragma unroll
        for (int j = 0; j < 4; ++j)
#pragma unroll
            for (int kk = 0; kk < 2; ++kk)
                bfv[j][kk] = *(const bf16x8*)&sB[cur][wc + j * 16 + fr][((kk * 4 + fg) ^ csw) * 8];
#pragma unroll
        for (int i = 0; i < 2; ++i)
#pragma unroll
            for (int j = 0; j < 4; ++j) {
                acc[i][j] = __builtin_amdgcn_mfma_f32_16x16x32_bf16(af[i][0], bfv[j][0], acc[i][j], 0, 0, 0);
                acc[i][j] = __builtin_amdgcn_mfma_f32_16x16x32_bf16(af[i][1], bfv[j][1], acc[i][j], 0, 0, 0);
            }
        __syncthreads();
    }
#undef STAGE

    int rb = (lane >> 4) * 4;
#pragma unroll
    for (int j = 0; j < 4; ++j) {
        int n = bn + wc + j * 16 + fr;
        float bia = bias[n];
#pragma unroll
        for (int i = 0; i < 2; ++i) {
#pragma unroll
            for (int r = 0; r < 4; ++r) {
                int m = bm + wr + i * 16 + rb + r;
                float v = acc[i][j][r] + bia;
                int b = m >> 10, l = m & 1023, h = n >> 6, d = n & 63;
                if (which == 2)
                    outp[(((size_t)(b * Hh + h)) * Dd + d) * Lq + l] = f2bf(v);
                else
                    outp[(((size_t)(b * Hh + h)) * Lq + l) * Dd + d] = f2bf(v);
            }
        }
    }
}

// ---------------------------------------------------------------------------
// Output projection: same stage-ahead dbuf structure, f32 out (M,N).
// ---------------------------------------------------------------------------
__global__ __launch_bounds__(256) void gemm_o(const unsigned short* __restrict__ A,
                                              const unsigned short* __restrict__ Bw,
                                              const float* __restrict__ bias,
                                              float* __restrict__ outp)
{
    const int K = 1024;
    __shared__ unsigned short sA[2][64][64];
    __shared__ unsigned short sB[2][128][64];
    int tid = threadIdx.x;
    int w = tid >> 6, lane = tid & 63;

    int lin = blockIdx.x;
    int xcd = lin & 7, idx = lin >> 3;
    int bm = (xcd * 8 + (idx >> 3)) * 64;
    int bn = (idx & 7) * 128;

    int wr = (w >> 1) * 32, wc = (w & 1) * 64;
    int fr = lane & 15, fg = lane >> 4;
    int csw = fr & 7;

    int srl = lane >> 3;
    int scb = (lane & 7) ^ srl;

    const unsigned short* Ag = A + (size_t)(bm + w * 16 + srl) * K + scb * 8;
    const unsigned short* Bg = Bw + (size_t)(bn + w * 32 + srl) * K + scb * 8;

#define STAGE(BUF, K0) do {                                                      \
    _Pragma("unroll")                                                            \
    for (int j = 0; j < 2; ++j)                                                  \
        GLOAD_LDS16(Ag + (size_t)j * 8 * K + (K0), &sA[BUF][w * 16 + j * 8][0]); \
    _Pragma("unroll")                                                            \
    for (int j = 0; j < 4; ++j)                                                  \
        GLOAD_LDS16(Bg + (size_t)j * 8 * K + (K0), &sB[BUF][w * 32 + j * 8][0]); \
} while (0)

    f32x4 acc[2][4];
#pragma unroll
    for (int i = 0; i < 2; ++i)
#pragma unroll
        for (int j = 0; j < 4; ++j) acc[i][j] = (f32x4){0.f, 0.f, 0.f, 0.f};

    STAGE(0, 0);
    __syncthreads();

#pragma unroll 1
    for (int k0 = 0; k0 < K; k0 += 64) {
        int cur = (k0 >> 6) & 1;
        if (k0 + 64 < K) STAGE(cur ^ 1, k0 + 64);
        bf16x8 af[2][2], bfv[4][2];
#pragma unroll
        for (int i = 0; i < 2; ++i)
#pragma unroll
            for (int kk = 0; kk < 2; ++kk)
                af[i][kk] = *(const bf16x8*)&sA[cur][wr + i * 16 + fr][((kk * 4 + fg) ^ csw) * 8];
#pragma unroll
        for (int j = 0; j < 4; ++j)
#pragma unroll
            for (int kk = 0; kk < 2; ++kk)
                bfv[j][kk] = *(const bf16x8*)&sB[cur][wc + j * 16 + fr][((kk * 4 + fg) ^ csw) * 8];
#pragma unroll
        for (int i = 0; i < 2; ++i)
#pragma unroll
            for (int j = 0; j < 4; ++j) {
                acc[i][j] = __builtin_amdgcn_mfma_f32_16x16x32_bf16(af[i][0], bfv[j][0], acc[i][j], 0, 0, 0);
                acc[i][j] = __builtin_amdgcn_mfma_f32_16x16x32_bf16(af[i][1], bfv[j][1], acc[i][j], 0, 0, 0);
            }
        __syncthreads();
    }
#undef STAGE

    int rb = (lane >> 4) * 4;
#pragma unroll
    for (int j = 0; j < 4; ++j) {
        int n = bn + wc + j * 16 + fr;
        float bia = bias[n];
#pragma unroll
        for (int i = 0; i < 2; ++i)
#pragma unroll
            for (int r = 0; r < 4; ++r) {
                int m = bm + wr + i * 16 + rb + r;
                outp[(size_t)m * 1024 + n] = acc[i][j][r] + bia;
            }
    }
}

// ---------------------------------------------------------------------------
// Pass C: flash attention, LDS-staged K/V (unchanged from round 10).
// ---------------------------------------------------------------------------
__global__ __launch_bounds__(256) void attn_flash(const unsigned short* __restrict__ Qh,
                                                  const unsigned short* __restrict__ Kh,
                                                  const unsigned short* __restrict__ Vt,
                                                  const float* __restrict__ mbias,
                                                  unsigned short* __restrict__ ctx,
                                                  float* __restrict__ mstats,
                                                  float* __restrict__ lstats)
{
    __shared__ float sBias[1024];                 // 4 KB
    __shared__ unsigned short Wl[4][2][16][64];   // 16 KB  per-wave P tiles
    __shared__ unsigned short Kl[2][64][64];      // 16 KB  K chunk dbuf (swizzled)
    __shared__ unsigned short Vl[2][64][64];      // 16 KB  V chunk dbuf (swizzled)

    int tid = threadIdx.x;
    int w = tid >> 6, lane = tid & 63;
    int fr = lane & 15, fg = lane >> 4;

    // XCD-colocation: all 8 qt-blocks of one (b,h) share an XCD.
    int lin = blockIdx.x;
    int xcd = lin & 7, jj = lin >> 3;          // jj in [0,64)
    int pair = xcd * 8 + (jj >> 3);            // 0..63 == h*4 + b
    int qt = jj & 7;
    int b = pair & 3, h = pair >> 2;

    int q0A = qt * 128 + w * 32;
    int q0B = q0A + 16;
    int swz = (fr & 7) << 2;                   // XOR on 4-byte-word index (P tile)
    int csw = fr & 7;                          // XOR on col16 index (K/V tiles)

    const unsigned short* Qp = Qh + ((size_t)(b * Hh + h)) * Lq * Dd;
    const unsigned short* Kp = Kh + ((size_t)(b * Hh + h)) * Lq * Dd;
    const unsigned short* Vp = Vt + ((size_t)(b * Hh + h)) * Dd * Lq;

    int srl = lane >> 3;                       // 0..7
    int scb = (lane & 7) ^ srl;                // pre-swizzled col16

#define STAGEK(BUF, KC) do {                                                     \
    _Pragma("unroll")                                                            \
    for (int i = 0; i < 2; ++i)                                                  \
        GLOAD_LDS16(Kp + (size_t)((KC) + w * 16 + i * 8 + srl) * Dd + scb * 8,   \
                    &Kl[BUF][w * 16 + i * 8][0]);                                \
} while (0)
#define STAGEV(BUF, KC) do {                                                     \
    _Pragma("unroll")                                                            \
    for (int i = 0; i < 2; ++i)                                                  \
        GLOAD_LDS16(Vp + (size_t)(w * 16 + i * 8 + srl) * Lq + (KC) + scb * 8,   \
                    &Vl[BUF][w * 16 + i * 8][0]);                                \
} while (0)

    for (int i = tid; i < 1024; i += 256) sBias[i] = mbias[b * Lq + i];

    bf16x8 qA0 = *(const bf16x8*)(Qp + (size_t)(q0A + fr) * Dd + fg * 8);
    bf16x8 qA1 = *(const bf16x8*)(Qp + (size_t)(q0A + fr) * Dd + 32 + fg * 8);
    bf16x8 qB0 = *(const bf16x8*)(Qp + (size_t)(q0B + fr) * Dd + fg * 8);
    bf16x8 qB1 = *(const bf16x8*)(Qp + (size_t)(q0B + fr) * Dd + 32 + fg * 8);

    f32x4 OA[4], OB[4];
#pragma unroll
    for (int dt = 0; dt < 4; ++dt) { OA[dt] = (f32x4){0.f,0.f,0.f,0.f}; OB[dt] = (f32x4){0.f,0.f,0.f,0.f}; }
    float mA = -INFINITY, lA = 0.f, mB = -INFINITY, lB = 0.f;

    bf16x8 vb0[4], vb1[4];

#define RDK(K0, K1, BUF) do {                                                    \
    _Pragma("unroll")                                                            \
    for (int kt = 0; kt < 4; ++kt) {                                             \
        K0[kt] = *(const bf16x8*)&Kl[BUF][kt * 16 + fr][(fg ^ csw) * 8];         \
        K1[kt] = *(const bf16x8*)&Kl[BUF][kt * 16 + fr][((4 + fg) ^ csw) * 8];   \
    }                                                                            \
} while (0)
#define RDV(BUF) do {                                                            \
    _Pragma("unroll")                                                            \
    for (int dt = 0; dt < 4; ++dt) {                                             \
        vb0[dt] = *(const bf16x8*)&Vl[BUF][dt * 16 + fr][(fg ^ csw) * 8];        \
        vb1[dt] = *(const bf16x8*)&Vl[BUF][dt * 16 + fr][((4 + fg) ^ csw) * 8];  \
    }                                                                            \
} while (0)

#define QK(S, K0, K1, B0, B1) do {                                               \
    _Pragma("unroll")                                                            \
    for (int kt = 0; kt < 4; ++kt) {                                             \
        S[kt] = __builtin_amdgcn_mfma_f32_16x16x32_bf16(K0[kt], B0, (f32x4){0.f,0.f,0.f,0.f}, 0, 0, 0); \
        S[kt] = __builtin_amdgcn_mfma_f32_16x16x32_bf16(K1[kt], B1, S[kt], 0, 0, 0); \
    }                                                                            \
} while (0)

#define SMPV(S, MT, LT, OT, TI, KC) do {                                         \
    float v_[16];                                                                \
    _Pragma("unroll")                                                            \
    for (int kt = 0; kt < 4; ++kt) {                                             \
        float4 bb = *(const float4*)&sBias[(KC) + kt * 16 + fg * 4];             \
        _Pragma("unroll")                                                        \
        for (int r = 0; r < 4; ++r)                                              \
            v_[kt * 4 + r] = S[kt][r] * 0.125f + (&bb.x)[r];                     \
    }                                                                            \
    float t8[8];                                                                 \
    _Pragma("unroll")                                                            \
    for (int i = 0; i < 8; ++i) t8[i] = fmaxf(v_[i], v_[i + 8]);                 \
    float t4[4];                                                                 \
    _Pragma("unroll")                                                            \
    for (int i = 0; i < 4; ++i) t4[i] = fmaxf(t8[i], t8[i + 4]);                 \
    float pmax = fmaxf(fmaxf(t4[0], t4[1]), fmaxf(t4[2], t4[3]));                \
    pmax = cross_max(pmax);                                                      \
    float mn = fmaxf(MT, pmax);                                                  \
    float sc = __expf(MT - mn);                                                  \
    _Pragma("unroll")                                                            \
    for (int i = 0; i < 16; ++i) v_[i] = __expf(v_[i] - mn);                     \
    _Pragma("unroll")                                                            \
    for (int i = 0; i < 8; ++i) t8[i] = v_[i] + v_[i + 8];                       \
    _Pragma("unroll")                                                            \
    for (int i = 0; i < 4; ++i) t4[i] = t8[i] + t8[i + 4];                       \
    float cs = (t4[0] + t4[1]) + (t4[2] + t4[3]);                                \
    cs = cross_sum(cs);                                                          \
    LT = LT * sc + cs;                                                           \
    MT = mn;                                                                     \
    _Pragma("unroll")                                                            \
    for (int dt = 0; dt < 4; ++dt)                                               \
        _Pragma("unroll")                                                        \
        for (int r = 0; r < 4; ++r) OT[dt][r] *= sc;                             \
    _Pragma("unroll")                                                            \
    for (int kt = 0; kt < 4; ++kt) {                                             \
        unsigned w0 = pack2(v_[kt * 4 + 0], v_[kt * 4 + 1]);                     \
        unsigned w1 = pack2(v_[kt * 4 + 2], v_[kt * 4 + 3]);                     \
        uint2 pr; pr.x = w0; pr.y = w1;                                          \
        *(uint2*)&Wl[w][TI][fr][2 * ((kt * 8 + fg * 2) ^ swz)] = pr;             \
    }                                                                            \
    bf16x8 pa0 = *(const bf16x8*)&Wl[w][TI][fr][2 * ((fg * 4) ^ swz)];           \
    bf16x8 pa1 = *(const bf16x8*)&Wl[w][TI][fr][2 * ((16 + fg * 4) ^ swz)];      \
    _Pragma("unroll")                                                            \
    for (int dt = 0; dt < 4; ++dt) {                                             \
        OT[dt] = __builtin_amdgcn_mfma_f32_16x16x32_bf16(vb0[dt], pa0, OT[dt], 0, 0, 0); \
        OT[dt] = __builtin_amdgcn_mfma_f32_16x16x32_bf16(vb1[dt], pa1, OT[dt], 0, 0, 0); \
    }                                                                            \
} while (0)

    // prologue: stage chunk 0 into buf 0 (drained by the barrier)
    STAGEK(0, 0);
    STAGEV(0, 0);
    __syncthreads();

#pragma unroll 1
    for (int c = 0; c < 16; ++c) {
        int cur = c & 1;
        if (c < 15) {                           // stage chunk c+1 into the other buf
            STAGEK(cur ^ 1, (c + 1) * 64);
            STAGEV(cur ^ 1, (c + 1) * 64);
        }
        bf16x8 k0[4], k1[4];
        RDK(k0, k1, cur);
        f32x4 SA[4], SB[4];
        QK(SA, k0, k1, qA0, qA1);
        QK(SB, k0, k1, qB0, qB1);
        RDV(cur);
        SMPV(SA, mA, lA, OA, 0, c * 64);
        SMPV(SB, mB, lB, OB, 1, c * 64);
        __syncthreads();                        // drains staging + guards dbuf
    }
#undef STAGEK
#undef STAGEV
#undef RDK
#undef RDV
#undef QK
#undef SMPV

    float liA = 1.f / lA, liB = 1.f / lB;
#pragma unroll
    for (int dt = 0; dt < 4; ++dt) {
#pragma unroll
        for (int r = 0; r < 4; ++r) { OA[dt][r] *= liA; OB[dt][r] *= liB; }
    }
    // O^T layout: lane holds q = fr, d = dt*16 + fg*4 + r  (4 consecutive d)
#pragma unroll
    for (int dt = 0; dt < 4; ++dt) {
        uint2 pa; pa.x = pack2(OA[dt][0], OA[dt][1]); pa.y = pack2(OA[dt][2], OA[dt][3]);
        *(uint2*)(ctx + ((size_t)(b * Lq + q0A + fr)) * Emb + h * Dd + dt * 16 + fg * 4) = pa;
        uint2 pb; pb.x = pack2(OB[dt][0], OB[dt][1]); pb.y = pack2(OB[dt][2], OB[dt][3]);
        *(uint2*)(ctx + ((size_t)(b * Lq + q0B + fr)) * Emb + h * Dd + dt * 16 + fg * 4) = pb;
    }

    if (lane < 16) {
        mstats[(size_t)(b * Hh + h) * Lq + q0A + lane] = mA;
        lstats[(size_t)(b * Hh + h) * Lq + q0A + lane] = liA;
        mstats[(size_t)(b * Hh + h) * Lq + q0B + lane] = mB;
        lstats[(size_t)(b * Hh + h) * Lq + q0B + lane] = liB;
    }
}

// ---------------------------------------------------------------------------
// Pass B: out2 = mean_h softmax weights, LDS-staged per-head Q/K (unchanged
// from round 11).
// ---------------------------------------------------------------------------
__global__ __launch_bounds__(256) void attn_out2(const unsigned short* __restrict__ Qh,
                                                 const unsigned short* __restrict__ Kh,
                                                 const float* __restrict__ mbias,
                                                 const float* __restrict__ mstats,
                                                 const float* __restrict__ lstats,
                                                 float* __restrict__ out2)
{
    __shared__ unsigned short sQ[2][32][64];    // 8 KB  Q tile dbuf (swizzled)
    __shared__ unsigned short sK[2][128][64];   // 32 KB K tile dbuf (swizzled)
    __shared__ float sM[16][32];
    __shared__ float sLi[16][32];

    int tid = threadIdx.x;
    int w = tid >> 6, lane = tid & 63;
    int fr = lane & 15, fg = lane >> 4;
    int q0 = blockIdx.x * 32;
    int kc = blockIdx.y * 128;
    int b  = blockIdx.z;

    for (int i = tid; i < 512; i += 256) {
        int h = i >> 5, qq = i & 31;
        sM[h][qq]  = mstats[(size_t)(b * Hh + h) * Lq + q0 + qq];
        sLi[h][qq] = lstats[(size_t)(b * Hh + h) * Lq + q0 + qq];
    }

    int srl = lane >> 3;           // 0..7
    int scb = (lane & 7) ^ srl;    // pre-swizzled col16
    int csw = fr & 7;              // read-side XOR

#define STAGEH(BUF, H) do {                                                      \
    const unsigned short* Qp_ = Qh + ((size_t)(b * Hh + (H))) * Lq * Dd;         \
    const unsigned short* Kp_ = Kh + ((size_t)(b * Hh + (H))) * Lq * Dd;         \
    GLOAD_LDS16(Qp_ + (size_t)(q0 + w * 8 + srl) * Dd + scb * 8, &sQ[BUF][w * 8][0]); \
    _Pragma("unroll")                                                            \
    for (int i = 0; i < 4; ++i)                                                  \
        GLOAD_LDS16(Kp_ + (size_t)(kc + w * 32 + i * 8 + srl) * Dd + scb * 8,    \
                    &sK[BUF][w * 32 + i * 8][0]);                                \
} while (0)

#define RDH(AQ, BKk, BUF) do {                                                   \
    _Pragma("unroll")                                                            \
    for (int rt = 0; rt < 2; ++rt)                                               \
        _Pragma("unroll")                                                        \
        for (int ks = 0; ks < 2; ++ks)                                           \
            AQ[rt][ks] = *(const bf16x8*)&sQ[BUF][rt * 16 + fr][((ks * 4 + fg) ^ csw) * 8]; \
    _Pragma("unroll")                                                            \
    for (int ct = 0; ct < 2; ++ct)                                               \
        _Pragma("unroll")                                                        \
        for (int ks = 0; ks < 2; ++ks)                                           \
            BKk[ct][ks] = *(const bf16x8*)&sK[BUF][w * 32 + ct * 16 + fr][((ks * 4 + fg) ^ csw) * 8]; \
} while (0)

#define COMPH(AQ, BKk, H) do {                                                   \
    float4 mrow[2], lirow[2];                                                    \
    _Pragma("unroll")                                                            \
    for (int rt = 0; rt < 2; ++rt) {                                             \
        mrow[rt]  = *(const float4*)&sM[(H)][rt * 16 + fg * 4];                  \
        lirow[rt] = *(const float4*)&sLi[(H)][rt * 16 + fg * 4];                 \
    }                                                                            \
    _Pragma("unroll")                                                            \
    for (int rt = 0; rt < 2; ++rt)                                               \
        _Pragma("unroll")                                                        \
        for (int ct = 0; ct < 2; ++ct) {                                         \
            f32x4 s_ = __builtin_amdgcn_mfma_f32_16x16x32_bf16(AQ[rt][0], BKk[ct][0], (f32x4){0.f,0.f,0.f,0.f}, 0, 0, 0); \
            s_ = __builtin_amdgcn_mfma_f32_16x16x32_bf16(AQ[rt][1], BKk[ct][1], s_, 0, 0, 0); \
            float bia = ct ? bias1 : bias0;                                      \
            _Pragma("unroll")                                                    \
            for (int r = 0; r < 4; ++r)                                          \
                o2[rt][ct][r] += __expf(s_[r] * 0.125f + bia - mrow[rt][r]) * lirow[rt][r]; \
        }                                                                        \
} while (0)

    float bias0 = mbias[b * Lq + kc + w * 32 + fr];
    float bias1 = mbias[b * Lq + kc + w * 32 + 16 + fr];

    float o2[2][2][4];
#pragma unroll
    for (int rt = 0; rt < 2; ++rt)
#pragma unroll
        for (int ct = 0; ct < 2; ++ct)
#pragma unroll
            for (int r = 0; r < 4; ++r) o2[rt][ct][r] = 0.f;

    STAGEH(0, 0);
    __syncthreads();

#pragma unroll 1
    for (int h = 0; h < Hh; ++h) {
        int cur = h & 1;
        if (h < Hh - 1) STAGEH(cur ^ 1, h + 1);
        bf16x8 aq[2][2], bk[2][2];
        RDH(aq, bk, cur);
        COMPH(aq, bk, h);
        __syncthreads();                        // drains staging + guards dbuf
    }
#undef STAGEH
#undef RDH
#undef COMPH

#pragma unroll
    for (int rt = 0; rt < 2; ++rt)
#pragma unroll
        for (int ct = 0; ct < 2; ++ct)
#pragma unroll
            for (int r = 0; r < 4; ++r)
                out2[((size_t)(b * Lq + q0 + rt * 16 + fg * 4 + r)) * Lq + kc + w * 32 + ct * 16 + fr]
                    = o2[rt][ct][r] * 0.0625f;
}

// ---------------------------------------------------------------------------
extern "C" void kernel_launch(void* const* d_in, const int* in_sizes, int n_in,
                              void* d_out, int out_size, void* d_ws, size_t ws_size,
                              hipStream_t stream)
{
    const float* query = (const float*)d_in[0];
    const float* key   = (const float*)d_in[1];
    const float* value = (const float*)d_in[2];
    const float* amask = (const float*)d_in[3];
    const int*   kpm   = (const int*)d_in[4];
    const float* Wq = (const float*)d_in[5];
    const float* bq = (const float*)d_in[6];
    const float* Wk = (const float*)d_in[7];
    const float* bk = (const float*)d_in[8];
    const float* Wv = (const float*)d_in[9];
    const float* bv = (const float*)d_in[10];
    const float* Wo = (const float*)d_in[11];
    const float* bo = (const float*)d_in[12];

    float* out1 = (float*)d_out;                       // (B,L,E) f32
    float* out2 = out1 + (size_t)Bsz * Lq * Emb;       // (B,L,L) f32

    const size_t MB = 1u << 20;
    char* ws = (char*)d_ws;
    unsigned short* qbf = (unsigned short*)(ws + 0 * MB);
    unsigned short* kbf = (unsigned short*)(ws + 8 * MB);
    unsigned short* vbf = (unsigned short*)(ws + 16 * MB);
    unsigned short* wqb = (unsigned short*)(ws + 24 * MB);
    unsigned short* wkb = (unsigned short*)(ws + 26 * MB);
    unsigned short* wvb = (unsigned short*)(ws + 28 * MB);
    unsigned short* wob = (unsigned short*)(ws + 30 * MB);
    unsigned short* QhB = (unsigned short*)(ws + 32 * MB);  // (B,H,L,D) bf16
    unsigned short* KhB = (unsigned short*)(ws + 40 * MB);
    unsigned short* VtB = (unsigned short*)(ws + 48 * MB);  // (B,H,D,L) bf16
    unsigned short* ctxB = (unsigned short*)(ws + 56 * MB); // (B,L,E) bf16
    float* mbias  = (float*)(ws + 64 * MB);                 // 16 KB
    // stats alias the qbf region (dead after gemm_qkv)
    float* mstats = (float*)(ws + 0 * MB);                  // 256 KB
    float* lstats = (float*)(ws + 0 * MB + 256 * 1024);     // 256 KB

    bias_kernel<<<16, 256, 0, stream>>>(amask, kpm, mbias, Bsz * Lq);

    cvt_qkv<<<12288, 256, 0, stream>>>(query, key, value, qbf, kbf, vbf);
    cvt_w4<<<4096, 256, 0, stream>>>(Wq, Wk, Wv, Wo, wqb, wkb, wvb, wob);

    gemm_qkv<<<1536, 256, 0, stream>>>(qbf, kbf, vbf, wqb, wkb, wvb,
                                       bq, bk, bv, QhB, KhB, VtB);

    attn_flash<<<512, 256, 0, stream>>>(QhB, KhB, VtB, mbias, ctxB, mstats, lstats);
    attn_out2<<<dim3(32, 8, 4), 256, 0, stream>>>(QhB, KhB, mbias, mstats, lstats, out2);

    gemm_o<<<512, 256, 0, stream>>>(ctxB, wob, bo, out1);
}